// Round 15
// baseline (445.979 us; speedup 1.0000x reference)
//
#include <hip/hip_runtime.h>
#include <hip/hip_bf16.h>

#define SCALE_ 0.17677669529663687f  // 32^-0.5

typedef __attribute__((ext_vector_type(4))) float f32x4;
typedef __attribute__((ext_vector_type(8))) short bf16x8;

__device__ __forceinline__ float gelu_f(float v) {
    return 0.5f * v * (1.0f + erff(v * 0.70710678118654752f));
}

__device__ __forceinline__ unsigned short f2bf(float f) {
    __hip_bfloat16 hb = __float2bfloat16(f);
    return *reinterpret_cast<unsigned short*>(&hb);
}
__device__ __forceinline__ float bf2f(unsigned short u) {
    unsigned int ui = ((unsigned int)u) << 16;
    float f;
    __builtin_memcpy(&f, &ui, 4);
    return f;
}

// ---------------------------------------------------------------------------
// Weight cast f32 -> bf16 (8 matrices of 256x256, incl. Wv)
// ---------------------------------------------------------------------------
struct WC {
    const float* s[8];
    unsigned short* d[8];
};

__global__ __launch_bounds__(256) void wcast_kernel(WC wc) {
    int m = blockIdx.y;
    int e = blockIdx.x * 1024 + threadIdx.x * 4;
    const float4 v = *(const float4*)(wc.s[m] + e);
    ushort4 o;
    o.x = f2bf(v.x); o.y = f2bf(v.y); o.z = f2bf(v.z); o.w = f2bf(v.w);
    *(ushort4*)(wc.d[m] + e) = o;
}

// Wk (256x256) -> Wk^T bf16
__global__ __launch_bounds__(256) void wtrans_kernel(
    const float* __restrict__ Wk, unsigned short* __restrict__ wktb)
{
    int o0 = blockIdx.x * 64, c0 = blockIdx.y * 64;
    __shared__ float sm[64][65];
    int tid = threadIdx.x;
    #pragma unroll
    for (int rep = 0; rep < 16; ++rep) {
        int oo = (tid >> 6) + rep * 4, cc = tid & 63;
        sm[oo][cc] = Wk[(size_t)(o0 + oo) * 256 + c0 + cc];
    }
    __syncthreads();
    #pragma unroll
    for (int rep = 0; rep < 16; ++rep) {
        int cc = (tid >> 6) + rep * 4, oo = tid & 63;
        wktb[(size_t)(c0 + cc) * 256 + o0 + oo] = f2bf(sm[oo][cc]);
    }
}

__global__ __launch_bounds__(512) void biascat_kernel(
    const float* __restrict__ bc1, const float* __restrict__ bl1,
    float* __restrict__ bias512)
{
    int t = threadIdx.x;
    bias512[t] = (t < 256) ? bc1[t] : bl1[t - 256];
}

// ---------------------------------------------------------------------------
// x (b, c, p) f32  ->  xt (b, p, c) bf16
// ---------------------------------------------------------------------------
__global__ __launch_bounds__(256) void xtk_kernel(
    const float* __restrict__ x, unsigned short* __restrict__ xt)
{
    int b = blockIdx.z;
    int c0 = blockIdx.y * 64;
    int p0 = blockIdx.x * 64;
    __shared__ float sm[64][65];
    int tid = threadIdx.x;
    #pragma unroll
    for (int rep = 0; rep < 16; ++rep) {
        int cc = (tid >> 6) + rep * 4, pp = tid & 63;
        sm[cc][pp] = x[(((size_t)(b * 256 + c0 + cc)) << 12) + p0 + pp];
    }
    __syncthreads();
    #pragma unroll
    for (int rep = 0; rep < 16; ++rep) {
        int pp = (tid >> 6) + rep * 4, cc = tid & 63;
        xt[((size_t)(b * 4096 + p0 + pp)) * 256 + c0 + cc] = f2bf(sm[cc][pp]);
    }
}

// ---------------------------------------------------------------------------
// MFMA GEMM: Y[r, o] = act(sum_k A[r,k] * W[o,k] + bias[o]), K = 256 fixed.
// ---------------------------------------------------------------------------
template<int ACT, bool ASRC_F32, bool OUT_BF16>
__global__ __launch_bounds__(256) void mfma_gemm(
    const void* __restrict__ Av, int lda,
    const unsigned short* __restrict__ Wb,
    const float* __restrict__ bias, void* __restrict__ Yv, int ldy)
{
    int r0 = blockIdx.x * 128;
    int o0 = blockIdx.y * 128;
    __shared__ unsigned short As[128][40];
    __shared__ unsigned short Bs[128][40];
    int tid = threadIdx.x;
    int lane = tid & 63;
    int wid = tid >> 6;
    int wr = (wid >> 1) * 64, wc = (wid & 1) * 64;
    int lrow = lane & 15, q = lane >> 4;
    f32x4 acc[4][4];
    #pragma unroll
    for (int i = 0; i < 4; ++i)
        #pragma unroll
        for (int j = 0; j < 4; ++j) {
            acc[i][j][0] = 0.f; acc[i][j][1] = 0.f;
            acc[i][j][2] = 0.f; acc[i][j][3] = 0.f;
        }

    int srow = tid & 127;
    int skc = (tid >> 7) * 16;

    for (int k0 = 0; k0 < 256; k0 += 32) {
        if constexpr (ASRC_F32) {
            const float* Ap = (const float*)Av + (size_t)(r0 + srow) * lda + k0 + skc;
            unsigned short tmp[16];
            #pragma unroll
            for (int t = 0; t < 16; ++t) tmp[t] = f2bf(Ap[t]);
            *(uint4*)&As[srow][skc]     = *(uint4*)&tmp[0];
            *(uint4*)&As[srow][skc + 8] = *(uint4*)&tmp[8];
        } else {
            const unsigned short* Ap = (const unsigned short*)Av + (size_t)(r0 + srow) * lda + k0 + skc;
            *(uint4*)&As[srow][skc]     = *(const uint4*)Ap;
            *(uint4*)&As[srow][skc + 8] = *(const uint4*)(Ap + 8);
        }
        const unsigned short* Wp = Wb + (size_t)(o0 + srow) * 256 + k0 + skc;
        *(uint4*)&Bs[srow][skc]     = *(const uint4*)Wp;
        *(uint4*)&Bs[srow][skc + 8] = *(const uint4*)(Wp + 8);
        __syncthreads();
        bf16x8 a[4], bv[4];
        #pragma unroll
        for (int i = 0; i < 4; ++i) a[i] = *(const bf16x8*)&As[wr + i * 16 + lrow][q * 8];
        #pragma unroll
        for (int j = 0; j < 4; ++j) bv[j] = *(const bf16x8*)&Bs[wc + j * 16 + lrow][q * 8];
        #pragma unroll
        for (int i = 0; i < 4; ++i)
            #pragma unroll
            for (int j = 0; j < 4; ++j)
                acc[i][j] = __builtin_amdgcn_mfma_f32_16x16x32_bf16(a[i], bv[j], acc[i][j], 0, 0, 0);
        __syncthreads();
    }

    #pragma unroll
    for (int i = 0; i < 4; ++i) {
        int rr = r0 + wr + i * 16 + q * 4;
        #pragma unroll
        for (int j = 0; j < 4; ++j) {
            int oo = o0 + wc + j * 16 + lrow;
            float bb = bias[oo];
            #pragma unroll
            for (int g2 = 0; g2 < 4; ++g2) {
                float v = acc[i][j][g2] + bb;
                if constexpr (ACT == 1) v = gelu_f(v);
                else if constexpr (ACT == 2) v = fmaxf(v, 0.0f);
                if constexpr (OUT_BF16)
                    ((unsigned short*)Yv)[(size_t)(rr + g2) * ldy + oo] = f2bf(v);
                else
                    ((float*)Yv)[(size_t)(rr + g2) * ldy + oo] = v;
            }
        }
    }
}

// ---------------------------------------------------------------------------
// cls layer-3 GEMM with FUSED BCE-loss partial.
// grid (128, 2), block 256.
// ---------------------------------------------------------------------------
__global__ __launch_bounds__(256) void mfma_gemm_cls(
    const unsigned short* __restrict__ Ab,
    const unsigned short* __restrict__ Wb,
    const float* __restrict__ bias, float* __restrict__ Y,
    const int* __restrict__ labels, float* __restrict__ part)
{
    int r0 = blockIdx.x * 128;
    int o0 = blockIdx.y * 128;
    __shared__ unsigned short As[128][40];
    __shared__ unsigned short Bs[128][40];
    __shared__ float red[256];
    int tid = threadIdx.x;
    int lane = tid & 63;
    int wid = tid >> 6;
    int wr = (wid >> 1) * 64, wc = (wid & 1) * 64;
    int lrow = lane & 15, q = lane >> 4;
    f32x4 acc[4][4];
    #pragma unroll
    for (int i = 0; i < 4; ++i)
        #pragma unroll
        for (int j = 0; j < 4; ++j) {
            acc[i][j][0] = 0.f; acc[i][j][1] = 0.f;
            acc[i][j][2] = 0.f; acc[i][j][3] = 0.f;
        }

    int srow = tid & 127;
    int skc = (tid >> 7) * 16;

    for (int k0 = 0; k0 < 256; k0 += 32) {
        const unsigned short* Ap = Ab + (size_t)(r0 + srow) * 256 + k0 + skc;
        *(uint4*)&As[srow][skc]     = *(const uint4*)Ap;
        *(uint4*)&As[srow][skc + 8] = *(const uint4*)(Ap + 8);
        const unsigned short* Wp = Wb + (size_t)(o0 + srow) * 256 + k0 + skc;
        *(uint4*)&Bs[srow][skc]     = *(const uint4*)Wp;
        *(uint4*)&Bs[srow][skc + 8] = *(const uint4*)(Wp + 8);
        __syncthreads();
        bf16x8 a[4], bv[4];
        #pragma unroll
        for (int i = 0; i < 4; ++i) a[i] = *(const bf16x8*)&As[wr + i * 16 + lrow][q * 8];
        #pragma unroll
        for (int j = 0; j < 4; ++j) bv[j] = *(const bf16x8*)&Bs[wc + j * 16 + lrow][q * 8];
        #pragma unroll
        for (int i = 0; i < 4; ++i)
            #pragma unroll
            for (int j = 0; j < 4; ++j)
                acc[i][j] = __builtin_amdgcn_mfma_f32_16x16x32_bf16(a[i], bv[j], acc[i][j], 0, 0, 0);
        __syncthreads();
    }

    int lab[4][4];
    #pragma unroll
    for (int i = 0; i < 4; ++i) {
        int rr = r0 + wr + i * 16 + q * 4;
        #pragma unroll
        for (int g2 = 0; g2 < 4; ++g2) lab[i][g2] = labels[rr + g2];
    }

    float lsum = 0.0f;
    #pragma unroll
    for (int i = 0; i < 4; ++i) {
        int rr = r0 + wr + i * 16 + q * 4;
        #pragma unroll
        for (int j = 0; j < 4; ++j) {
            int oo = o0 + wc + j * 16 + lrow;
            float bb = bias[oo];
            #pragma unroll
            for (int g2 = 0; g2 < 4; ++g2) {
                float p = acc[i][j][g2] + bb;
                Y[(size_t)(rr + g2) * 256 + oo] = p;
                float t = (lab[i][g2] == oo) ? 1.0f : 0.0f;
                lsum += fmaxf(p, 0.0f) - p * t + log1pf(expf(-fabsf(p)));
            }
        }
    }
    red[tid] = lsum;
    __syncthreads();
    for (int w = 128; w > 0; w >>= 1) {
        if (tid < w) red[tid] += red[tid + w];
        __syncthreads();
    }
    if (tid == 0) part[blockIdx.y * 128 + blockIdx.x] = red[0];
}

// ---------------------------------------------------------------------------
// posk2: fused dwconv@points + pointwise + tanh, block per (bg, 64-n tile).
// ---------------------------------------------------------------------------
__global__ __launch_bounds__(256) void posk2_kernel(
    const unsigned short* __restrict__ qft, const int* __restrict__ idx,
    const float* __restrict__ W_dw, const float* __restrict__ b_dw,
    const float* __restrict__ W_pw, float* __restrict__ posb)
{
    int bg = blockIdx.y;
    int b = bg >> 2, g = bg & 3;
    int n0 = blockIdx.x * 64;
    __shared__ unsigned short h_s[64][66];   // [c][n]
    __shared__ float wpw_s[20 * 64];         // padded to 20 outputs
    __shared__ float off_s[20][64];
    __shared__ int pny[64], pnx[64];
    int tid = threadIdx.x;

    if (tid < 64) {
        pny[tid] = idx[2 * (n0 + tid)];
        pnx[tid] = idx[2 * (n0 + tid) + 1];
    }
    #pragma unroll
    for (int k = 0; k < 5; ++k) {
        int e = tid + k * 256;
        wpw_s[e] = (e < 1152) ? W_pw[e] : 0.0f;
    }
    __syncthreads();

    int c = tid & 63, nq = tid >> 6;
    float wdw[9];
    #pragma unroll
    for (int k = 0; k < 9; ++k) wdw[k] = W_dw[c * 9 + k];
    float bdw = b_dw[c];
    const unsigned short* qp = qft + (((size_t)b) << 12) * 256 + g * 64 + c;

    #pragma unroll
    for (int ii = 0; ii < 16; ++ii) {
        int nl = nq * 16 + ii;
        int yn = pny[nl], xn = pnx[nl];
        float acc = bdw;
        #pragma unroll
        for (int ky = 0; ky < 3; ++ky) {
            int yy = yn + ky - 1;
            if (yy < 0 || yy > 63) continue;
            #pragma unroll
            for (int kx = 0; kx < 3; ++kx) {
                int xx = xn + kx - 1;
                if (xx < 0 || xx > 63) continue;
                acc += wdw[ky * 3 + kx] * bf2f(qp[(size_t)(yy * 64 + xx) * 256]);
            }
        }
        h_s[c][nl] = f2bf(gelu_f(acc));
    }
    __syncthreads();

    // phase 2: off[o][n] = sum_c wpw[o][c] * h[c][n]
    {
        int n = tid & 63, og = tid >> 6;
        int obase = og * 5;
        float acc[5] = {};
        for (int cc = 0; cc < 64; ++cc) {
            float hval = bf2f(h_s[cc][n]);
            #pragma unroll
            for (int j = 0; j < 5; ++j)
                acc[j] += wpw_s[(obase + j) * 64 + cc] * hval;
        }
        #pragma unroll
        for (int j = 0; j < 5; ++j) off_s[obase + j][n] = acc[j];
    }
    __syncthreads();

    // phase 3: tanh + clamp + write positions
    for (int e = tid; e < 576; e += 256) {
        int km = e / 64, n2 = e & 63;
        int yn = pny[n2], xn = pnx[n2];
        int ky = km / 3, kx = km % 3;
        int yc = yn + ky - 1; yc = yc < 0 ? 0 : (yc > 63 ? 63 : yc);
        int xc = xn + kx - 1; xc = xc < 0 ? 0 : (xc > 63 ? 63 : xc);
        float py = tanhf(off_s[2 * km][n2])     * 0.03125f + ((yc + 0.5f) * 0.03125f - 1.0f);
        float px = tanhf(off_s[2 * km + 1][n2]) * 0.03125f + ((xc + 0.5f) * 0.03125f - 1.0f);
        size_t pb = (((size_t)bg * 9 + km) * 2048 + n0 + n2) * 2;
        posb[pb] = py;
        posb[pb + 1] = px;
    }
}

// ---------------------------------------------------------------------------
// Bilinear sample v4: ushort4 gathers (4 channels/lane) -> 4x fewer VMEM ops.
// grid (32 n-tiles, 36 = g*9+km, 8 b), block 256.
// ---------------------------------------------------------------------------
__global__ __launch_bounds__(256, 4) void sample4_kernel(
    const unsigned short* __restrict__ x1t, const float* __restrict__ posb,
    float* __restrict__ o_xs)
{
    int b = blockIdx.z;
    int g = blockIdx.y / 9, km = blockIdx.y % 9;
    int n0 = blockIdx.x * 64;
    int tid = threadIdx.x;
    int cq = tid & 15;        // c-quad: c = cq*4 .. +3 (within group g)
    int ns = tid >> 4;        // 16 n-slots x 4 consecutive n each
    int bg = b * 4 + g;
    __shared__ float sm[64][68];
    const unsigned short* img4 = x1t + (((size_t)b) << 12) * 256 + g * 64 + cq * 4;
    size_t pb = (((size_t)bg * 9 + km) * 2048 + n0 + ns * 4) * 2;
    float4 P01 = *(const float4*)&posb[pb];
    float4 P23 = *(const float4*)&posb[pb + 4];
    float py[4] = {P01.x, P01.z, P23.x, P23.z};
    float px[4] = {P01.y, P01.w, P23.y, P23.w};
    #pragma unroll
    for (int j = 0; j < 4; ++j) {
        float iy = (py[j] + 1.0f) * 31.5f;
        float ix = (px[j] + 1.0f) * 31.5f;
        float y0f = floorf(iy), x0f = floorf(ix);
        float wy = iy - y0f, wx = ix - x0f;
        int yy = (int)y0f, xx = (int)x0f;
        float w00 = (1.0f - wx) * (1.0f - wy), w01 = wx * (1.0f - wy);
        float w10 = (1.0f - wx) * wy,          w11 = wx * wy;
        bool vy0 = (yy >= 0) & (yy <= 63), vy1 = (yy >= -1) & (yy <= 62);
        bool vx0 = (xx >= 0) & (xx <= 63), vx1 = (xx >= -1) & (xx <= 62);
        if (!vy0) { w00 = 0.f; w01 = 0.f; }
        if (!vy1) { w10 = 0.f; w11 = 0.f; }
        if (!vx0) { w00 = 0.f; w10 = 0.f; }
        if (!vx1) { w01 = 0.f; w11 = 0.f; }
        int yc0 = yy < 0 ? 0 : (yy > 63 ? 63 : yy);
        int yc1 = yy + 1 < 0 ? 0 : (yy + 1 > 63 ? 63 : yy + 1);
        int xc0 = xx < 0 ? 0 : (xx > 63 ? 63 : xx);
        int xc1 = xx + 1 < 0 ? 0 : (xx + 1 > 63 ? 63 : xx + 1);
        ushort4 u00 = *(const ushort4*)(img4 + (size_t)(yc0 * 64 + xc0) * 256);
        ushort4 u01 = *(const ushort4*)(img4 + (size_t)(yc0 * 64 + xc1) * 256);
        ushort4 u10 = *(const ushort4*)(img4 + (size_t)(yc1 * 64 + xc0) * 256);
        ushort4 u11 = *(const ushort4*)(img4 + (size_t)(yc1 * 64 + xc1) * 256);
        f32x4 o;
        o[0] = w00 * bf2f(u00.x) + w01 * bf2f(u01.x) + w10 * bf2f(u10.x) + w11 * bf2f(u11.x);
        o[1] = w00 * bf2f(u00.y) + w01 * bf2f(u01.y) + w10 * bf2f(u10.y) + w11 * bf2f(u11.y);
        o[2] = w00 * bf2f(u00.z) + w01 * bf2f(u01.z) + w10 * bf2f(u10.z) + w11 * bf2f(u11.z);
        o[3] = w00 * bf2f(u00.w) + w01 * bf2f(u01.w) + w10 * bf2f(u10.w) + w11 * bf2f(u11.w);
        *(f32x4*)&sm[ns * 4 + j][cq * 4] = o;
    }
    __syncthreads();
    size_t obase = ((((size_t)(b * 256 + g * 64)) * 9 + km) << 11) + n0;
    int nn = tid & 63;
    #pragma unroll
    for (int rep = 0; rep < 4; ++rep) {
        int cc4 = (tid >> 6) + rep * 4;
        float4 v4 = *(const float4*)&sm[nn][cc4 * 4];
        o_xs[obase + (size_t)(cc4 * 4 + 0) * 18432 + nn] = v4.x;
        o_xs[obase + (size_t)(cc4 * 4 + 1) * 18432 + nn] = v4.y;
        o_xs[obase + (size_t)(cc4 * 4 + 2) * 18432 + nn] = v4.z;
        o_xs[obase + (size_t)(cc4 * 4 + 3) * 18432 + nn] = v4.w;
    }
}

// ---------------------------------------------------------------------------
// qk3[((b*2048+n)*8+h)*256 + c] = sum_j Wk[h*32+j, c] * q[b, h*32+j, n]
// MFMA K=32 with inline q-row gather (qft + idx), flat (b,n,h,c) layout.
// grid (16 n-tiles, 2 c-tiles, 64 bh)
// ---------------------------------------------------------------------------
__global__ __launch_bounds__(256) void qk_mfma_kernel(
    const unsigned short* __restrict__ wktb, const unsigned short* __restrict__ qft,
    const int* __restrict__ idx, unsigned short* __restrict__ qk3)
{
    int bh = blockIdx.z, b = bh >> 3, h = bh & 7;
    int c0 = blockIdx.y * 128;
    int n0 = blockIdx.x * 128;
    __shared__ unsigned short As[128][40];
    __shared__ unsigned short Bs[128][40];
    __shared__ int pn[128];
    int tid = threadIdx.x, lane = tid & 63, wid = tid >> 6;
    int wr = (wid >> 1) * 64, wc = (wid & 1) * 64;
    int lrow = lane & 15, qd = lane >> 4;
    int srow = tid & 127, skc = (tid >> 7) * 16;
    if (tid < 128) pn[tid] = idx[2 * (n0 + tid)] * 64 + idx[2 * (n0 + tid) + 1];
    __syncthreads();
    {
        const unsigned short* Ap = wktb + (size_t)(c0 + srow) * 256 + h * 32 + skc;
        *(uint4*)&As[srow][skc]     = *(const uint4*)Ap;
        *(uint4*)&As[srow][skc + 8] = *(const uint4*)(Ap + 8);
        const unsigned short* Bp = qft + ((size_t)(b * 4096 + pn[srow])) * 256 + h * 32 + skc;
        *(uint4*)&Bs[srow][skc]     = *(const uint4*)Bp;
        *(uint4*)&Bs[srow][skc + 8] = *(const uint4*)(Bp + 8);
    }
    __syncthreads();
    f32x4 acc[4][4];
    #pragma unroll
    for (int i = 0; i < 4; ++i)
        #pragma unroll
        for (int j = 0; j < 4; ++j) {
            acc[i][j][0] = 0.f; acc[i][j][1] = 0.f;
            acc[i][j][2] = 0.f; acc[i][j][3] = 0.f;
        }
    bf16x8 a[4], bv[4];
    #pragma unroll
    for (int i = 0; i < 4; ++i) a[i] = *(const bf16x8*)&As[wr + i * 16 + lrow][qd * 8];
    #pragma unroll
    for (int j = 0; j < 4; ++j) bv[j] = *(const bf16x8*)&Bs[wc + j * 16 + lrow][qd * 8];
    #pragma unroll
    for (int i = 0; i < 4; ++i)
        #pragma unroll
        for (int j = 0; j < 4; ++j)
            acc[i][j] = __builtin_amdgcn_mfma_f32_16x16x32_bf16(a[i], bv[j], acc[i][j], 0, 0, 0);
    #pragma unroll
    for (int i = 0; i < 4; ++i) {
        #pragma unroll
        for (int j = 0; j < 4; ++j) {
            int n = n0 + wc + j * 16 + lrow;
            int c = c0 + wr + i * 16 + qd * 4;
            ushort4 pk;
            pk.x = f2bf(acc[i][j][0]); pk.y = f2bf(acc[i][j][1]);
            pk.z = f2bf(acc[i][j][2]); pk.w = f2bf(acc[i][j][3]);
            *(ushort4*)(qk3 + ((size_t)(b * 2048 + n) * 8 + h) * 256 + c) = pk;
        }
    }
}

// ---------------------------------------------------------------------------
// Fused score+softmax+xsw v10 = v8 structure with 4-n tiles for 2x occupancy:
// LDS 25.2 KB -> 6 blocks/CU (24 waves).  Thread = (cg 64 of 4c, nn 4).
// xs_s stride 38 u16 -> dword bank spread 16 banks, broadcast pairs (free).
// grid (512, 8), block 256.
// ---------------------------------------------------------------------------
__global__ __launch_bounds__(256, 6) void scorexsw10_kernel(
    unsigned short* __restrict__ qk3, const float* __restrict__ xs,
    float* __restrict__ attf)
{
    int b = blockIdx.y;
    int bx = blockIdx.x;
    int nt4 = ((bx & 7) << 6) | (bx >> 3);   // adjacent tiles -> same XCD
    int n0 = nt4 * 4;
    __shared__ unsigned short xs_s[256 * 38];   // [c][km][nn4], stride 38 u16
    __shared__ float sred[4 * 4 * 72];          // [wave][nn][h*9+km]
    __shared__ float a_s[32 * 9];               // [(h*4+nn)][km]
    int tid = threadIdx.x;

    // stage xs tile (f32 global -> bf16 LDS), 9 x float4 per thread
    {
        const float* xsb = xs + (size_t)b * 256 * 18432 + n0;
        #pragma unroll
        for (int k = 0; k < 9; ++k) {
            int li = tid + k * 256;
            int c = li / 9, km = li - c * 9;
            float4 v = *(const float4*)(xsb + ((size_t)c * 9 + km) * 2048);
            ushort4 o;
            o.x = f2bf(v.x); o.y = f2bf(v.y); o.z = f2bf(v.z); o.w = f2bf(v.w);
            *(ushort4*)&xs_s[c * 38 + km * 4] = o;
        }
    }
    __syncthreads();

    int cg = tid >> 2;      // c-group (4 c each), 0..63
    int nn = tid & 3;       // n within 4-tile
    int n = n0 + nn;
    unsigned short* qkp = qk3 + ((size_t)(b * 2048 + n) * 8) * 256 + cg * 4;
    int wv = tid >> 6;
    int sbase = (wv * 4 + nn) * 72;

    // ---- phase A: scores, 2 chunks of 4 heads ----
    #pragma unroll
    for (int hc = 0; hc < 2; ++hc) {
        uint2 qpk[4];
        #pragma unroll
        for (int hh = 0; hh < 4; ++hh)
            qpk[hh] = *(const uint2*)(qkp + (size_t)(hc * 4 + hh) * 256);
        float s[4][9];
        #pragma unroll
        for (int hh = 0; hh < 4; ++hh)
            #pragma unroll
            for (int km = 0; km < 9; ++km) s[hh][km] = 0.0f;
        #pragma unroll
        for (int cl = 0; cl < 4; ++cl) {
            float xv[9];
            const unsigned short* xrow = &xs_s[(cg * 4 + cl) * 38 + nn];
            #pragma unroll
            for (int km = 0; km < 9; ++km) xv[km] = bf2f(xrow[km * 4]);
            #pragma unroll
            for (int hh = 0; hh < 4; ++hh) {
                float qv = bf2f(((const unsigned short*)&qpk[hh])[cl]);
                #pragma unroll
                for (int km = 0; km < 9; ++km) s[hh][km] += qv * xv[km];
            }
        }
        // butterfly over the 16 c-groups within the wave (lane bits 2..5)
        #pragma unroll
        for (int hh = 0; hh < 4; ++hh)
            #pragma unroll
            for (int km = 0; km < 9; ++km) {
                float v = s[hh][km];
                v += __shfl_xor(v, 4);
                v += __shfl_xor(v, 8);
                v += __shfl_xor(v, 16);
                v += __shfl_xor(v, 32);
                s[hh][km] = v;
            }
        if ((cg & 15) == 0) {
            #pragma unroll
            for (int hh = 0; hh < 4; ++hh)
                #pragma unroll
                for (int km = 0; km < 9; ++km)
                    sred[sbase + (hc * 4 + hh) * 9 + km] = s[hh][km];
        }
    }
    __syncthreads();

    // ---- softmax: 32 threads, one per (h, nn) ----
    if (tid < 32) {
        int h = tid >> 2, nn2 = tid & 3;
        float t[9];
        float m = -1e30f;
        #pragma unroll
        for (int km = 0; km < 9; ++km) {
            t[km] = (sred[(0 * 4 + nn2) * 72 + h * 9 + km]
                   + sred[(1 * 4 + nn2) * 72 + h * 9 + km]
                   + sred[(2 * 4 + nn2) * 72 + h * 9 + km]
                   + sred[(3 * 4 + nn2) * 72 + h * 9 + km]) * SCALE_;
            m = fmaxf(m, t[km]);
        }
        float den = 0.0f;
        #pragma unroll
        for (int km = 0; km < 9; ++km) { t[km] = expf(t[km] - m); den += t[km]; }
        float inv = 1.0f / den;
        size_t ab = (((size_t)(b * 8 + h)) * 2048 + n0 + nn2) * 9;
        #pragma unroll
        for (int km = 0; km < 9; ++km) {
            float av = t[km] * inv;
            attf[ab + km] = av;
            a_s[(h * 4 + nn2) * 9 + km] = av;
        }
    }
    __syncthreads();

    // ---- phase B: xsw in-place, 2 chunks of 4 heads ----
    #pragma unroll
    for (int hc = 0; hc < 2; ++hc) {
        float a[4][9];
        #pragma unroll
        for (int hh = 0; hh < 4; ++hh)
            #pragma unroll
            for (int km = 0; km < 9; ++km)
                a[hh][km] = a_s[((hc * 4 + hh) * 4 + nn) * 9 + km];
        unsigned short ov[4][4];
        #pragma unroll
        for (int cl = 0; cl < 4; ++cl) {
            float xv[9];
            const unsigned short* xrow = &xs_s[(cg * 4 + cl) * 38 + nn];
            #pragma unroll
            for (int km = 0; km < 9; ++km) xv[km] = bf2f(xrow[km * 4]);
            #pragma unroll
            for (int hh = 0; hh < 4; ++hh) {
                float acc = 0.0f;
                #pragma unroll
                for (int km = 0; km < 9; ++km) acc += a[hh][km] * xv[km];
                ov[hh][cl] = f2bf(acc);
            }
        }
        #pragma unroll
        for (int hh = 0; hh < 4; ++hh)
            *(uint2*)(qkp + (size_t)(hc * 4 + hh) * 256) = *(const uint2*)&ov[hh][0];
    }
}

// attn.mean(0) -> (NS, KM), deterministic
__global__ __launch_bounds__(256) void attn_reduce_kernel(
    const float* __restrict__ attf, float* __restrict__ o_attn)
{
    int e = blockIdx.x * 256 + threadIdx.x;
    int n = e / 9, km = e % 9;
    float sum = 0.0f;
    for (int bh = 0; bh < 64; ++bh)
        sum += attf[(((size_t)bh << 11) + n) * 9 + km];
    o_attn[e] = sum * (1.0f / 64.0f);
}

// ---------------------------------------------------------------------------
// outv via MFMA -> outb bf16 (r, 256)
// grid (128 row-tiles, 8 h), block 256.
// ---------------------------------------------------------------------------
__global__ __launch_bounds__(256) void outv_mfma_kernel(
    const unsigned short* __restrict__ xswb, const unsigned short* __restrict__ wvb,
    const float* __restrict__ bv, unsigned short* __restrict__ outb)
{
    int h = blockIdx.y;
    int r0 = blockIdx.x * 128;
    __shared__ unsigned short As[128][40];
    __shared__ unsigned short Bs[32][40];
    int tid = threadIdx.x, lane = tid & 63, wid = tid >> 6;
    int lrow = lane & 15, q = lane >> 4;
    int srow = tid & 127, skc = (tid >> 7) * 16;
    f32x4 acc[2][2];
    #pragma unroll
    for (int i = 0; i < 2; ++i)
        #pragma unroll
        for (int j = 0; j < 2; ++j) {
            acc[i][j][0] = 0.f; acc[i][j][1] = 0.f;
            acc[i][j][2] = 0.f; acc[i][j][3] = 0.f;
        }

    for (int k0 = 0; k0 < 256; k0 += 32) {
        const unsigned short* Ap = xswb + ((size_t)(r0 + srow) * 8 + h) * 256 + k0 + skc;
        *(uint4*)&As[srow][skc]     = *(const uint4*)Ap;
        *(uint4*)&As[srow][skc + 8] = *(const uint4*)(Ap + 8);
        if (tid < 64) {
            int o = tid & 31, seg = (tid >> 5) * 16;
            const unsigned short* Wp = wvb + (size_t)(h * 32 + o) * 256 + k0 + seg;
            *(uint4*)&Bs[o][seg]     = *(const uint4*)Wp;
            *(uint4*)&Bs[o][seg + 8] = *(const uint4*)(Wp + 8);
        }
        __syncthreads();
        bf16x8 a2[2], b2[2];
        #pragma unroll
        for (int i = 0; i < 2; ++i) a2[i] = *(const bf16x8*)&As[wid * 32 + i * 16 + lrow][q * 8];
        #pragma unroll
        for (int j = 0; j < 2; ++j) b2[j] = *(const bf16x8*)&Bs[j * 16 + lrow][q * 8];
        #pragma unroll
        for (int i = 0; i < 2; ++i)
            #pragma unroll
            for (int j = 0; j < 2; ++j)
                acc[i][j] = __builtin_amdgcn_mfma_f32_16x16x32_bf16(a2[i], b2[j], acc[i][j], 0, 0, 0);
        __syncthreads();
    }

    #pragma unroll
    for (int i = 0; i < 2; ++i) {
        int rr = r0 + wid * 32 + i * 16 + q * 4;
        #pragma unroll
        for (int j = 0; j < 2; ++j) {
            int oo = h * 32 + j * 16 + lrow;
            float bvv = bv[oo];
            #pragma unroll
            for (int g2 = 0; g2 < 4; ++g2)
                outb[(size_t)(rr + g2) * 256 + oo] = f2bf(acc[i][j][g2] + bvv);
        }
    }
}

// pred_loc = l2 @ Wl3^T + bl3  (Cout=2), l2 in bf16
__global__ __launch_bounds__(256) void loc_kernel(
    const unsigned short* __restrict__ l2, const float* __restrict__ Wl3,
    const float* __restrict__ bl3, float* __restrict__ o_loc)
{
    int f = blockIdx.x * 256 + threadIdx.x;
    int r = f >> 1, o = f & 1;
    const unsigned short* row = l2 + (size_t)r * 256;
    const float* wr = Wl3 + (size_t)o * 256;
    float sum = bl3[o];
    for (int c = 0; c < 256; c += 8) {
        uint4 u = *(const uint4*)&row[c];
        const unsigned short* us = (const unsigned short*)&u;
        float4 w0 = *(const float4*)&wr[c];
        float4 w1 = *(const float4*)&wr[c + 4];
        sum += bf2f(us[0]) * w0.x + bf2f(us[1]) * w0.y + bf2f(us[2]) * w0.z + bf2f(us[3]) * w0.w;
        sum += bf2f(us[4]) * w1.x + bf2f(us[5]) * w1.y + bf2f(us[6]) * w1.z + bf2f(us[7]) * w1.w;
    }
    o_loc[f] = sum;
}

__global__ __launch_bounds__(256) void loss_loc_partial(
    const float* __restrict__ pred, const float* __restrict__ coords,
    float* __restrict__ partial)
{
    int tid = threadIdx.x;
    float sum = 0.0f;
    for (int e = blockIdx.x * 256 + tid; e < 32768; e += 65536)
        sum += fabsf(pred[e] - coords[e]);
    __shared__ float red[256];
    red[tid] = sum;
    __syncthreads();
    for (int w = 128; w > 0; w >>= 1) {
        if (tid < w) red[tid] += red[tid + w];
        __syncthreads();
    }
    if (tid == 0) partial[blockIdx.x] = red[0];
}

__global__ __launch_bounds__(256) void loss_final(
    const float* __restrict__ part, float* __restrict__ out)
{
    __shared__ float red[256];
    int t = threadIdx.x;
    red[t] = part[t];
    __syncthreads();
    for (int w = 128; w > 0; w >>= 1) {
        if (t < w) red[t] += red[t + w];
        __syncthreads();
    }
    if (t == 0) out[0] = red[0] * (1.0f / 4194304.0f);
    __syncthreads();
    red[t] = part[256 + t];
    __syncthreads();
    for (int w = 128; w > 0; w >>= 1) {
        if (t < w) red[t] += red[t + w];
        __syncthreads();
    }
    if (t == 0) out[1] = red[0] * (1.0f / 32768.0f);
}

extern "C" void kernel_launch(void* const* d_in, const int* in_sizes, int n_in,
                              void* d_out, int out_size, void* d_ws, size_t ws_size,
                              hipStream_t stream) {
    const float* x     = (const float*)d_in[0];
    const int*   idx   = (const int*)d_in[1];
    const int*   labels= (const int*)d_in[2];
    const float* coords= (const float*)d_in[3];
    const float* W_ip  = (const float*)d_in[4];
    const float* b_ip  = (const float*)d_in[5];
    const float* Wq    = (const float*)d_in[6];
    const float* bq    = (const float*)d_in[7];
    const float* Wk    = (const float*)d_in[8];
    const float* bk    = (const float*)d_in[9];
    const float* Wv    = (const float*)d_in[10];
    const float* bv    = (const float*)d_in[11];
    const float* W_dw  = (const float*)d_in[12];
    const float* b_dw  = (const float*)d_in[13];
    const float* W_pw  = (const float*)d_in[14];
    const float* Wc1   = (const float*)d_in[15];
    const float* bc1   = (const float*)d_in[16];
    const float* Wc2   = (const float*)d_in[17];
    const float* bc2   = (const float*)d_in[18];
    const float* Wc3   = (const float*)d_in[19];
    const float* bc3   = (const float*)d_in[20];
    const float* Wl1   = (const float*)d_in[21];
    const float* bl1   = (const float*)d_in[22];
    const float* Wl2   = (const float*)d_in[23];
    const float* bl2   = (const float*)d_in[24];
    const float* Wl3   = (const float*)d_in[25];
    const float* bl3   = (const float*)d_in[26];

    float* out = (float*)d_out;
    float* ws  = (float*)d_ws;

    // workspace (f32 units), total ~24.6M = 98.5 MB.
    unsigned short* xt   = (unsigned short*)ws;                       // [0, 8.4M)
    unsigned short* x1t  = (unsigned short*)(ws + 8388608);           // [8.4M, 12.6M)
    unsigned short* qk3  = (unsigned short*)ws;                       // [0, 16.8M) over dead xt/x1t
    unsigned short* qft  = (unsigned short*)(ws + 16777216);          // [16.8M, 21.0M)
    unsigned short* h1   = (unsigned short*)ws;                       // [0, 4.2M) over dead qk3
    unsigned short* h2c  = (unsigned short*)(ws + 4194304);
    unsigned short* h2l  = (unsigned short*)(ws + 6291456);
    float*          posb = ws + 20971520;                             // [21.0M, 22.15M) (later attf)
    float*          attf = ws + 20971520;
    unsigned short* wktb = (unsigned short*)(ws + 22151168);          // 65536 bf16
    unsigned short* wb   = (unsigned short*)(ws + 22183936);          // 8x65536 bf16
    float*          b512 = ws + 22446080;
    float*          part = ws + 22446592;                             // 512
    unsigned short* outb = (unsigned short*)(ws + 22447104);          // 16384x256 bf16

    unsigned short* wipb = wb;
    unsigned short* wqb  = wb + 65536;
    unsigned short* wc1b = wb + 131072;   // wl1 adjacent -> merged 512-row weight
    unsigned short* wl1b = wb + 196608;
    unsigned short* wc2b = wb + 262144;
    unsigned short* wl2b = wb + 327680;
    unsigned short* wc3b = wb + 393216;
    unsigned short* wvb  = wb + 458752;
    (void)wl1b;

    float* o_xs   = out + 2;
    float* o_cls  = out + 37748738;
    float* o_loc  = out + 41943042;
    float* o_attn = out + 41975810;

    // 0. weight casts + Wk^T + merged bias
    WC wc;
    wc.s[0] = W_ip; wc.d[0] = wipb;
    wc.s[1] = Wq;   wc.d[1] = wqb;
    wc.s[2] = Wc1;  wc.d[2] = wc1b;
    wc.s[3] = Wl1;  wc.d[3] = wl1b;
    wc.s[4] = Wc2;  wc.d[4] = wc2b;
    wc.s[5] = Wl2;  wc.d[5] = wl2b;
    wc.s[6] = Wc3;  wc.d[6] = wc3b;
    wc.s[7] = Wv;   wc.d[7] = wvb;
    wcast_kernel<<<dim3(64, 8), 256, 0, stream>>>(wc);
    wtrans_kernel<<<dim3(4, 4), 256, 0, stream>>>(Wk, wktb);
    biascat_kernel<<<1, 512, 0, stream>>>(bc1, bl1, b512);
    // 0b. x -> xt (b,p,c) bf16
    xtk_kernel<<<dim3(64, 4, 8), 256, 0, stream>>>(x, xt);
    // 1. x1t = gelu(xt @ W_ip^T + b_ip)
    mfma_gemm<1, false, true><<<dim3(256, 2), 256, 0, stream>>>(xt, 256, wipb, b_ip, x1t, 256);
    // 2. qft = x1t @ Wq^T + bq
    mfma_gemm<0, false, true><<<dim3(256, 2), 256, 0, stream>>>(x1t, 256, wqb, bq, qft, 256);
    // 3. positions (tiled fused dwconv + pointwise + tanh)
    posk2_kernel<<<dim3(32, 32), 256, 0, stream>>>(qft, idx, W_dw, b_dw, W_pw, posb);
    // 4. bilinear sample (ushort4 gathers) -> x_sampled (output)
    sample4_kernel<<<dim3(32, 36, 8), 256, 0, stream>>>(x1t, posb, o_xs);
    // 5. qk (MFMA, inline q-gather) -> qk3 (b,n,h,c)
    qk_mfma_kernel<<<dim3(16, 2, 64), 256, 0, stream>>>(wktb, qft, idx, qk3);
    // 6. fused scores + softmax + xsw (4-n tiles, 6 blk/CU, in-place)
    scorexsw10_kernel<<<dim3(512, 8), 256, 0, stream>>>(qk3, o_xs, attf);
    // 7. attn mean
    attn_reduce_kernel<<<72, 256, 0, stream>>>(attf, o_attn);
    // 8. out = Wv @ xsw + bv -> outb BF16 (B*NS, 256)  [MFMA]
    outv_mfma_kernel<<<dim3(128, 8), 256, 0, stream>>>(qk3, wvb, bv, outb);
    // 9. merged MLP layer 1 (cls||loc) -> h1 (16384 x 512)  [bf16 A]
    mfma_gemm<2, false, true><<<dim3(128, 4), 256, 0, stream>>>(outb, 256, wc1b, b512, h1, 512);
    // 10-11. layer 2
    mfma_gemm<2, false, true><<<dim3(128, 2), 256, 0, stream>>>(h1, 512, wc2b, bc2, h2c, 256);
    mfma_gemm<2, false, true><<<dim3(128, 2), 256, 0, stream>>>(h1 + 256, 512, wl2b, bl2, h2l, 256);
    // 12. cls layer 3 -> o_cls with FUSED loss partial -> part[0..255]
    mfma_gemm_cls<<<dim3(128, 2), 256, 0, stream>>>(h2c, wc3b, bc3, o_cls, labels, part);
    // 13. loc layer 3
    loc_kernel<<<128, 256, 0, stream>>>(h2l, Wl3, bl3, o_loc);
    // 14-15. losses (cls partial already fused into GEMM)
    loss_loc_partial<<<256, 256, 0, stream>>>(o_loc, coords, part + 256);
    loss_final<<<1, 256, 0, stream>>>(part, out);
}

// Round 16
// 404.023 us; speedup vs baseline: 1.1038x; 1.1038x over previous
//
#include <hip/hip_runtime.h>
#include <hip/hip_bf16.h>

#define SCALE_ 0.17677669529663687f  // 32^-0.5

typedef __attribute__((ext_vector_type(4))) float f32x4;
typedef __attribute__((ext_vector_type(8))) short bf16x8;

__device__ __forceinline__ float gelu_f(float v) {
    return 0.5f * v * (1.0f + erff(v * 0.70710678118654752f));
}

__device__ __forceinline__ unsigned short f2bf(float f) {
    __hip_bfloat16 hb = __float2bfloat16(f);
    return *reinterpret_cast<unsigned short*>(&hb);
}
__device__ __forceinline__ float bf2f(unsigned short u) {
    unsigned int ui = ((unsigned int)u) << 16;
    float f;
    __builtin_memcpy(&f, &ui, 4);
    return f;
}

// ---------------------------------------------------------------------------
// Weight cast f32 -> bf16 (8 matrices of 256x256, incl. Wv)
// ---------------------------------------------------------------------------
struct WC {
    const float* s[8];
    unsigned short* d[8];
};

__global__ __launch_bounds__(256) void wcast_kernel(WC wc) {
    int m = blockIdx.y;
    int e = blockIdx.x * 1024 + threadIdx.x * 4;
    const float4 v = *(const float4*)(wc.s[m] + e);
    ushort4 o;
    o.x = f2bf(v.x); o.y = f2bf(v.y); o.z = f2bf(v.z); o.w = f2bf(v.w);
    *(ushort4*)(wc.d[m] + e) = o;
}

// Wk (256x256) -> Wk^T bf16
__global__ __launch_bounds__(256) void wtrans_kernel(
    const float* __restrict__ Wk, unsigned short* __restrict__ wktb)
{
    int o0 = blockIdx.x * 64, c0 = blockIdx.y * 64;
    __shared__ float sm[64][65];
    int tid = threadIdx.x;
    #pragma unroll
    for (int rep = 0; rep < 16; ++rep) {
        int oo = (tid >> 6) + rep * 4, cc = tid & 63;
        sm[oo][cc] = Wk[(size_t)(o0 + oo) * 256 + c0 + cc];
    }
    __syncthreads();
    #pragma unroll
    for (int rep = 0; rep < 16; ++rep) {
        int cc = (tid >> 6) + rep * 4, oo = tid & 63;
        wktb[(size_t)(c0 + cc) * 256 + o0 + oo] = f2bf(sm[oo][cc]);
    }
}

__global__ __launch_bounds__(512) void biascat_kernel(
    const float* __restrict__ bc1, const float* __restrict__ bl1,
    float* __restrict__ bias512)
{
    int t = threadIdx.x;
    bias512[t] = (t < 256) ? bc1[t] : bl1[t - 256];
}

// ---------------------------------------------------------------------------
// x (b, c, p) f32  ->  xt (b, p, c) bf16
// ---------------------------------------------------------------------------
__global__ __launch_bounds__(256) void xtk_kernel(
    const float* __restrict__ x, unsigned short* __restrict__ xt)
{
    int b = blockIdx.z;
    int c0 = blockIdx.y * 64;
    int p0 = blockIdx.x * 64;
    __shared__ float sm[64][65];
    int tid = threadIdx.x;
    #pragma unroll
    for (int rep = 0; rep < 16; ++rep) {
        int cc = (tid >> 6) + rep * 4, pp = tid & 63;
        sm[cc][pp] = x[(((size_t)(b * 256 + c0 + cc)) << 12) + p0 + pp];
    }
    __syncthreads();
    #pragma unroll
    for (int rep = 0; rep < 16; ++rep) {
        int pp = (tid >> 6) + rep * 4, cc = tid & 63;
        xt[((size_t)(b * 4096 + p0 + pp)) * 256 + c0 + cc] = f2bf(sm[cc][pp]);
    }
}

// ---------------------------------------------------------------------------
// MFMA GEMM: Y[r, o] = act(sum_k A[r,k] * W[o,k] + bias[o]), K = 256 fixed.
// ---------------------------------------------------------------------------
template<int ACT, bool ASRC_F32, bool OUT_BF16>
__global__ __launch_bounds__(256) void mfma_gemm(
    const void* __restrict__ Av, int lda,
    const unsigned short* __restrict__ Wb,
    const float* __restrict__ bias, void* __restrict__ Yv, int ldy)
{
    int r0 = blockIdx.x * 128;
    int o0 = blockIdx.y * 128;
    __shared__ unsigned short As[128][40];
    __shared__ unsigned short Bs[128][40];
    int tid = threadIdx.x;
    int lane = tid & 63;
    int wid = tid >> 6;
    int wr = (wid >> 1) * 64, wc = (wid & 1) * 64;
    int lrow = lane & 15, q = lane >> 4;
    f32x4 acc[4][4];
    #pragma unroll
    for (int i = 0; i < 4; ++i)
        #pragma unroll
        for (int j = 0; j < 4; ++j) {
            acc[i][j][0] = 0.f; acc[i][j][1] = 0.f;
            acc[i][j][2] = 0.f; acc[i][j][3] = 0.f;
        }

    int srow = tid & 127;
    int skc = (tid >> 7) * 16;

    for (int k0 = 0; k0 < 256; k0 += 32) {
        if constexpr (ASRC_F32) {
            const float* Ap = (const float*)Av + (size_t)(r0 + srow) * lda + k0 + skc;
            unsigned short tmp[16];
            #pragma unroll
            for (int t = 0; t < 16; ++t) tmp[t] = f2bf(Ap[t]);
            *(uint4*)&As[srow][skc]     = *(uint4*)&tmp[0];
            *(uint4*)&As[srow][skc + 8] = *(uint4*)&tmp[8];
        } else {
            const unsigned short* Ap = (const unsigned short*)Av + (size_t)(r0 + srow) * lda + k0 + skc;
            *(uint4*)&As[srow][skc]     = *(const uint4*)Ap;
            *(uint4*)&As[srow][skc + 8] = *(const uint4*)(Ap + 8);
        }
        const unsigned short* Wp = Wb + (size_t)(o0 + srow) * 256 + k0 + skc;
        *(uint4*)&Bs[srow][skc]     = *(const uint4*)Wp;
        *(uint4*)&Bs[srow][skc + 8] = *(const uint4*)(Wp + 8);
        __syncthreads();
        bf16x8 a[4], bv[4];
        #pragma unroll
        for (int i = 0; i < 4; ++i) a[i] = *(const bf16x8*)&As[wr + i * 16 + lrow][q * 8];
        #pragma unroll
        for (int j = 0; j < 4; ++j) bv[j] = *(const bf16x8*)&Bs[wc + j * 16 + lrow][q * 8];
        #pragma unroll
        for (int i = 0; i < 4; ++i)
            #pragma unroll
            for (int j = 0; j < 4; ++j)
                acc[i][j] = __builtin_amdgcn_mfma_f32_16x16x32_bf16(a[i], bv[j], acc[i][j], 0, 0, 0);
        __syncthreads();
    }

    #pragma unroll
    for (int i = 0; i < 4; ++i) {
        int rr = r0 + wr + i * 16 + q * 4;
        #pragma unroll
        for (int j = 0; j < 4; ++j) {
            int oo = o0 + wc + j * 16 + lrow;
            float bb = bias[oo];
            #pragma unroll
            for (int g2 = 0; g2 < 4; ++g2) {
                float v = acc[i][j][g2] + bb;
                if constexpr (ACT == 1) v = gelu_f(v);
                else if constexpr (ACT == 2) v = fmaxf(v, 0.0f);
                if constexpr (OUT_BF16)
                    ((unsigned short*)Yv)[(size_t)(rr + g2) * ldy + oo] = f2bf(v);
                else
                    ((float*)Yv)[(size_t)(rr + g2) * ldy + oo] = v;
            }
        }
    }
}

// ---------------------------------------------------------------------------
// cls layer-3 GEMM with FUSED BCE-loss partial.
// grid (128, 2), block 256.
// ---------------------------------------------------------------------------
__global__ __launch_bounds__(256) void mfma_gemm_cls(
    const unsigned short* __restrict__ Ab,
    const unsigned short* __restrict__ Wb,
    const float* __restrict__ bias, float* __restrict__ Y,
    const int* __restrict__ labels, float* __restrict__ part)
{
    int r0 = blockIdx.x * 128;
    int o0 = blockIdx.y * 128;
    __shared__ unsigned short As[128][40];
    __shared__ unsigned short Bs[128][40];
    __shared__ float red[256];
    int tid = threadIdx.x;
    int lane = tid & 63;
    int wid = tid >> 6;
    int wr = (wid >> 1) * 64, wc = (wid & 1) * 64;
    int lrow = lane & 15, q = lane >> 4;
    f32x4 acc[4][4];
    #pragma unroll
    for (int i = 0; i < 4; ++i)
        #pragma unroll
        for (int j = 0; j < 4; ++j) {
            acc[i][j][0] = 0.f; acc[i][j][1] = 0.f;
            acc[i][j][2] = 0.f; acc[i][j][3] = 0.f;
        }

    int srow = tid & 127;
    int skc = (tid >> 7) * 16;

    for (int k0 = 0; k0 < 256; k0 += 32) {
        const unsigned short* Ap = Ab + (size_t)(r0 + srow) * 256 + k0 + skc;
        *(uint4*)&As[srow][skc]     = *(const uint4*)Ap;
        *(uint4*)&As[srow][skc + 8] = *(const uint4*)(Ap + 8);
        const unsigned short* Wp = Wb + (size_t)(o0 + srow) * 256 + k0 + skc;
        *(uint4*)&Bs[srow][skc]     = *(const uint4*)Wp;
        *(uint4*)&Bs[srow][skc + 8] = *(const uint4*)(Wp + 8);
        __syncthreads();
        bf16x8 a[4], bv[4];
        #pragma unroll
        for (int i = 0; i < 4; ++i) a[i] = *(const bf16x8*)&As[wr + i * 16 + lrow][q * 8];
        #pragma unroll
        for (int j = 0; j < 4; ++j) bv[j] = *(const bf16x8*)&Bs[wc + j * 16 + lrow][q * 8];
        #pragma unroll
        for (int i = 0; i < 4; ++i)
            #pragma unroll
            for (int j = 0; j < 4; ++j)
                acc[i][j] = __builtin_amdgcn_mfma_f32_16x16x32_bf16(a[i], bv[j], acc[i][j], 0, 0, 0);
        __syncthreads();
    }

    int lab[4][4];
    #pragma unroll
    for (int i = 0; i < 4; ++i) {
        int rr = r0 + wr + i * 16 + q * 4;
        #pragma unroll
        for (int g2 = 0; g2 < 4; ++g2) lab[i][g2] = labels[rr + g2];
    }

    float lsum = 0.0f;
    #pragma unroll
    for (int i = 0; i < 4; ++i) {
        int rr = r0 + wr + i * 16 + q * 4;
        #pragma unroll
        for (int j = 0; j < 4; ++j) {
            int oo = o0 + wc + j * 16 + lrow;
            float bb = bias[oo];
            #pragma unroll
            for (int g2 = 0; g2 < 4; ++g2) {
                float p = acc[i][j][g2] + bb;
                Y[(size_t)(rr + g2) * 256 + oo] = p;
                float t = (lab[i][g2] == oo) ? 1.0f : 0.0f;
                lsum += fmaxf(p, 0.0f) - p * t + log1pf(expf(-fabsf(p)));
            }
        }
    }
    red[tid] = lsum;
    __syncthreads();
    for (int w = 128; w > 0; w >>= 1) {
        if (tid < w) red[tid] += red[tid + w];
        __syncthreads();
    }
    if (tid == 0) part[blockIdx.y * 128 + blockIdx.x] = red[0];
}

// ---------------------------------------------------------------------------
// posk2: fused dwconv@points + pointwise + tanh, block per (bg, 64-n tile).
// ---------------------------------------------------------------------------
__global__ __launch_bounds__(256) void posk2_kernel(
    const unsigned short* __restrict__ qft, const int* __restrict__ idx,
    const float* __restrict__ W_dw, const float* __restrict__ b_dw,
    const float* __restrict__ W_pw, float* __restrict__ posb)
{
    int bg = blockIdx.y;
    int b = bg >> 2, g = bg & 3;
    int n0 = blockIdx.x * 64;
    __shared__ unsigned short h_s[64][66];   // [c][n]
    __shared__ float wpw_s[20 * 64];         // padded to 20 outputs
    __shared__ float off_s[20][64];
    __shared__ int pny[64], pnx[64];
    int tid = threadIdx.x;

    if (tid < 64) {
        pny[tid] = idx[2 * (n0 + tid)];
        pnx[tid] = idx[2 * (n0 + tid) + 1];
    }
    #pragma unroll
    for (int k = 0; k < 5; ++k) {
        int e = tid + k * 256;
        wpw_s[e] = (e < 1152) ? W_pw[e] : 0.0f;
    }
    __syncthreads();

    int c = tid & 63, nq = tid >> 6;
    float wdw[9];
    #pragma unroll
    for (int k = 0; k < 9; ++k) wdw[k] = W_dw[c * 9 + k];
    float bdw = b_dw[c];
    const unsigned short* qp = qft + (((size_t)b) << 12) * 256 + g * 64 + c;

    #pragma unroll
    for (int ii = 0; ii < 16; ++ii) {
        int nl = nq * 16 + ii;
        int yn = pny[nl], xn = pnx[nl];
        float acc = bdw;
        #pragma unroll
        for (int ky = 0; ky < 3; ++ky) {
            int yy = yn + ky - 1;
            if (yy < 0 || yy > 63) continue;
            #pragma unroll
            for (int kx = 0; kx < 3; ++kx) {
                int xx = xn + kx - 1;
                if (xx < 0 || xx > 63) continue;
                acc += wdw[ky * 3 + kx] * bf2f(qp[(size_t)(yy * 64 + xx) * 256]);
            }
        }
        h_s[c][nl] = f2bf(gelu_f(acc));
    }
    __syncthreads();

    // phase 2: off[o][n] = sum_c wpw[o][c] * h[c][n]
    {
        int n = tid & 63, og = tid >> 6;
        int obase = og * 5;
        float acc[5] = {};
        for (int cc = 0; cc < 64; ++cc) {
            float hval = bf2f(h_s[cc][n]);
            #pragma unroll
            for (int j = 0; j < 5; ++j)
                acc[j] += wpw_s[(obase + j) * 64 + cc] * hval;
        }
        #pragma unroll
        for (int j = 0; j < 5; ++j) off_s[obase + j][n] = acc[j];
    }
    __syncthreads();

    // phase 3: tanh + clamp + write positions
    for (int e = tid; e < 576; e += 256) {
        int km = e / 64, n2 = e & 63;
        int yn = pny[n2], xn = pnx[n2];
        int ky = km / 3, kx = km % 3;
        int yc = yn + ky - 1; yc = yc < 0 ? 0 : (yc > 63 ? 63 : yc);
        int xc = xn + kx - 1; xc = xc < 0 ? 0 : (xc > 63 ? 63 : xc);
        float py = tanhf(off_s[2 * km][n2])     * 0.03125f + ((yc + 0.5f) * 0.03125f - 1.0f);
        float px = tanhf(off_s[2 * km + 1][n2]) * 0.03125f + ((xc + 0.5f) * 0.03125f - 1.0f);
        size_t pb = (((size_t)bg * 9 + km) * 2048 + n0 + n2) * 2;
        posb[pb] = py;
        posb[pb + 1] = px;
    }
}

// ---------------------------------------------------------------------------
// Bilinear sample v4: ushort4 gathers (4 channels/lane) -> 4x fewer VMEM ops.
// grid (32 n-tiles, 36 = g*9+km, 8 b), block 256.
// ---------------------------------------------------------------------------
__global__ __launch_bounds__(256, 4) void sample4_kernel(
    const unsigned short* __restrict__ x1t, const float* __restrict__ posb,
    float* __restrict__ o_xs)
{
    int b = blockIdx.z;
    int g = blockIdx.y / 9, km = blockIdx.y % 9;
    int n0 = blockIdx.x * 64;
    int tid = threadIdx.x;
    int cq = tid & 15;        // c-quad: c = cq*4 .. +3 (within group g)
    int ns = tid >> 4;        // 16 n-slots x 4 consecutive n each
    int bg = b * 4 + g;
    __shared__ float sm[64][68];
    const unsigned short* img4 = x1t + (((size_t)b) << 12) * 256 + g * 64 + cq * 4;
    size_t pb = (((size_t)bg * 9 + km) * 2048 + n0 + ns * 4) * 2;
    float4 P01 = *(const float4*)&posb[pb];
    float4 P23 = *(const float4*)&posb[pb + 4];
    float py[4] = {P01.x, P01.z, P23.x, P23.z};
    float px[4] = {P01.y, P01.w, P23.y, P23.w};
    #pragma unroll
    for (int j = 0; j < 4; ++j) {
        float iy = (py[j] + 1.0f) * 31.5f;
        float ix = (px[j] + 1.0f) * 31.5f;
        float y0f = floorf(iy), x0f = floorf(ix);
        float wy = iy - y0f, wx = ix - x0f;
        int yy = (int)y0f, xx = (int)x0f;
        float w00 = (1.0f - wx) * (1.0f - wy), w01 = wx * (1.0f - wy);
        float w10 = (1.0f - wx) * wy,          w11 = wx * wy;
        bool vy0 = (yy >= 0) & (yy <= 63), vy1 = (yy >= -1) & (yy <= 62);
        bool vx0 = (xx >= 0) & (xx <= 63), vx1 = (xx >= -1) & (xx <= 62);
        if (!vy0) { w00 = 0.f; w01 = 0.f; }
        if (!vy1) { w10 = 0.f; w11 = 0.f; }
        if (!vx0) { w00 = 0.f; w10 = 0.f; }
        if (!vx1) { w01 = 0.f; w11 = 0.f; }
        int yc0 = yy < 0 ? 0 : (yy > 63 ? 63 : yy);
        int yc1 = yy + 1 < 0 ? 0 : (yy + 1 > 63 ? 63 : yy + 1);
        int xc0 = xx < 0 ? 0 : (xx > 63 ? 63 : xx);
        int xc1 = xx + 1 < 0 ? 0 : (xx + 1 > 63 ? 63 : xx + 1);
        ushort4 u00 = *(const ushort4*)(img4 + (size_t)(yc0 * 64 + xc0) * 256);
        ushort4 u01 = *(const ushort4*)(img4 + (size_t)(yc0 * 64 + xc1) * 256);
        ushort4 u10 = *(const ushort4*)(img4 + (size_t)(yc1 * 64 + xc0) * 256);
        ushort4 u11 = *(const ushort4*)(img4 + (size_t)(yc1 * 64 + xc1) * 256);
        f32x4 o;
        o[0] = w00 * bf2f(u00.x) + w01 * bf2f(u01.x) + w10 * bf2f(u10.x) + w11 * bf2f(u11.x);
        o[1] = w00 * bf2f(u00.y) + w01 * bf2f(u01.y) + w10 * bf2f(u10.y) + w11 * bf2f(u11.y);
        o[2] = w00 * bf2f(u00.z) + w01 * bf2f(u01.z) + w10 * bf2f(u10.z) + w11 * bf2f(u11.z);
        o[3] = w00 * bf2f(u00.w) + w01 * bf2f(u01.w) + w10 * bf2f(u10.w) + w11 * bf2f(u11.w);
        *(f32x4*)&sm[ns * 4 + j][cq * 4] = o;
    }
    __syncthreads();
    size_t obase = ((((size_t)(b * 256 + g * 64)) * 9 + km) << 11) + n0;
    int nn = tid & 63;
    #pragma unroll
    for (int rep = 0; rep < 4; ++rep) {
        int cc4 = (tid >> 6) + rep * 4;
        float4 v4 = *(const float4*)&sm[nn][cc4 * 4];
        o_xs[obase + (size_t)(cc4 * 4 + 0) * 18432 + nn] = v4.x;
        o_xs[obase + (size_t)(cc4 * 4 + 1) * 18432 + nn] = v4.y;
        o_xs[obase + (size_t)(cc4 * 4 + 2) * 18432 + nn] = v4.z;
        o_xs[obase + (size_t)(cc4 * 4 + 3) * 18432 + nn] = v4.w;
    }
}

// ---------------------------------------------------------------------------
// qk3[((b*2048+n)*8+h)*256 + c] = sum_j Wk[h*32+j, c] * q[b, h*32+j, n]
// MFMA K=32 with inline q-row gather (qft + idx), flat (b,n,h,c) layout.
// grid (16 n-tiles, 2 c-tiles, 64 bh)
// ---------------------------------------------------------------------------
__global__ __launch_bounds__(256) void qk_mfma_kernel(
    const unsigned short* __restrict__ wktb, const unsigned short* __restrict__ qft,
    const int* __restrict__ idx, unsigned short* __restrict__ qk3)
{
    int bh = blockIdx.z, b = bh >> 3, h = bh & 7;
    int c0 = blockIdx.y * 128;
    int n0 = blockIdx.x * 128;
    __shared__ unsigned short As[128][40];
    __shared__ unsigned short Bs[128][40];
    __shared__ int pn[128];
    int tid = threadIdx.x, lane = tid & 63, wid = tid >> 6;
    int wr = (wid >> 1) * 64, wc = (wid & 1) * 64;
    int lrow = lane & 15, qd = lane >> 4;
    int srow = tid & 127, skc = (tid >> 7) * 16;
    if (tid < 128) pn[tid] = idx[2 * (n0 + tid)] * 64 + idx[2 * (n0 + tid) + 1];
    __syncthreads();
    {
        const unsigned short* Ap = wktb + (size_t)(c0 + srow) * 256 + h * 32 + skc;
        *(uint4*)&As[srow][skc]     = *(const uint4*)Ap;
        *(uint4*)&As[srow][skc + 8] = *(const uint4*)(Ap + 8);
        const unsigned short* Bp = qft + ((size_t)(b * 4096 + pn[srow])) * 256 + h * 32 + skc;
        *(uint4*)&Bs[srow][skc]     = *(const uint4*)Bp;
        *(uint4*)&Bs[srow][skc + 8] = *(const uint4*)(Bp + 8);
    }
    __syncthreads();
    f32x4 acc[4][4];
    #pragma unroll
    for (int i = 0; i < 4; ++i)
        #pragma unroll
        for (int j = 0; j < 4; ++j) {
            acc[i][j][0] = 0.f; acc[i][j][1] = 0.f;
            acc[i][j][2] = 0.f; acc[i][j][3] = 0.f;
        }
    bf16x8 a[4], bv[4];
    #pragma unroll
    for (int i = 0; i < 4; ++i) a[i] = *(const bf16x8*)&As[wr + i * 16 + lrow][qd * 8];
    #pragma unroll
    for (int j = 0; j < 4; ++j) bv[j] = *(const bf16x8*)&Bs[wc + j * 16 + lrow][qd * 8];
    #pragma unroll
    for (int i = 0; i < 4; ++i)
        #pragma unroll
        for (int j = 0; j < 4; ++j)
            acc[i][j] = __builtin_amdgcn_mfma_f32_16x16x32_bf16(a[i], bv[j], acc[i][j], 0, 0, 0);
    #pragma unroll
    for (int i = 0; i < 4; ++i) {
        #pragma unroll
        for (int j = 0; j < 4; ++j) {
            int n = n0 + wc + j * 16 + lrow;
            int c = c0 + wr + i * 16 + qd * 4;
            ushort4 pk;
            pk.x = f2bf(acc[i][j][0]); pk.y = f2bf(acc[i][j][1]);
            pk.z = f2bf(acc[i][j][2]); pk.w = f2bf(acc[i][j][3]);
            *(ushort4*)(qk3 + ((size_t)(b * 2048 + n) * 8 + h) * 256 + c) = pk;
        }
    }
}

// ---------------------------------------------------------------------------
// Fused score+softmax+xsw v8 (measured-best structure), flat qk3 layout.
// grid (256, 8), block 256 = 32 cg x 8 nn.  49.9 KB LDS -> 3 blk/CU.
// ---------------------------------------------------------------------------
__global__ __launch_bounds__(256, 3) void scorexsw8_kernel(
    unsigned short* __restrict__ qk3, const float* __restrict__ xs,
    float* __restrict__ attf)
{
    int b = blockIdx.y;
    int bx = blockIdx.x;
    int nt8 = ((bx & 7) << 5) | (bx >> 3);   // adjacent tiles -> same XCD
    int n0 = nt8 * 8;
    __shared__ unsigned short xs_s[256 * 74];   // [c][km][nn8], stride 74 u16
    __shared__ float sred[4 * 8 * 72];          // [wave][nn][h*9+km]
    __shared__ float a_s[64 * 9];               // [(h*8+nn)][km]
    int tid = threadIdx.x;

    // stage xs tile (f32 global -> bf16 LDS), 18 x float4 per thread
    {
        const float* xsb = xs + (size_t)b * 256 * 18432 + n0;
        #pragma unroll
        for (int k = 0; k < 18; ++k) {
            int li = tid + k * 256;
            int c = li / 18, r = li - c * 18;
            int km = r >> 1, np2 = r & 1;
            float4 v = *(const float4*)(xsb + ((size_t)c * 9 + km) * 2048 + np2 * 4);
            ushort4 o;
            o.x = f2bf(v.x); o.y = f2bf(v.y); o.z = f2bf(v.z); o.w = f2bf(v.w);
            *(ushort4*)&xs_s[c * 74 + km * 8 + np2 * 4] = o;
        }
    }
    __syncthreads();

    int cg = tid >> 3;      // c-group (8 c each), 0..31
    int nn = tid & 7;       // n within 8-tile
    int n = n0 + nn;
    unsigned short* qkp = qk3 + ((size_t)(b * 2048 + n) * 8) * 256 + cg * 8;
    int wv = tid >> 6;
    int sbase = (wv * 8 + nn) * 72;

    // ---- phase A: scores, 2 chunks of 4 heads ----
    #pragma unroll
    for (int hc = 0; hc < 2; ++hc) {
        uint4 qpk[4];
        #pragma unroll
        for (int hh = 0; hh < 4; ++hh)
            qpk[hh] = *(const uint4*)(qkp + (size_t)(hc * 4 + hh) * 256);
        float s[4][9];
        #pragma unroll
        for (int hh = 0; hh < 4; ++hh)
            #pragma unroll
            for (int km = 0; km < 9; ++km) s[hh][km] = 0.0f;
        #pragma unroll
        for (int cl = 0; cl < 8; ++cl) {
            float xv[9];
            const unsigned short* xrow = &xs_s[(cg * 8 + cl) * 74 + nn];
            #pragma unroll
            for (int km = 0; km < 9; ++km) xv[km] = bf2f(xrow[km * 8]);
            #pragma unroll
            for (int hh = 0; hh < 4; ++hh) {
                float qv = bf2f(((const unsigned short*)&qpk[hh])[cl]);
                #pragma unroll
                for (int km = 0; km < 9; ++km) s[hh][km] += qv * xv[km];
            }
        }
        // butterfly over the 8 c-groups within the wave (lane bits 3..5)
        #pragma unroll
        for (int hh = 0; hh < 4; ++hh)
            #pragma unroll
            for (int km = 0; km < 9; ++km) {
                float v = s[hh][km];
                v += __shfl_xor(v, 8);
                v += __shfl_xor(v, 16);
                v += __shfl_xor(v, 32);
                s[hh][km] = v;
            }
        if ((cg & 7) == 0) {
            #pragma unroll
            for (int hh = 0; hh < 4; ++hh)
                #pragma unroll
                for (int km = 0; km < 9; ++km)
                    sred[sbase + (hc * 4 + hh) * 9 + km] = s[hh][km];
        }
    }
    __syncthreads();

    // ---- softmax: 64 threads, one per (h, nn) ----
    if (tid < 64) {
        int h = tid >> 3, nn2 = tid & 7;
        float t[9];
        float m = -1e30f;
        #pragma unroll
        for (int km = 0; km < 9; ++km) {
            t[km] = (sred[(0 * 8 + nn2) * 72 + h * 9 + km]
                   + sred[(1 * 8 + nn2) * 72 + h * 9 + km]
                   + sred[(2 * 8 + nn2) * 72 + h * 9 + km]
                   + sred[(3 * 8 + nn2) * 72 + h * 9 + km]) * SCALE_;
            m = fmaxf(m, t[km]);
        }
        float den = 0.0f;
        #pragma unroll
        for (int km = 0; km < 9; ++km) { t[km] = expf(t[km] - m); den += t[km]; }
        float inv = 1.0f / den;
        size_t ab = (((size_t)(b * 8 + h)) * 2048 + n0 + nn2) * 9;
        #pragma unroll
        for (int km = 0; km < 9; ++km) {
            float av = t[km] * inv;
            attf[ab + km] = av;
            a_s[(h * 8 + nn2) * 9 + km] = av;
        }
    }
    __syncthreads();

    // ---- phase B: xsw in-place, 2 chunks of 4 heads ----
    #pragma unroll
    for (int hc = 0; hc < 2; ++hc) {
        float a[4][9];
        #pragma unroll
        for (int hh = 0; hh < 4; ++hh)
            #pragma unroll
            for (int km = 0; km < 9; ++km)
                a[hh][km] = a_s[((hc * 4 + hh) * 8 + nn) * 9 + km];
        unsigned short ov[4][8];
        #pragma unroll
        for (int cl = 0; cl < 8; ++cl) {
            float xv[9];
            const unsigned short* xrow = &xs_s[(cg * 8 + cl) * 74 + nn];
            #pragma unroll
            for (int km = 0; km < 9; ++km) xv[km] = bf2f(xrow[km * 8]);
            #pragma unroll
            for (int hh = 0; hh < 4; ++hh) {
                float acc = 0.0f;
                #pragma unroll
                for (int km = 0; km < 9; ++km) acc += a[hh][km] * xv[km];
                ov[hh][cl] = f2bf(acc);
            }
        }
        #pragma unroll
        for (int hh = 0; hh < 4; ++hh)
            *(uint4*)(qkp + (size_t)(hc * 4 + hh) * 256) = *(const uint4*)&ov[hh][0];
    }
}

// attn.mean(0) -> (NS, KM), deterministic
__global__ __launch_bounds__(256) void attn_reduce_kernel(
    const float* __restrict__ attf, float* __restrict__ o_attn)
{
    int e = blockIdx.x * 256 + threadIdx.x;
    int n = e / 9, km = e % 9;
    float sum = 0.0f;
    for (int bh = 0; bh < 64; ++bh)
        sum += attf[(((size_t)bh << 11) + n) * 9 + km];
    o_attn[e] = sum * (1.0f / 64.0f);
}

// ---------------------------------------------------------------------------
// outv via MFMA -> outb bf16 (r, 256)
// grid (128 row-tiles, 8 h), block 256.
// ---------------------------------------------------------------------------
__global__ __launch_bounds__(256) void outv_mfma_kernel(
    const unsigned short* __restrict__ xswb, const unsigned short* __restrict__ wvb,
    const float* __restrict__ bv, unsigned short* __restrict__ outb)
{
    int h = blockIdx.y;
    int r0 = blockIdx.x * 128;
    __shared__ unsigned short As[128][40];
    __shared__ unsigned short Bs[32][40];
    int tid = threadIdx.x, lane = tid & 63, wid = tid >> 6;
    int lrow = lane & 15, q = lane >> 4;
    int srow = tid & 127, skc = (tid >> 7) * 16;
    f32x4 acc[2][2];
    #pragma unroll
    for (int i = 0; i < 2; ++i)
        #pragma unroll
        for (int j = 0; j < 2; ++j) {
            acc[i][j][0] = 0.f; acc[i][j][1] = 0.f;
            acc[i][j][2] = 0.f; acc[i][j][3] = 0.f;
        }

    for (int k0 = 0; k0 < 256; k0 += 32) {
        const unsigned short* Ap = xswb + ((size_t)(r0 + srow) * 8 + h) * 256 + k0 + skc;
        *(uint4*)&As[srow][skc]     = *(const uint4*)Ap;
        *(uint4*)&As[srow][skc + 8] = *(const uint4*)(Ap + 8);
        if (tid < 64) {
            int o = tid & 31, seg = (tid >> 5) * 16;
            const unsigned short* Wp = wvb + (size_t)(h * 32 + o) * 256 + k0 + seg;
            *(uint4*)&Bs[o][seg]     = *(const uint4*)Wp;
            *(uint4*)&Bs[o][seg + 8] = *(const uint4*)(Wp + 8);
        }
        __syncthreads();
        bf16x8 a2[2], b2[2];
        #pragma unroll
        for (int i = 0; i < 2; ++i) a2[i] = *(const bf16x8*)&As[wid * 32 + i * 16 + lrow][q * 8];
        #pragma unroll
        for (int j = 0; j < 2; ++j) b2[j] = *(const bf16x8*)&Bs[j * 16 + lrow][q * 8];
        #pragma unroll
        for (int i = 0; i < 2; ++i)
            #pragma unroll
            for (int j = 0; j < 2; ++j)
                acc[i][j] = __builtin_amdgcn_mfma_f32_16x16x32_bf16(a2[i], b2[j], acc[i][j], 0, 0, 0);
        __syncthreads();
    }

    #pragma unroll
    for (int i = 0; i < 2; ++i) {
        int rr = r0 + wid * 32 + i * 16 + q * 4;
        #pragma unroll
        for (int j = 0; j < 2; ++j) {
            int oo = h * 32 + j * 16 + lrow;
            float bvv = bv[oo];
            #pragma unroll
            for (int g2 = 0; g2 < 4; ++g2)
                outb[(size_t)(rr + g2) * 256 + oo] = f2bf(acc[i][j][g2] + bvv);
        }
    }
}

// pred_loc = l2 @ Wl3^T + bl3  (Cout=2), l2 in bf16
__global__ __launch_bounds__(256) void loc_kernel(
    const unsigned short* __restrict__ l2, const float* __restrict__ Wl3,
    const float* __restrict__ bl3, float* __restrict__ o_loc)
{
    int f = blockIdx.x * 256 + threadIdx.x;
    int r = f >> 1, o = f & 1;
    const unsigned short* row = l2 + (size_t)r * 256;
    const float* wr = Wl3 + (size_t)o * 256;
    float sum = bl3[o];
    for (int c = 0; c < 256; c += 8) {
        uint4 u = *(const uint4*)&row[c];
        const unsigned short* us = (const unsigned short*)&u;
        float4 w0 = *(const float4*)&wr[c];
        float4 w1 = *(const float4*)&wr[c + 4];
        sum += bf2f(us[0]) * w0.x + bf2f(us[1]) * w0.y + bf2f(us[2]) * w0.z + bf2f(us[3]) * w0.w;
        sum += bf2f(us[4]) * w1.x + bf2f(us[5]) * w1.y + bf2f(us[6]) * w1.z + bf2f(us[7]) * w1.w;
    }
    o_loc[f] = sum;
}

__global__ __launch_bounds__(256) void loss_loc_partial(
    const float* __restrict__ pred, const float* __restrict__ coords,
    float* __restrict__ partial)
{
    int tid = threadIdx.x;
    float sum = 0.0f;
    for (int e = blockIdx.x * 256 + tid; e < 32768; e += 65536)
        sum += fabsf(pred[e] - coords[e]);
    __shared__ float red[256];
    red[tid] = sum;
    __syncthreads();
    for (int w = 128; w > 0; w >>= 1) {
        if (tid < w) red[tid] += red[tid + w];
        __syncthreads();
    }
    if (tid == 0) partial[blockIdx.x] = red[0];
}

__global__ __launch_bounds__(256) void loss_final(
    const float* __restrict__ part, float* __restrict__ out)
{
    __shared__ float red[256];
    int t = threadIdx.x;
    red[t] = part[t];
    __syncthreads();
    for (int w = 128; w > 0; w >>= 1) {
        if (t < w) red[t] += red[t + w];
        __syncthreads();
    }
    if (t == 0) out[0] = red[0] * (1.0f / 4194304.0f);
    __syncthreads();
    red[t] = part[256 + t];
    __syncthreads();
    for (int w = 128; w > 0; w >>= 1) {
        if (t < w) red[t] += red[t + w];
        __syncthreads();
    }
    if (t == 0) out[1] = red[0] * (1.0f / 32768.0f);
}

extern "C" void kernel_launch(void* const* d_in, const int* in_sizes, int n_in,
                              void* d_out, int out_size, void* d_ws, size_t ws_size,
                              hipStream_t stream) {
    const float* x     = (const float*)d_in[0];
    const int*   idx   = (const int*)d_in[1];
    const int*   labels= (const int*)d_in[2];
    const float* coords= (const float*)d_in[3];
    const float* W_ip  = (const float*)d_in[4];
    const float* b_ip  = (const float*)d_in[5];
    const float* Wq    = (const float*)d_in[6];
    const float* bq    = (const float*)d_in[7];
    const float* Wk    = (const float*)d_in[8];
    const float* bk    = (const float*)d_in[9];
    const float* Wv    = (const float*)d_in[10];
    const float* bv    = (const float*)d_in[11];
    const float* W_dw  = (const float*)d_in[12];
    const float* b_dw  = (const float*)d_in[13];
    const float* W_pw  = (const float*)d_in[14];
    const float* Wc1   = (const float*)d_in[15];
    const float* bc1   = (const float*)d_in[16];
    const float* Wc2   = (const float*)d_in[17];
    const float* bc2   = (const float*)d_in[18];
    const float* Wc3   = (const float*)d_in[19];
    const float* bc3   = (const float*)d_in[20];
    const float* Wl1   = (const float*)d_in[21];
    const float* bl1   = (const float*)d_in[22];
    const float* Wl2   = (const float*)d_in[23];
    const float* bl2   = (const float*)d_in[24];
    const float* Wl3   = (const float*)d_in[25];
    const float* bl3   = (const float*)d_in[26];

    float* out = (float*)d_out;
    float* ws  = (float*)d_ws;

    // workspace (f32 units), total ~24.6M = 98.5 MB.
    unsigned short* xt   = (unsigned short*)ws;                       // [0, 8.4M)
    unsigned short* x1t  = (unsigned short*)(ws + 8388608);           // [8.4M, 12.6M)
    unsigned short* qk3  = (unsigned short*)ws;                       // [0, 16.8M) over dead xt/x1t
    unsigned short* qft  = (unsigned short*)(ws + 16777216);          // [16.8M, 21.0M)
    unsigned short* h1   = (unsigned short*)ws;                       // [0, 4.2M) over dead qk3
    unsigned short* h2c  = (unsigned short*)(ws + 4194304);
    unsigned short* h2l  = (unsigned short*)(ws + 6291456);
    float*          posb = ws + 20971520;                             // [21.0M, 22.15M) (later attf)
    float*          attf = ws + 20971520;
    unsigned short* wktb = (unsigned short*)(ws + 22151168);          // 65536 bf16
    unsigned short* wb   = (unsigned short*)(ws + 22183936);          // 8x65536 bf16
    float*          b512 = ws + 22446080;
    float*          part = ws + 22446592;                             // 512
    unsigned short* outb = (unsigned short*)(ws + 22447104);          // 16384x256 bf16

    unsigned short* wipb = wb;
    unsigned short* wqb  = wb + 65536;
    unsigned short* wc1b = wb + 131072;   // wl1 adjacent -> merged 512-row weight
    unsigned short* wl1b = wb + 196608;
    unsigned short* wc2b = wb + 262144;
    unsigned short* wl2b = wb + 327680;
    unsigned short* wc3b = wb + 393216;
    unsigned short* wvb  = wb + 458752;
    (void)wl1b;

    float* o_xs   = out + 2;
    float* o_cls  = out + 37748738;
    float* o_loc  = out + 41943042;
    float* o_attn = out + 41975810;

    // 0. weight casts + Wk^T + merged bias
    WC wc;
    wc.s[0] = W_ip; wc.d[0] = wipb;
    wc.s[1] = Wq;   wc.d[1] = wqb;
    wc.s[2] = Wc1;  wc.d[2] = wc1b;
    wc.s[3] = Wl1;  wc.d[3] = wl1b;
    wc.s[4] = Wc2;  wc.d[4] = wc2b;
    wc.s[5] = Wl2;  wc.d[5] = wl2b;
    wc.s[6] = Wc3;  wc.d[6] = wc3b;
    wc.s[7] = Wv;   wc.d[7] = wvb;
    wcast_kernel<<<dim3(64, 8), 256, 0, stream>>>(wc);
    wtrans_kernel<<<dim3(4, 4), 256, 0, stream>>>(Wk, wktb);
    biascat_kernel<<<1, 512, 0, stream>>>(bc1, bl1, b512);
    // 0b. x -> xt (b,p,c) bf16
    xtk_kernel<<<dim3(64, 4, 8), 256, 0, stream>>>(x, xt);
    // 1. x1t = gelu(xt @ W_ip^T + b_ip)
    mfma_gemm<1, false, true><<<dim3(256, 2), 256, 0, stream>>>(xt, 256, wipb, b_ip, x1t, 256);
    // 2. qft = x1t @ Wq^T + bq
    mfma_gemm<0, false, true><<<dim3(256, 2), 256, 0, stream>>>(x1t, 256, wqb, bq, qft, 256);
    // 3. positions (tiled fused dwconv + pointwise + tanh)
    posk2_kernel<<<dim3(32, 32), 256, 0, stream>>>(qft, idx, W_dw, b_dw, W_pw, posb);
    // 4. bilinear sample (ushort4 gathers) -> x_sampled (output)
    sample4_kernel<<<dim3(32, 36, 8), 256, 0, stream>>>(x1t, posb, o_xs);
    // 5. qk (MFMA, inline q-gather) -> qk3 (b,n,h,c)
    qk_mfma_kernel<<<dim3(16, 2, 64), 256, 0, stream>>>(wktb, qft, idx, qk3);
    // 6. fused scores + softmax + xsw (v8 proven structure, in-place)
    scorexsw8_kernel<<<dim3(256, 8), 256, 0, stream>>>(qk3, o_xs, attf);
    // 7. attn mean
    attn_reduce_kernel<<<72, 256, 0, stream>>>(attf, o_attn);
    // 8. out = Wv @ xsw + bv -> outb BF16 (B*NS, 256)  [MFMA]
    outv_mfma_kernel<<<dim3(128, 8), 256, 0, stream>>>(qk3, wvb, bv, outb);
    // 9. merged MLP layer 1 (cls||loc) -> h1 (16384 x 512)  [bf16 A]
    mfma_gemm<2, false, true><<<dim3(128, 4), 256, 0, stream>>>(outb, 256, wc1b, b512, h1, 512);
    // 10-11. layer 2
    mfma_gemm<2, false, true><<<dim3(128, 2), 256, 0, stream>>>(h1, 512, wc2b, bc2, h2c, 256);
    mfma_gemm<2, false, true><<<dim3(128, 2), 256, 0, stream>>>(h1 + 256, 512, wl2b, bl2, h2l, 256);
    // 12. cls layer 3 -> o_cls with FUSED loss partial -> part[0..255]
    mfma_gemm_cls<<<dim3(128, 2), 256, 0, stream>>>(h2c, wc3b, bc3, o_cls, labels, part);
    // 13. loc layer 3
    loc_kernel<<<128, 256, 0, stream>>>(h2l, Wl3, bl3, o_loc);
    // 14-15. losses (cls partial already fused into GEMM)
    loss_loc_partial<<<256, 256, 0, stream>>>(o_loc, coords, part + 256);
    loss_final<<<1, 256, 0, stream>>>(part, out);
}

// Round 17
// 374.895 us; speedup vs baseline: 1.1896x; 1.0777x over previous
//
#include <hip/hip_runtime.h>
#include <hip/hip_bf16.h>

#define SCALE_ 0.17677669529663687f  // 32^-0.5

typedef __attribute__((ext_vector_type(4))) float f32x4;
typedef __attribute__((ext_vector_type(8))) short bf16x8;

__device__ __forceinline__ float gelu_f(float v) {
    return 0.5f * v * (1.0f + erff(v * 0.70710678118654752f));
}

__device__ __forceinline__ unsigned short f2bf(float f) {
    __hip_bfloat16 hb = __float2bfloat16(f);
    return *reinterpret_cast<unsigned short*>(&hb);
}
__device__ __forceinline__ float bf2f(unsigned short u) {
    unsigned int ui = ((unsigned int)u) << 16;
    float f;
    __builtin_memcpy(&f, &ui, 4);
    return f;
}

// ---------------------------------------------------------------------------
// Weight cast f32 -> bf16 (8 matrices of 256x256, incl. Wv)
// ---------------------------------------------------------------------------
struct WC {
    const float* s[8];
    unsigned short* d[8];
};

__global__ __launch_bounds__(256) void wcast_kernel(WC wc) {
    int m = blockIdx.y;
    int e = blockIdx.x * 1024 + threadIdx.x * 4;
    const float4 v = *(const float4*)(wc.s[m] + e);
    ushort4 o;
    o.x = f2bf(v.x); o.y = f2bf(v.y); o.z = f2bf(v.z); o.w = f2bf(v.w);
    *(ushort4*)(wc.d[m] + e) = o;
}

// Wk (256x256) -> Wk^T bf16
__global__ __launch_bounds__(256) void wtrans_kernel(
    const float* __restrict__ Wk, unsigned short* __restrict__ wktb)
{
    int o0 = blockIdx.x * 64, c0 = blockIdx.y * 64;
    __shared__ float sm[64][65];
    int tid = threadIdx.x;
    #pragma unroll
    for (int rep = 0; rep < 16; ++rep) {
        int oo = (tid >> 6) + rep * 4, cc = tid & 63;
        sm[oo][cc] = Wk[(size_t)(o0 + oo) * 256 + c0 + cc];
    }
    __syncthreads();
    #pragma unroll
    for (int rep = 0; rep < 16; ++rep) {
        int cc = (tid >> 6) + rep * 4, oo = tid & 63;
        wktb[(size_t)(c0 + cc) * 256 + o0 + oo] = f2bf(sm[oo][cc]);
    }
}

__global__ __launch_bounds__(512) void biascat_kernel(
    const float* __restrict__ bc1, const float* __restrict__ bl1,
    float* __restrict__ bias512)
{
    int t = threadIdx.x;
    bias512[t] = (t < 256) ? bc1[t] : bl1[t - 256];
}

// ---------------------------------------------------------------------------
// x (b, c, p) f32  ->  xt (b, p, c) bf16
// ---------------------------------------------------------------------------
__global__ __launch_bounds__(256) void xtk_kernel(
    const float* __restrict__ x, unsigned short* __restrict__ xt)
{
    int b = blockIdx.z;
    int c0 = blockIdx.y * 64;
    int p0 = blockIdx.x * 64;
    __shared__ float sm[64][65];
    int tid = threadIdx.x;
    #pragma unroll
    for (int rep = 0; rep < 16; ++rep) {
        int cc = (tid >> 6) + rep * 4, pp = tid & 63;
        sm[cc][pp] = x[(((size_t)(b * 256 + c0 + cc)) << 12) + p0 + pp];
    }
    __syncthreads();
    #pragma unroll
    for (int rep = 0; rep < 16; ++rep) {
        int pp = (tid >> 6) + rep * 4, cc = tid & 63;
        xt[((size_t)(b * 4096 + p0 + pp)) * 256 + c0 + cc] = f2bf(sm[cc][pp]);
    }
}

// ---------------------------------------------------------------------------
// MFMA GEMM: Y[r, o] = act(sum_k A[r,k] * W[o,k] + bias[o]), K = 256 fixed.
// ---------------------------------------------------------------------------
template<int ACT, bool ASRC_F32, bool OUT_BF16>
__global__ __launch_bounds__(256) void mfma_gemm(
    const void* __restrict__ Av, int lda,
    const unsigned short* __restrict__ Wb,
    const float* __restrict__ bias, void* __restrict__ Yv, int ldy)
{
    int r0 = blockIdx.x * 128;
    int o0 = blockIdx.y * 128;
    __shared__ unsigned short As[128][40];
    __shared__ unsigned short Bs[128][40];
    int tid = threadIdx.x;
    int lane = tid & 63;
    int wid = tid >> 6;
    int wr = (wid >> 1) * 64, wc = (wid & 1) * 64;
    int lrow = lane & 15, q = lane >> 4;
    f32x4 acc[4][4];
    #pragma unroll
    for (int i = 0; i < 4; ++i)
        #pragma unroll
        for (int j = 0; j < 4; ++j) {
            acc[i][j][0] = 0.f; acc[i][j][1] = 0.f;
            acc[i][j][2] = 0.f; acc[i][j][3] = 0.f;
        }

    int srow = tid & 127;
    int skc = (tid >> 7) * 16;

    for (int k0 = 0; k0 < 256; k0 += 32) {
        if constexpr (ASRC_F32) {
            const float* Ap = (const float*)Av + (size_t)(r0 + srow) * lda + k0 + skc;
            unsigned short tmp[16];
            #pragma unroll
            for (int t = 0; t < 16; ++t) tmp[t] = f2bf(Ap[t]);
            *(uint4*)&As[srow][skc]     = *(uint4*)&tmp[0];
            *(uint4*)&As[srow][skc + 8] = *(uint4*)&tmp[8];
        } else {
            const unsigned short* Ap = (const unsigned short*)Av + (size_t)(r0 + srow) * lda + k0 + skc;
            *(uint4*)&As[srow][skc]     = *(const uint4*)Ap;
            *(uint4*)&As[srow][skc + 8] = *(const uint4*)(Ap + 8);
        }
        const unsigned short* Wp = Wb + (size_t)(o0 + srow) * 256 + k0 + skc;
        *(uint4*)&Bs[srow][skc]     = *(const uint4*)Wp;
        *(uint4*)&Bs[srow][skc + 8] = *(const uint4*)(Wp + 8);
        __syncthreads();
        bf16x8 a[4], bv[4];
        #pragma unroll
        for (int i = 0; i < 4; ++i) a[i] = *(const bf16x8*)&As[wr + i * 16 + lrow][q * 8];
        #pragma unroll
        for (int j = 0; j < 4; ++j) bv[j] = *(const bf16x8*)&Bs[wc + j * 16 + lrow][q * 8];
        #pragma unroll
        for (int i = 0; i < 4; ++i)
            #pragma unroll
            for (int j = 0; j < 4; ++j)
                acc[i][j] = __builtin_amdgcn_mfma_f32_16x16x32_bf16(a[i], bv[j], acc[i][j], 0, 0, 0);
        __syncthreads();
    }

    #pragma unroll
    for (int i = 0; i < 4; ++i) {
        int rr = r0 + wr + i * 16 + q * 4;
        #pragma unroll
        for (int j = 0; j < 4; ++j) {
            int oo = o0 + wc + j * 16 + lrow;
            float bb = bias[oo];
            #pragma unroll
            for (int g2 = 0; g2 < 4; ++g2) {
                float v = acc[i][j][g2] + bb;
                if constexpr (ACT == 1) v = gelu_f(v);
                else if constexpr (ACT == 2) v = fmaxf(v, 0.0f);
                if constexpr (OUT_BF16)
                    ((unsigned short*)Yv)[(size_t)(rr + g2) * ldy + oo] = f2bf(v);
                else
                    ((float*)Yv)[(size_t)(rr + g2) * ldy + oo] = v;
            }
        }
    }
}

// ---------------------------------------------------------------------------
// cls layer-3 GEMM with FUSED BCE-loss partial.
// grid (128, 2), block 256.
// ---------------------------------------------------------------------------
__global__ __launch_bounds__(256) void mfma_gemm_cls(
    const unsigned short* __restrict__ Ab,
    const unsigned short* __restrict__ Wb,
    const float* __restrict__ bias, float* __restrict__ Y,
    const int* __restrict__ labels, float* __restrict__ part)
{
    int r0 = blockIdx.x * 128;
    int o0 = blockIdx.y * 128;
    __shared__ unsigned short As[128][40];
    __shared__ unsigned short Bs[128][40];
    __shared__ float red[256];
    int tid = threadIdx.x;
    int lane = tid & 63;
    int wid = tid >> 6;
    int wr = (wid >> 1) * 64, wc = (wid & 1) * 64;
    int lrow = lane & 15, q = lane >> 4;
    f32x4 acc[4][4];
    #pragma unroll
    for (int i = 0; i < 4; ++i)
        #pragma unroll
        for (int j = 0; j < 4; ++j) {
            acc[i][j][0] = 0.f; acc[i][j][1] = 0.f;
            acc[i][j][2] = 0.f; acc[i][j][3] = 0.f;
        }

    int srow = tid & 127;
    int skc = (tid >> 7) * 16;

    for (int k0 = 0; k0 < 256; k0 += 32) {
        const unsigned short* Ap = Ab + (size_t)(r0 + srow) * 256 + k0 + skc;
        *(uint4*)&As[srow][skc]     = *(const uint4*)Ap;
        *(uint4*)&As[srow][skc + 8] = *(const uint4*)(Ap + 8);
        const unsigned short* Wp = Wb + (size_t)(o0 + srow) * 256 + k0 + skc;
        *(uint4*)&Bs[srow][skc]     = *(const uint4*)Wp;
        *(uint4*)&Bs[srow][skc + 8] = *(const uint4*)(Wp + 8);
        __syncthreads();
        bf16x8 a[4], bv[4];
        #pragma unroll
        for (int i = 0; i < 4; ++i) a[i] = *(const bf16x8*)&As[wr + i * 16 + lrow][q * 8];
        #pragma unroll
        for (int j = 0; j < 4; ++j) bv[j] = *(const bf16x8*)&Bs[wc + j * 16 + lrow][q * 8];
        #pragma unroll
        for (int i = 0; i < 4; ++i)
            #pragma unroll
            for (int j = 0; j < 4; ++j)
                acc[i][j] = __builtin_amdgcn_mfma_f32_16x16x32_bf16(a[i], bv[j], acc[i][j], 0, 0, 0);
        __syncthreads();
    }

    int lab[4][4];
    #pragma unroll
    for (int i = 0; i < 4; ++i) {
        int rr = r0 + wr + i * 16 + q * 4;
        #pragma unroll
        for (int g2 = 0; g2 < 4; ++g2) lab[i][g2] = labels[rr + g2];
    }

    float lsum = 0.0f;
    #pragma unroll
    for (int i = 0; i < 4; ++i) {
        int rr = r0 + wr + i * 16 + q * 4;
        #pragma unroll
        for (int j = 0; j < 4; ++j) {
            int oo = o0 + wc + j * 16 + lrow;
            float bb = bias[oo];
            #pragma unroll
            for (int g2 = 0; g2 < 4; ++g2) {
                float p = acc[i][j][g2] + bb;
                Y[(size_t)(rr + g2) * 256 + oo] = p;
                float t = (lab[i][g2] == oo) ? 1.0f : 0.0f;
                lsum += fmaxf(p, 0.0f) - p * t + log1pf(expf(-fabsf(p)));
            }
        }
    }
    red[tid] = lsum;
    __syncthreads();
    for (int w = 128; w > 0; w >>= 1) {
        if (tid < w) red[tid] += red[tid + w];
        __syncthreads();
    }
    if (tid == 0) part[blockIdx.y * 128 + blockIdx.x] = red[0];
}

// ---------------------------------------------------------------------------
// posk3: fused dwconv@points + pointwise + tanh; channel-vectorized gathers.
// Phase 1 thread = (cq 16 of 4c, ns 16 of 4n): taps are ushort4 (4 channels)
// -> 4x fewer VMEM issues vs posk2.  h_s flipped to [n][c] (pad 68).
// grid (32 n-tiles, 32 bg), block 256.
// ---------------------------------------------------------------------------
__global__ __launch_bounds__(256) void posk3_kernel(
    const unsigned short* __restrict__ qft, const int* __restrict__ idx,
    const float* __restrict__ W_dw, const float* __restrict__ b_dw,
    const float* __restrict__ W_pw, float* __restrict__ posb)
{
    int bg = blockIdx.y;
    int b = bg >> 2, g = bg & 3;
    int n0 = blockIdx.x * 64;
    __shared__ unsigned short h_s[64][68];   // [n][c]
    __shared__ float wpw_s[20 * 64];         // padded to 20 outputs
    __shared__ float off_s[20][64];
    __shared__ int pny[64], pnx[64];
    int tid = threadIdx.x;

    if (tid < 64) {
        pny[tid] = idx[2 * (n0 + tid)];
        pnx[tid] = idx[2 * (n0 + tid) + 1];
    }
    #pragma unroll
    for (int k = 0; k < 5; ++k) {
        int e = tid + k * 256;
        wpw_s[e] = (e < 1152) ? W_pw[e] : 0.0f;
    }
    __syncthreads();

    int cq = tid & 15, ns = tid >> 4;
    int cb = cq * 4;
    float wdw[4][9];
    #pragma unroll
    for (int cc = 0; cc < 4; ++cc)
        #pragma unroll
        for (int k = 0; k < 9; ++k) wdw[cc][k] = W_dw[(cb + cc) * 9 + k];
    float bdw[4];
    #pragma unroll
    for (int cc = 0; cc < 4; ++cc) bdw[cc] = b_dw[cb + cc];
    const unsigned short* qp4 = qft + (((size_t)b) << 12) * 256 + g * 64 + cb;

    #pragma unroll
    for (int jj = 0; jj < 4; ++jj) {
        int nl = ns * 4 + jj;
        int yn = pny[nl], xn = pnx[nl];
        float acc0 = bdw[0], acc1 = bdw[1], acc2 = bdw[2], acc3 = bdw[3];
        #pragma unroll
        for (int ky = 0; ky < 3; ++ky) {
            int yy = yn + ky - 1;
            if (yy < 0 || yy > 63) continue;
            #pragma unroll
            for (int kx = 0; kx < 3; ++kx) {
                int xx = xn + kx - 1;
                if (xx < 0 || xx > 63) continue;
                ushort4 u = *(const ushort4*)(qp4 + (size_t)(yy * 64 + xx) * 256);
                int k = ky * 3 + kx;
                acc0 += wdw[0][k] * bf2f(u.x);
                acc1 += wdw[1][k] * bf2f(u.y);
                acc2 += wdw[2][k] * bf2f(u.z);
                acc3 += wdw[3][k] * bf2f(u.w);
            }
        }
        ushort4 hv;
        hv.x = f2bf(gelu_f(acc0)); hv.y = f2bf(gelu_f(acc1));
        hv.z = f2bf(gelu_f(acc2)); hv.w = f2bf(gelu_f(acc3));
        *(ushort4*)&h_s[nl][cb] = hv;
    }
    __syncthreads();

    // phase 2: off[o][n] = sum_c wpw[o][c] * h[n][c]
    {
        int n = tid & 63, og = tid >> 6;
        int obase = og * 5;
        float acc[5] = {};
        for (int cc = 0; cc < 64; ++cc) {
            float hval = bf2f(h_s[n][cc]);
            #pragma unroll
            for (int j = 0; j < 5; ++j)
                acc[j] += wpw_s[(obase + j) * 64 + cc] * hval;
        }
        #pragma unroll
        for (int j = 0; j < 5; ++j) off_s[obase + j][n] = acc[j];
    }
    __syncthreads();

    // phase 3: tanh + clamp + write positions
    for (int e = tid; e < 576; e += 256) {
        int km = e / 64, n2 = e & 63;
        int yn = pny[n2], xn = pnx[n2];
        int ky = km / 3, kx = km % 3;
        int yc = yn + ky - 1; yc = yc < 0 ? 0 : (yc > 63 ? 63 : yc);
        int xc = xn + kx - 1; xc = xc < 0 ? 0 : (xc > 63 ? 63 : xc);
        float py = tanhf(off_s[2 * km][n2])     * 0.03125f + ((yc + 0.5f) * 0.03125f - 1.0f);
        float px = tanhf(off_s[2 * km + 1][n2]) * 0.03125f + ((xc + 0.5f) * 0.03125f - 1.0f);
        size_t pb = (((size_t)bg * 9 + km) * 2048 + n0 + n2) * 2;
        posb[pb] = py;
        posb[pb + 1] = px;
    }
}

// ---------------------------------------------------------------------------
// Bilinear sample v5: ushort8 gathers (8 channels/lane) -> 2x fewer VMEM ops
// vs v4.  Thread = (c8 of 8 channels, ns of 2 n).
// grid (32 n-tiles, 36 = g*9+km, 8 b), block 256.
// ---------------------------------------------------------------------------
__global__ __launch_bounds__(256, 4) void sample5_kernel(
    const unsigned short* __restrict__ x1t, const float* __restrict__ posb,
    float* __restrict__ o_xs)
{
    int b = blockIdx.z;
    int g = blockIdx.y / 9, km = blockIdx.y % 9;
    int n0 = blockIdx.x * 64;
    int tid = threadIdx.x;
    int c8 = tid & 7;         // 8 channels each: c = c8*8 .. +7
    int ns = tid >> 3;        // 32 n-slots x 2 consecutive n each
    int bg = b * 4 + g;
    __shared__ float sm[64][68];
    const unsigned short* img8 = x1t + (((size_t)b) << 12) * 256 + g * 64 + c8 * 8;
    size_t pb = (((size_t)bg * 9 + km) * 2048 + n0 + ns * 2) * 2;
    float4 P = *(const float4*)&posb[pb];   // (y0,x0,y1,x1)
    float py[2] = {P.x, P.z};
    float px[2] = {P.y, P.w};
    #pragma unroll
    for (int j = 0; j < 2; ++j) {
        float iy = (py[j] + 1.0f) * 31.5f;
        float ix = (px[j] + 1.0f) * 31.5f;
        float y0f = floorf(iy), x0f = floorf(ix);
        float wy = iy - y0f, wx = ix - x0f;
        int yy = (int)y0f, xx = (int)x0f;
        float w00 = (1.0f - wx) * (1.0f - wy), w01 = wx * (1.0f - wy);
        float w10 = (1.0f - wx) * wy,          w11 = wx * wy;
        bool vy0 = (yy >= 0) & (yy <= 63), vy1 = (yy >= -1) & (yy <= 62);
        bool vx0 = (xx >= 0) & (xx <= 63), vx1 = (xx >= -1) & (xx <= 62);
        if (!vy0) { w00 = 0.f; w01 = 0.f; }
        if (!vy1) { w10 = 0.f; w11 = 0.f; }
        if (!vx0) { w00 = 0.f; w10 = 0.f; }
        if (!vx1) { w01 = 0.f; w11 = 0.f; }
        int yc0 = yy < 0 ? 0 : (yy > 63 ? 63 : yy);
        int yc1 = yy + 1 < 0 ? 0 : (yy + 1 > 63 ? 63 : yy + 1);
        int xc0 = xx < 0 ? 0 : (xx > 63 ? 63 : xx);
        int xc1 = xx + 1 < 0 ? 0 : (xx + 1 > 63 ? 63 : xx + 1);
        uint4 u00 = *(const uint4*)(img8 + (size_t)(yc0 * 64 + xc0) * 256);
        uint4 u01 = *(const uint4*)(img8 + (size_t)(yc0 * 64 + xc1) * 256);
        uint4 u10 = *(const uint4*)(img8 + (size_t)(yc1 * 64 + xc0) * 256);
        uint4 u11 = *(const uint4*)(img8 + (size_t)(yc1 * 64 + xc1) * 256);
        const unsigned short* s00 = (const unsigned short*)&u00;
        const unsigned short* s01 = (const unsigned short*)&u01;
        const unsigned short* s10 = (const unsigned short*)&u10;
        const unsigned short* s11 = (const unsigned short*)&u11;
        f32x4 oA, oB;
        #pragma unroll
        for (int e = 0; e < 4; ++e)
            oA[e] = w00 * bf2f(s00[e]) + w01 * bf2f(s01[e])
                  + w10 * bf2f(s10[e]) + w11 * bf2f(s11[e]);
        #pragma unroll
        for (int e = 0; e < 4; ++e)
            oB[e] = w00 * bf2f(s00[e + 4]) + w01 * bf2f(s01[e + 4])
                  + w10 * bf2f(s10[e + 4]) + w11 * bf2f(s11[e + 4]);
        *(f32x4*)&sm[ns * 2 + j][c8 * 8]     = oA;
        *(f32x4*)&sm[ns * 2 + j][c8 * 8 + 4] = oB;
    }
    __syncthreads();
    size_t obase = ((((size_t)(b * 256 + g * 64)) * 9 + km) << 11) + n0;
    int nn = tid & 63;
    #pragma unroll
    for (int rep = 0; rep < 4; ++rep) {
        int cc4 = (tid >> 6) + rep * 4;
        float4 v4 = *(const float4*)&sm[nn][cc4 * 4];
        o_xs[obase + (size_t)(cc4 * 4 + 0) * 18432 + nn] = v4.x;
        o_xs[obase + (size_t)(cc4 * 4 + 1) * 18432 + nn] = v4.y;
        o_xs[obase + (size_t)(cc4 * 4 + 2) * 18432 + nn] = v4.z;
        o_xs[obase + (size_t)(cc4 * 4 + 3) * 18432 + nn] = v4.w;
    }
}

// ---------------------------------------------------------------------------
// qk3[((b*2048+n)*8+h)*256 + c] = sum_j Wk[h*32+j, c] * q[b, h*32+j, n]
// MFMA K=32 with inline q-row gather (qft + idx), flat (b,n,h,c) layout.
// grid (16 n-tiles, 2 c-tiles, 64 bh)
// ---------------------------------------------------------------------------
__global__ __launch_bounds__(256) void qk_mfma_kernel(
    const unsigned short* __restrict__ wktb, const unsigned short* __restrict__ qft,
    const int* __restrict__ idx, unsigned short* __restrict__ qk3)
{
    int bh = blockIdx.z, b = bh >> 3, h = bh & 7;
    int c0 = blockIdx.y * 128;
    int n0 = blockIdx.x * 128;
    __shared__ unsigned short As[128][40];
    __shared__ unsigned short Bs[128][40];
    __shared__ int pn[128];
    int tid = threadIdx.x, lane = tid & 63, wid = tid >> 6;
    int wr = (wid >> 1) * 64, wc = (wid & 1) * 64;
    int lrow = lane & 15, qd = lane >> 4;
    int srow = tid & 127, skc = (tid >> 7) * 16;
    if (tid < 128) pn[tid] = idx[2 * (n0 + tid)] * 64 + idx[2 * (n0 + tid) + 1];
    __syncthreads();
    {
        const unsigned short* Ap = wktb + (size_t)(c0 + srow) * 256 + h * 32 + skc;
        *(uint4*)&As[srow][skc]     = *(const uint4*)Ap;
        *(uint4*)&As[srow][skc + 8] = *(const uint4*)(Ap + 8);
        const unsigned short* Bp = qft + ((size_t)(b * 4096 + pn[srow])) * 256 + h * 32 + skc;
        *(uint4*)&Bs[srow][skc]     = *(const uint4*)Bp;
        *(uint4*)&Bs[srow][skc + 8] = *(const uint4*)(Bp + 8);
    }
    __syncthreads();
    f32x4 acc[4][4];
    #pragma unroll
    for (int i = 0; i < 4; ++i)
        #pragma unroll
        for (int j = 0; j < 4; ++j) {
            acc[i][j][0] = 0.f; acc[i][j][1] = 0.f;
            acc[i][j][2] = 0.f; acc[i][j][3] = 0.f;
        }
    bf16x8 a[4], bv[4];
    #pragma unroll
    for (int i = 0; i < 4; ++i) a[i] = *(const bf16x8*)&As[wr + i * 16 + lrow][qd * 8];
    #pragma unroll
    for (int j = 0; j < 4; ++j) bv[j] = *(const bf16x8*)&Bs[wc + j * 16 + lrow][qd * 8];
    #pragma unroll
    for (int i = 0; i < 4; ++i)
        #pragma unroll
        for (int j = 0; j < 4; ++j)
            acc[i][j] = __builtin_amdgcn_mfma_f32_16x16x32_bf16(a[i], bv[j], acc[i][j], 0, 0, 0);
    #pragma unroll
    for (int i = 0; i < 4; ++i) {
        #pragma unroll
        for (int j = 0; j < 4; ++j) {
            int n = n0 + wc + j * 16 + lrow;
            int c = c0 + wr + i * 16 + qd * 4;
            ushort4 pk;
            pk.x = f2bf(acc[i][j][0]); pk.y = f2bf(acc[i][j][1]);
            pk.z = f2bf(acc[i][j][2]); pk.w = f2bf(acc[i][j][3]);
            *(ushort4*)(qk3 + ((size_t)(b * 2048 + n) * 8 + h) * 256 + c) = pk;
        }
    }
}

// ---------------------------------------------------------------------------
// Fused score+softmax+xsw v8 (measured-best structure), flat qk3 layout.
// grid (256, 8), block 256 = 32 cg x 8 nn.  49.9 KB LDS -> 3 blk/CU.
// ---------------------------------------------------------------------------
__global__ __launch_bounds__(256, 3) void scorexsw8_kernel(
    unsigned short* __restrict__ qk3, const float* __restrict__ xs,
    float* __restrict__ attf)
{
    int b = blockIdx.y;
    int bx = blockIdx.x;
    int nt8 = ((bx & 7) << 5) | (bx >> 3);   // adjacent tiles -> same XCD
    int n0 = nt8 * 8;
    __shared__ unsigned short xs_s[256 * 74];   // [c][km][nn8], stride 74 u16
    __shared__ float sred[4 * 8 * 72];          // [wave][nn][h*9+km]
    __shared__ float a_s[64 * 9];               // [(h*8+nn)][km]
    int tid = threadIdx.x;

    // stage xs tile (f32 global -> bf16 LDS), 18 x float4 per thread
    {
        const float* xsb = xs + (size_t)b * 256 * 18432 + n0;
        #pragma unroll
        for (int k = 0; k < 18; ++k) {
            int li = tid + k * 256;
            int c = li / 18, r = li - c * 18;
            int km = r >> 1, np2 = r & 1;
            float4 v = *(const float4*)(xsb + ((size_t)c * 9 + km) * 2048 + np2 * 4);
            ushort4 o;
            o.x = f2bf(v.x); o.y = f2bf(v.y); o.z = f2bf(v.z); o.w = f2bf(v.w);
            *(ushort4*)&xs_s[c * 74 + km * 8 + np2 * 4] = o;
        }
    }
    __syncthreads();

    int cg = tid >> 3;      // c-group (8 c each), 0..31
    int nn = tid & 7;       // n within 8-tile
    int n = n0 + nn;
    unsigned short* qkp = qk3 + ((size_t)(b * 2048 + n) * 8) * 256 + cg * 8;
    int wv = tid >> 6;
    int sbase = (wv * 8 + nn) * 72;

    // ---- phase A: scores, 2 chunks of 4 heads ----
    #pragma unroll
    for (int hc = 0; hc < 2; ++hc) {
        uint4 qpk[4];
        #pragma unroll
        for (int hh = 0; hh < 4; ++hh)
            qpk[hh] = *(const uint4*)(qkp + (size_t)(hc * 4 + hh) * 256);
        float s[4][9];
        #pragma unroll
        for (int hh = 0; hh < 4; ++hh)
            #pragma unroll
            for (int km = 0; km < 9; ++km) s[hh][km] = 0.0f;
        #pragma unroll
        for (int cl = 0; cl < 8; ++cl) {
            float xv[9];
            const unsigned short* xrow = &xs_s[(cg * 8 + cl) * 74 + nn];
            #pragma unroll
            for (int km = 0; km < 9; ++km) xv[km] = bf2f(xrow[km * 8]);
            #pragma unroll
            for (int hh = 0; hh < 4; ++hh) {
                float qv = bf2f(((const unsigned short*)&qpk[hh])[cl]);
                #pragma unroll
                for (int km = 0; km < 9; ++km) s[hh][km] += qv * xv[km];
            }
        }
        // butterfly over the 8 c-groups within the wave (lane bits 3..5)
        #pragma unroll
        for (int hh = 0; hh < 4; ++hh)
            #pragma unroll
            for (int km = 0; km < 9; ++km) {
                float v = s[hh][km];
                v += __shfl_xor(v, 8);
                v += __shfl_xor(v, 16);
                v += __shfl_xor(v, 32);
                s[hh][km] = v;
            }
        if ((cg & 7) == 0) {
            #pragma unroll
            for (int hh = 0; hh < 4; ++hh)
                #pragma unroll
                for (int km = 0; km < 9; ++km)
                    sred[sbase + (hc * 4 + hh) * 9 + km] = s[hh][km];
        }
    }
    __syncthreads();

    // ---- softmax: 64 threads, one per (h, nn) ----
    if (tid < 64) {
        int h = tid >> 3, nn2 = tid & 7;
        float t[9];
        float m = -1e30f;
        #pragma unroll
        for (int km = 0; km < 9; ++km) {
            t[km] = (sred[(0 * 8 + nn2) * 72 + h * 9 + km]
                   + sred[(1 * 8 + nn2) * 72 + h * 9 + km]
                   + sred[(2 * 8 + nn2) * 72 + h * 9 + km]
                   + sred[(3 * 8 + nn2) * 72 + h * 9 + km]) * SCALE_;
            m = fmaxf(m, t[km]);
        }
        float den = 0.0f;
        #pragma unroll
        for (int km = 0; km < 9; ++km) { t[km] = expf(t[km] - m); den += t[km]; }
        float inv = 1.0f / den;
        size_t ab = (((size_t)(b * 8 + h)) * 2048 + n0 + nn2) * 9;
        #pragma unroll
        for (int km = 0; km < 9; ++km) {
            float av = t[km] * inv;
            attf[ab + km] = av;
            a_s[(h * 8 + nn2) * 9 + km] = av;
        }
    }
    __syncthreads();

    // ---- phase B: xsw in-place, 2 chunks of 4 heads ----
    #pragma unroll
    for (int hc = 0; hc < 2; ++hc) {
        float a[4][9];
        #pragma unroll
        for (int hh = 0; hh < 4; ++hh)
            #pragma unroll
            for (int km = 0; km < 9; ++km)
                a[hh][km] = a_s[((hc * 4 + hh) * 8 + nn) * 9 + km];
        unsigned short ov[4][8];
        #pragma unroll
        for (int cl = 0; cl < 8; ++cl) {
            float xv[9];
            const unsigned short* xrow = &xs_s[(cg * 8 + cl) * 74 + nn];
            #pragma unroll
            for (int km = 0; km < 9; ++km) xv[km] = bf2f(xrow[km * 8]);
            #pragma unroll
            for (int hh = 0; hh < 4; ++hh) {
                float acc = 0.0f;
                #pragma unroll
                for (int km = 0; km < 9; ++km) acc += a[hh][km] * xv[km];
                ov[hh][cl] = f2bf(acc);
            }
        }
        #pragma unroll
        for (int hh = 0; hh < 4; ++hh)
            *(uint4*)(qkp + (size_t)(hc * 4 + hh) * 256) = *(const uint4*)&ov[hh][0];
    }
}

// attn.mean(0) -> (NS, KM), deterministic
__global__ __launch_bounds__(256) void attn_reduce_kernel(
    const float* __restrict__ attf, float* __restrict__ o_attn)
{
    int e = blockIdx.x * 256 + threadIdx.x;
    int n = e / 9, km = e % 9;
    float sum = 0.0f;
    for (int bh = 0; bh < 64; ++bh)
        sum += attf[(((size_t)bh << 11) + n) * 9 + km];
    o_attn[e] = sum * (1.0f / 64.0f);
}

// ---------------------------------------------------------------------------
// outv via MFMA -> outb bf16 (r, 256)
// grid (128 row-tiles, 8 h), block 256.
// ---------------------------------------------------------------------------
__global__ __launch_bounds__(256) void outv_mfma_kernel(
    const unsigned short* __restrict__ xswb, const unsigned short* __restrict__ wvb,
    const float* __restrict__ bv, unsigned short* __restrict__ outb)
{
    int h = blockIdx.y;
    int r0 = blockIdx.x * 128;
    __shared__ unsigned short As[128][40];
    __shared__ unsigned short Bs[32][40];
    int tid = threadIdx.x, lane = tid & 63, wid = tid >> 6;
    int lrow = lane & 15, q = lane >> 4;
    int srow = tid & 127, skc = (tid >> 7) * 16;
    f32x4 acc[2][2];
    #pragma unroll
    for (int i = 0; i < 2; ++i)
        #pragma unroll
        for (int j = 0; j < 2; ++j) {
            acc[i][j][0] = 0.f; acc[i][j][1] = 0.f;
            acc[i][j][2] = 0.f; acc[i][j][3] = 0.f;
        }

    for (int k0 = 0; k0 < 256; k0 += 32) {
        const unsigned short* Ap = xswb + ((size_t)(r0 + srow) * 8 + h) * 256 + k0 + skc;
        *(uint4*)&As[srow][skc]     = *(const uint4*)Ap;
        *(uint4*)&As[srow][skc + 8] = *(const uint4*)(Ap + 8);
        if (tid < 64) {
            int o = tid & 31, seg = (tid >> 5) * 16;
            const unsigned short* Wp = wvb + (size_t)(h * 32 + o) * 256 + k0 + seg;
            *(uint4*)&Bs[o][seg]     = *(const uint4*)Wp;
            *(uint4*)&Bs[o][seg + 8] = *(const uint4*)(Wp + 8);
        }
        __syncthreads();
        bf16x8 a2[2], b2[2];
        #pragma unroll
        for (int i = 0; i < 2; ++i) a2[i] = *(const bf16x8*)&As[wid * 32 + i * 16 + lrow][q * 8];
        #pragma unroll
        for (int j = 0; j < 2; ++j) b2[j] = *(const bf16x8*)&Bs[j * 16 + lrow][q * 8];
        #pragma unroll
        for (int i = 0; i < 2; ++i)
            #pragma unroll
            for (int j = 0; j < 2; ++j)
                acc[i][j] = __builtin_amdgcn_mfma_f32_16x16x32_bf16(a2[i], b2[j], acc[i][j], 0, 0, 0);
        __syncthreads();
    }

    #pragma unroll
    for (int i = 0; i < 2; ++i) {
        int rr = r0 + wid * 32 + i * 16 + q * 4;
        #pragma unroll
        for (int j = 0; j < 2; ++j) {
            int oo = h * 32 + j * 16 + lrow;
            float bvv = bv[oo];
            #pragma unroll
            for (int g2 = 0; g2 < 4; ++g2)
                outb[(size_t)(rr + g2) * 256 + oo] = f2bf(acc[i][j][g2] + bvv);
        }
    }
}

// pred_loc = l2 @ Wl3^T + bl3  (Cout=2), l2 in bf16
__global__ __launch_bounds__(256) void loc_kernel(
    const unsigned short* __restrict__ l2, const float* __restrict__ Wl3,
    const float* __restrict__ bl3, float* __restrict__ o_loc)
{
    int f = blockIdx.x * 256 + threadIdx.x;
    int r = f >> 1, o = f & 1;
    const unsigned short* row = l2 + (size_t)r * 256;
    const float* wr = Wl3 + (size_t)o * 256;
    float sum = bl3[o];
    for (int c = 0; c < 256; c += 8) {
        uint4 u = *(const uint4*)&row[c];
        const unsigned short* us = (const unsigned short*)&u;
        float4 w0 = *(const float4*)&wr[c];
        float4 w1 = *(const float4*)&wr[c + 4];
        sum += bf2f(us[0]) * w0.x + bf2f(us[1]) * w0.y + bf2f(us[2]) * w0.z + bf2f(us[3]) * w0.w;
        sum += bf2f(us[4]) * w1.x + bf2f(us[5]) * w1.y + bf2f(us[6]) * w1.z + bf2f(us[7]) * w1.w;
    }
    o_loc[f] = sum;
}

__global__ __launch_bounds__(256) void loss_loc_partial(
    const float* __restrict__ pred, const float* __restrict__ coords,
    float* __restrict__ partial)
{
    int tid = threadIdx.x;
    float sum = 0.0f;
    for (int e = blockIdx.x * 256 + tid; e < 32768; e += 65536)
        sum += fabsf(pred[e] - coords[e]);
    __shared__ float red[256];
    red[tid] = sum;
    __syncthreads();
    for (int w = 128; w > 0; w >>= 1) {
        if (tid < w) red[tid] += red[tid + w];
        __syncthreads();
    }
    if (tid == 0) partial[blockIdx.x] = red[0];
}

__global__ __launch_bounds__(256) void loss_final(
    const float* __restrict__ part, float* __restrict__ out)
{
    __shared__ float red[256];
    int t = threadIdx.x;
    red[t] = part[t];
    __syncthreads();
    for (int w = 128; w > 0; w >>= 1) {
        if (t < w) red[t] += red[t + w];
        __syncthreads();
    }
    if (t == 0) out[0] = red[0] * (1.0f / 4194304.0f);
    __syncthreads();
    red[t] = part[256 + t];
    __syncthreads();
    for (int w = 128; w > 0; w >>= 1) {
        if (t < w) red[t] += red[t + w];
        __syncthreads();
    }
    if (t == 0) out[1] = red[0] * (1.0f / 32768.0f);
}

extern "C" void kernel_launch(void* const* d_in, const int* in_sizes, int n_in,
                              void* d_out, int out_size, void* d_ws, size_t ws_size,
                              hipStream_t stream) {
    const float* x     = (const float*)d_in[0];
    const int*   idx   = (const int*)d_in[1];
    const int*   labels= (const int*)d_in[2];
    const float* coords= (const float*)d_in[3];
    const float* W_ip  = (const float*)d_in[4];
    const float* b_ip  = (const float*)d_in[5];
    const float* Wq    = (const float*)d_in[6];
    const float* bq    = (const float*)d_in[7];
    const float* Wk    = (const float*)d_in[8];
    const float* bk    = (const float*)d_in[9];
    const float* Wv    = (const float*)d_in[10];
    const float* bv    = (const float*)d_in[11];
    const float* W_dw  = (const float*)d_in[12];
    const float* b_dw  = (const float*)d_in[13];
    const float* W_pw  = (const float*)d_in[14];
    const float* Wc1   = (const float*)d_in[15];
    const float* bc1   = (const float*)d_in[16];
    const float* Wc2   = (const float*)d_in[17];
    const float* bc2   = (const float*)d_in[18];
    const float* Wc3   = (const float*)d_in[19];
    const float* bc3   = (const float*)d_in[20];
    const float* Wl1   = (const float*)d_in[21];
    const float* bl1   = (const float*)d_in[22];
    const float* Wl2   = (const float*)d_in[23];
    const float* bl2   = (const float*)d_in[24];
    const float* Wl3   = (const float*)d_in[25];
    const float* bl3   = (const float*)d_in[26];

    float* out = (float*)d_out;
    float* ws  = (float*)d_ws;

    // workspace (f32 units), total ~24.6M = 98.5 MB.
    unsigned short* xt   = (unsigned short*)ws;                       // [0, 8.4M)
    unsigned short* x1t  = (unsigned short*)(ws + 8388608);           // [8.4M, 12.6M)
    unsigned short* qk3  = (unsigned short*)ws;                       // [0, 16.8M) over dead xt/x1t
    unsigned short* qft  = (unsigned short*)(ws + 16777216);          // [16.8M, 21.0M)
    unsigned short* h1   = (unsigned short*)ws;                       // [0, 4.2M) over dead qk3
    unsigned short* h2c  = (unsigned short*)(ws + 4194304);
    unsigned short* h2l  = (unsigned short*)(ws + 6291456);
    float*          posb = ws + 20971520;                             // [21.0M, 22.15M) (later attf)
    float*          attf = ws + 20971520;
    unsigned short* wktb = (unsigned short*)(ws + 22151168);          // 65536 bf16
    unsigned short* wb   = (unsigned short*)(ws + 22183936);          // 8x65536 bf16
    float*          b512 = ws + 22446080;
    float*          part = ws + 22446592;                             // 512
    unsigned short* outb = (unsigned short*)(ws + 22447104);          // 16384x256 bf16

    unsigned short* wipb = wb;
    unsigned short* wqb  = wb + 65536;
    unsigned short* wc1b = wb + 131072;   // wl1 adjacent -> merged 512-row weight
    unsigned short* wl1b = wb + 196608;
    unsigned short* wc2b = wb + 262144;
    unsigned short* wl2b = wb + 327680;
    unsigned short* wc3b = wb + 393216;
    unsigned short* wvb  = wb + 458752;
    (void)wl1b;

    float* o_xs   = out + 2;
    float* o_cls  = out + 37748738;
    float* o_loc  = out + 41943042;
    float* o_attn = out + 41975810;

    // 0. weight casts + Wk^T + merged bias
    WC wc;
    wc.s[0] = W_ip; wc.d[0] = wipb;
    wc.s[1] = Wq;   wc.d[1] = wqb;
    wc.s[2] = Wc1;  wc.d[2] = wc1b;
    wc.s[3] = Wl1;  wc.d[3] = wl1b;
    wc.s[4] = Wc2;  wc.d[4] = wc2b;
    wc.s[5] = Wl2;  wc.d[5] = wl2b;
    wc.s[6] = Wc3;  wc.d[6] = wc3b;
    wc.s[7] = Wv;   wc.d[7] = wvb;
    wcast_kernel<<<dim3(64, 8), 256, 0, stream>>>(wc);
    wtrans_kernel<<<dim3(4, 4), 256, 0, stream>>>(Wk, wktb);
    biascat_kernel<<<1, 512, 0, stream>>>(bc1, bl1, b512);
    // 0b. x -> xt (b,p,c) bf16
    xtk_kernel<<<dim3(64, 4, 8), 256, 0, stream>>>(x, xt);
    // 1. x1t = gelu(xt @ W_ip^T + b_ip)
    mfma_gemm<1, false, true><<<dim3(256, 2), 256, 0, stream>>>(xt, 256, wipb, b_ip, x1t, 256);
    // 2. qft = x1t @ Wq^T + bq
    mfma_gemm<0, false, true><<<dim3(256, 2), 256, 0, stream>>>(x1t, 256, wqb, bq, qft, 256);
    // 3. positions (vectorized-gather dwconv + pointwise + tanh)
    posk3_kernel<<<dim3(32, 32), 256, 0, stream>>>(qft, idx, W_dw, b_dw, W_pw, posb);
    // 4. bilinear sample (ushort8 gathers) -> x_sampled (output)
    sample5_kernel<<<dim3(32, 36, 8), 256, 0, stream>>>(x1t, posb, o_xs);
    // 5. qk (MFMA, inline q-gather) -> qk3 (b,n,h,c)
    qk_mfma_kernel<<<dim3(16, 2, 64), 256, 0, stream>>>(wktb, qft, idx, qk3);
    // 6. fused scores + softmax + xsw (v8 proven structure, in-place)
    scorexsw8_kernel<<<dim3(256, 8), 256, 0, stream>>>(qk3, o_xs, attf);
    // 7. attn mean
    attn_reduce_kernel<<<72, 256, 0, stream>>>(attf, o_attn);
    // 8. out = Wv @ xsw + bv -> outb BF16 (B*NS, 256)  [MFMA]
    outv_mfma_kernel<<<dim3(128, 8), 256, 0, stream>>>(qk3, wvb, bv, outb);
    // 9. merged MLP layer 1 (cls||loc) -> h1 (16384 x 512)  [bf16 A]
    mfma_gemm<2, false, true><<<dim3(128, 4), 256, 0, stream>>>(outb, 256, wc1b, b512, h1, 512);
    // 10-11. layer 2
    mfma_gemm<2, false, true><<<dim3(128, 2), 256, 0, stream>>>(h1, 512, wc2b, bc2, h2c, 256);
    mfma_gemm<2, false, true><<<dim3(128, 2), 256, 0, stream>>>(h1 + 256, 512, wl2b, bl2, h2l, 256);
    // 12. cls layer 3 -> o_cls with FUSED loss partial -> part[0..255]
    mfma_gemm_cls<<<dim3(128, 2), 256, 0, stream>>>(h2c, wc3b, bc3, o_cls, labels, part);
    // 13. loc layer 3
    loc_kernel<<<128, 256, 0, stream>>>(h2l, Wl3, bl3, o_loc);
    // 14-15. losses (cls partial already fused into GEMM)
    loss_loc_partial<<<256, 256, 0, stream>>>(o_loc, coords, part + 256);
    loss_final<<<1, 256, 0, stream>>>(part, out);
}

// Round 18
// 373.929 us; speedup vs baseline: 1.1927x; 1.0026x over previous
//
#include <hip/hip_runtime.h>
#include <hip/hip_bf16.h>

#define SCALE_ 0.17677669529663687f  // 32^-0.5

typedef __attribute__((ext_vector_type(4))) float f32x4;
typedef __attribute__((ext_vector_type(8))) short bf16x8;

__device__ __forceinline__ float gelu_f(float v) {
    return 0.5f * v * (1.0f + erff(v * 0.70710678118654752f));
}

__device__ __forceinline__ unsigned short f2bf(float f) {
    __hip_bfloat16 hb = __float2bfloat16(f);
    return *reinterpret_cast<unsigned short*>(&hb);
}
__device__ __forceinline__ float bf2f(unsigned short u) {
    unsigned int ui = ((unsigned int)u) << 16;
    float f;
    __builtin_memcpy(&f, &ui, 4);
    return f;
}

// ---------------------------------------------------------------------------
// Weight cast f32 -> bf16 (8 matrices of 256x256, incl. Wv)
// ---------------------------------------------------------------------------
struct WC {
    const float* s[8];
    unsigned short* d[8];
};

__global__ __launch_bounds__(256) void wcast_kernel(WC wc) {
    int m = blockIdx.y;
    int e = blockIdx.x * 1024 + threadIdx.x * 4;
    const float4 v = *(const float4*)(wc.s[m] + e);
    ushort4 o;
    o.x = f2bf(v.x); o.y = f2bf(v.y); o.z = f2bf(v.z); o.w = f2bf(v.w);
    *(ushort4*)(wc.d[m] + e) = o;
}

// Wk (256x256) -> Wk^T bf16
__global__ __launch_bounds__(256) void wtrans_kernel(
    const float* __restrict__ Wk, unsigned short* __restrict__ wktb)
{
    int o0 = blockIdx.x * 64, c0 = blockIdx.y * 64;
    __shared__ float sm[64][65];
    int tid = threadIdx.x;
    #pragma unroll
    for (int rep = 0; rep < 16; ++rep) {
        int oo = (tid >> 6) + rep * 4, cc = tid & 63;
        sm[oo][cc] = Wk[(size_t)(o0 + oo) * 256 + c0 + cc];
    }
    __syncthreads();
    #pragma unroll
    for (int rep = 0; rep < 16; ++rep) {
        int cc = (tid >> 6) + rep * 4, oo = tid & 63;
        wktb[(size_t)(c0 + cc) * 256 + o0 + oo] = f2bf(sm[oo][cc]);
    }
}

__global__ __launch_bounds__(512) void biascat_kernel(
    const float* __restrict__ bc1, const float* __restrict__ bl1,
    float* __restrict__ bias512)
{
    int t = threadIdx.x;
    bias512[t] = (t < 256) ? bc1[t] : bl1[t - 256];
}

// ---------------------------------------------------------------------------
// x (b, c, p) f32  ->  xt (b, p, c) bf16
// ---------------------------------------------------------------------------
__global__ __launch_bounds__(256) void xtk_kernel(
    const float* __restrict__ x, unsigned short* __restrict__ xt)
{
    int b = blockIdx.z;
    int c0 = blockIdx.y * 64;
    int p0 = blockIdx.x * 64;
    __shared__ float sm[64][65];
    int tid = threadIdx.x;
    #pragma unroll
    for (int rep = 0; rep < 16; ++rep) {
        int cc = (tid >> 6) + rep * 4, pp = tid & 63;
        sm[cc][pp] = x[(((size_t)(b * 256 + c0 + cc)) << 12) + p0 + pp];
    }
    __syncthreads();
    #pragma unroll
    for (int rep = 0; rep < 16; ++rep) {
        int pp = (tid >> 6) + rep * 4, cc = tid & 63;
        xt[((size_t)(b * 4096 + p0 + pp)) * 256 + c0 + cc] = f2bf(sm[cc][pp]);
    }
}

// ---------------------------------------------------------------------------
// MFMA GEMM: Y[r, o] = act(sum_k A[r,k] * W[o,k] + bias[o]), K = 256 fixed.
// ---------------------------------------------------------------------------
template<int ACT, bool ASRC_F32, bool OUT_BF16>
__global__ __launch_bounds__(256) void mfma_gemm(
    const void* __restrict__ Av, int lda,
    const unsigned short* __restrict__ Wb,
    const float* __restrict__ bias, void* __restrict__ Yv, int ldy)
{
    int r0 = blockIdx.x * 128;
    int o0 = blockIdx.y * 128;
    __shared__ unsigned short As[128][40];
    __shared__ unsigned short Bs[128][40];
    int tid = threadIdx.x;
    int lane = tid & 63;
    int wid = tid >> 6;
    int wr = (wid >> 1) * 64, wc = (wid & 1) * 64;
    int lrow = lane & 15, q = lane >> 4;
    f32x4 acc[4][4];
    #pragma unroll
    for (int i = 0; i < 4; ++i)
        #pragma unroll
        for (int j = 0; j < 4; ++j) {
            acc[i][j][0] = 0.f; acc[i][j][1] = 0.f;
            acc[i][j][2] = 0.f; acc[i][j][3] = 0.f;
        }

    int srow = tid & 127;
    int skc = (tid >> 7) * 16;

    for (int k0 = 0; k0 < 256; k0 += 32) {
        if constexpr (ASRC_F32) {
            const float* Ap = (const float*)Av + (size_t)(r0 + srow) * lda + k0 + skc;
            unsigned short tmp[16];
            #pragma unroll
            for (int t = 0; t < 16; ++t) tmp[t] = f2bf(Ap[t]);
            *(uint4*)&As[srow][skc]     = *(uint4*)&tmp[0];
            *(uint4*)&As[srow][skc + 8] = *(uint4*)&tmp[8];
        } else {
            const unsigned short* Ap = (const unsigned short*)Av + (size_t)(r0 + srow) * lda + k0 + skc;
            *(uint4*)&As[srow][skc]     = *(const uint4*)Ap;
            *(uint4*)&As[srow][skc + 8] = *(const uint4*)(Ap + 8);
        }
        const unsigned short* Wp = Wb + (size_t)(o0 + srow) * 256 + k0 + skc;
        *(uint4*)&Bs[srow][skc]     = *(const uint4*)Wp;
        *(uint4*)&Bs[srow][skc + 8] = *(const uint4*)(Wp + 8);
        __syncthreads();
        bf16x8 a[4], bv[4];
        #pragma unroll
        for (int i = 0; i < 4; ++i) a[i] = *(const bf16x8*)&As[wr + i * 16 + lrow][q * 8];
        #pragma unroll
        for (int j = 0; j < 4; ++j) bv[j] = *(const bf16x8*)&Bs[wc + j * 16 + lrow][q * 8];
        #pragma unroll
        for (int i = 0; i < 4; ++i)
            #pragma unroll
            for (int j = 0; j < 4; ++j)
                acc[i][j] = __builtin_amdgcn_mfma_f32_16x16x32_bf16(a[i], bv[j], acc[i][j], 0, 0, 0);
        __syncthreads();
    }

    #pragma unroll
    for (int i = 0; i < 4; ++i) {
        int rr = r0 + wr + i * 16 + q * 4;
        #pragma unroll
        for (int j = 0; j < 4; ++j) {
            int oo = o0 + wc + j * 16 + lrow;
            float bb = bias[oo];
            #pragma unroll
            for (int g2 = 0; g2 < 4; ++g2) {
                float v = acc[i][j][g2] + bb;
                if constexpr (ACT == 1) v = gelu_f(v);
                else if constexpr (ACT == 2) v = fmaxf(v, 0.0f);
                if constexpr (OUT_BF16)
                    ((unsigned short*)Yv)[(size_t)(rr + g2) * ldy + oo] = f2bf(v);
                else
                    ((float*)Yv)[(size_t)(rr + g2) * ldy + oo] = v;
            }
        }
    }
}

// ---------------------------------------------------------------------------
// cls layer-3 GEMM with FUSED BCE-loss partial.
// grid (128, 2), block 256.
// ---------------------------------------------------------------------------
__global__ __launch_bounds__(256) void mfma_gemm_cls(
    const unsigned short* __restrict__ Ab,
    const unsigned short* __restrict__ Wb,
    const float* __restrict__ bias, float* __restrict__ Y,
    const int* __restrict__ labels, float* __restrict__ part)
{
    int r0 = blockIdx.x * 128;
    int o0 = blockIdx.y * 128;
    __shared__ unsigned short As[128][40];
    __shared__ unsigned short Bs[128][40];
    __shared__ float red[256];
    int tid = threadIdx.x;
    int lane = tid & 63;
    int wid = tid >> 6;
    int wr = (wid >> 1) * 64, wc = (wid & 1) * 64;
    int lrow = lane & 15, q = lane >> 4;
    f32x4 acc[4][4];
    #pragma unroll
    for (int i = 0; i < 4; ++i)
        #pragma unroll
        for (int j = 0; j < 4; ++j) {
            acc[i][j][0] = 0.f; acc[i][j][1] = 0.f;
            acc[i][j][2] = 0.f; acc[i][j][3] = 0.f;
        }

    int srow = tid & 127;
    int skc = (tid >> 7) * 16;

    for (int k0 = 0; k0 < 256; k0 += 32) {
        const unsigned short* Ap = Ab + (size_t)(r0 + srow) * 256 + k0 + skc;
        *(uint4*)&As[srow][skc]     = *(const uint4*)Ap;
        *(uint4*)&As[srow][skc + 8] = *(const uint4*)(Ap + 8);
        const unsigned short* Wp = Wb + (size_t)(o0 + srow) * 256 + k0 + skc;
        *(uint4*)&Bs[srow][skc]     = *(const uint4*)Wp;
        *(uint4*)&Bs[srow][skc + 8] = *(const uint4*)(Wp + 8);
        __syncthreads();
        bf16x8 a[4], bv[4];
        #pragma unroll
        for (int i = 0; i < 4; ++i) a[i] = *(const bf16x8*)&As[wr + i * 16 + lrow][q * 8];
        #pragma unroll
        for (int j = 0; j < 4; ++j) bv[j] = *(const bf16x8*)&Bs[wc + j * 16 + lrow][q * 8];
        #pragma unroll
        for (int i = 0; i < 4; ++i)
            #pragma unroll
            for (int j = 0; j < 4; ++j)
                acc[i][j] = __builtin_amdgcn_mfma_f32_16x16x32_bf16(a[i], bv[j], acc[i][j], 0, 0, 0);
        __syncthreads();
    }

    int lab[4][4];
    #pragma unroll
    for (int i = 0; i < 4; ++i) {
        int rr = r0 + wr + i * 16 + q * 4;
        #pragma unroll
        for (int g2 = 0; g2 < 4; ++g2) lab[i][g2] = labels[rr + g2];
    }

    float lsum = 0.0f;
    #pragma unroll
    for (int i = 0; i < 4; ++i) {
        int rr = r0 + wr + i * 16 + q * 4;
        #pragma unroll
        for (int j = 0; j < 4; ++j) {
            int oo = o0 + wc + j * 16 + lrow;
            float bb = bias[oo];
            #pragma unroll
            for (int g2 = 0; g2 < 4; ++g2) {
                float p = acc[i][j][g2] + bb;
                Y[(size_t)(rr + g2) * 256 + oo] = p;
                float t = (lab[i][g2] == oo) ? 1.0f : 0.0f;
                lsum += fmaxf(p, 0.0f) - p * t + log1pf(expf(-fabsf(p)));
            }
        }
    }
    red[tid] = lsum;
    __syncthreads();
    for (int w = 128; w > 0; w >>= 1) {
        if (tid < w) red[tid] += red[tid + w];
        __syncthreads();
    }
    if (tid == 0) part[blockIdx.y * 128 + blockIdx.x] = red[0];
}

// ---------------------------------------------------------------------------
// posk3: fused dwconv@points + pointwise + tanh; channel-vectorized gathers.
// __launch_bounds__(256,6): 19.5 KB LDS, ~70 VGPR -> 6 blocks/CU for
// latency hiding of the ushort4 taps.
// grid (32 n-tiles, 32 bg), block 256.
// ---------------------------------------------------------------------------
__global__ __launch_bounds__(256, 6) void posk3_kernel(
    const unsigned short* __restrict__ qft, const int* __restrict__ idx,
    const float* __restrict__ W_dw, const float* __restrict__ b_dw,
    const float* __restrict__ W_pw, float* __restrict__ posb)
{
    int bg = blockIdx.y;
    int b = bg >> 2, g = bg & 3;
    int n0 = blockIdx.x * 64;
    __shared__ unsigned short h_s[64][68];   // [n][c]
    __shared__ float wpw_s[20 * 64];         // padded to 20 outputs
    __shared__ float off_s[20][64];
    __shared__ int pny[64], pnx[64];
    int tid = threadIdx.x;

    if (tid < 64) {
        pny[tid] = idx[2 * (n0 + tid)];
        pnx[tid] = idx[2 * (n0 + tid) + 1];
    }
    #pragma unroll
    for (int k = 0; k < 5; ++k) {
        int e = tid + k * 256;
        wpw_s[e] = (e < 1152) ? W_pw[e] : 0.0f;
    }
    __syncthreads();

    int cq = tid & 15, ns = tid >> 4;
    int cb = cq * 4;
    float wdw[4][9];
    #pragma unroll
    for (int cc = 0; cc < 4; ++cc)
        #pragma unroll
        for (int k = 0; k < 9; ++k) wdw[cc][k] = W_dw[(cb + cc) * 9 + k];
    float bdw[4];
    #pragma unroll
    for (int cc = 0; cc < 4; ++cc) bdw[cc] = b_dw[cb + cc];
    const unsigned short* qp4 = qft + (((size_t)b) << 12) * 256 + g * 64 + cb;

    #pragma unroll
    for (int jj = 0; jj < 4; ++jj) {
        int nl = ns * 4 + jj;
        int yn = pny[nl], xn = pnx[nl];
        float acc0 = bdw[0], acc1 = bdw[1], acc2 = bdw[2], acc3 = bdw[3];
        #pragma unroll
        for (int ky = 0; ky < 3; ++ky) {
            int yy = yn + ky - 1;
            if (yy < 0 || yy > 63) continue;
            #pragma unroll
            for (int kx = 0; kx < 3; ++kx) {
                int xx = xn + kx - 1;
                if (xx < 0 || xx > 63) continue;
                ushort4 u = *(const ushort4*)(qp4 + (size_t)(yy * 64 + xx) * 256);
                int k = ky * 3 + kx;
                acc0 += wdw[0][k] * bf2f(u.x);
                acc1 += wdw[1][k] * bf2f(u.y);
                acc2 += wdw[2][k] * bf2f(u.z);
                acc3 += wdw[3][k] * bf2f(u.w);
            }
        }
        ushort4 hv;
        hv.x = f2bf(gelu_f(acc0)); hv.y = f2bf(gelu_f(acc1));
        hv.z = f2bf(gelu_f(acc2)); hv.w = f2bf(gelu_f(acc3));
        *(ushort4*)&h_s[nl][cb] = hv;
    }
    __syncthreads();

    // phase 2: off[o][n] = sum_c wpw[o][c] * h[n][c]
    {
        int n = tid & 63, og = tid >> 6;
        int obase = og * 5;
        float acc[5] = {};
        for (int cc = 0; cc < 64; ++cc) {
            float hval = bf2f(h_s[n][cc]);
            #pragma unroll
            for (int j = 0; j < 5; ++j)
                acc[j] += wpw_s[(obase + j) * 64 + cc] * hval;
        }
        #pragma unroll
        for (int j = 0; j < 5; ++j) off_s[obase + j][n] = acc[j];
    }
    __syncthreads();

    // phase 3: tanh + clamp + write positions
    for (int e = tid; e < 576; e += 256) {
        int km = e / 64, n2 = e & 63;
        int yn = pny[n2], xn = pnx[n2];
        int ky = km / 3, kx = km % 3;
        int yc = yn + ky - 1; yc = yc < 0 ? 0 : (yc > 63 ? 63 : yc);
        int xc = xn + kx - 1; xc = xc < 0 ? 0 : (xc > 63 ? 63 : xc);
        float py = tanhf(off_s[2 * km][n2])     * 0.03125f + ((yc + 0.5f) * 0.03125f - 1.0f);
        float px = tanhf(off_s[2 * km + 1][n2]) * 0.03125f + ((xc + 0.5f) * 0.03125f - 1.0f);
        size_t pb = (((size_t)bg * 9 + km) * 2048 + n0 + n2) * 2;
        posb[pb] = py;
        posb[pb + 1] = px;
    }
}

// ---------------------------------------------------------------------------
// Bilinear sample v5: ushort8 gathers; __launch_bounds__(256,6) for 6 blk/CU
// (17.4 KB LDS, ~60 VGPR) -> more waves to hide L2 gather latency.
// grid (32 n-tiles, 36 = g*9+km, 8 b), block 256.
// ---------------------------------------------------------------------------
__global__ __launch_bounds__(256, 6) void sample5_kernel(
    const unsigned short* __restrict__ x1t, const float* __restrict__ posb,
    float* __restrict__ o_xs)
{
    int b = blockIdx.z;
    int g = blockIdx.y / 9, km = blockIdx.y % 9;
    int n0 = blockIdx.x * 64;
    int tid = threadIdx.x;
    int c8 = tid & 7;         // 8 channels each: c = c8*8 .. +7
    int ns = tid >> 3;        // 32 n-slots x 2 consecutive n each
    int bg = b * 4 + g;
    __shared__ float sm[64][68];
    const unsigned short* img8 = x1t + (((size_t)b) << 12) * 256 + g * 64 + c8 * 8;
    size_t pb = (((size_t)bg * 9 + km) * 2048 + n0 + ns * 2) * 2;
    float4 P = *(const float4*)&posb[pb];   // (y0,x0,y1,x1)
    float py[2] = {P.x, P.z};
    float px[2] = {P.y, P.w};
    #pragma unroll
    for (int j = 0; j < 2; ++j) {
        float iy = (py[j] + 1.0f) * 31.5f;
        float ix = (px[j] + 1.0f) * 31.5f;
        float y0f = floorf(iy), x0f = floorf(ix);
        float wy = iy - y0f, wx = ix - x0f;
        int yy = (int)y0f, xx = (int)x0f;
        float w00 = (1.0f - wx) * (1.0f - wy), w01 = wx * (1.0f - wy);
        float w10 = (1.0f - wx) * wy,          w11 = wx * wy;
        bool vy0 = (yy >= 0) & (yy <= 63), vy1 = (yy >= -1) & (yy <= 62);
        bool vx0 = (xx >= 0) & (xx <= 63), vx1 = (xx >= -1) & (xx <= 62);
        if (!vy0) { w00 = 0.f; w01 = 0.f; }
        if (!vy1) { w10 = 0.f; w11 = 0.f; }
        if (!vx0) { w00 = 0.f; w10 = 0.f; }
        if (!vx1) { w01 = 0.f; w11 = 0.f; }
        int yc0 = yy < 0 ? 0 : (yy > 63 ? 63 : yy);
        int yc1 = yy + 1 < 0 ? 0 : (yy + 1 > 63 ? 63 : yy + 1);
        int xc0 = xx < 0 ? 0 : (xx > 63 ? 63 : xx);
        int xc1 = xx + 1 < 0 ? 0 : (xx + 1 > 63 ? 63 : xx + 1);
        uint4 u00 = *(const uint4*)(img8 + (size_t)(yc0 * 64 + xc0) * 256);
        uint4 u01 = *(const uint4*)(img8 + (size_t)(yc0 * 64 + xc1) * 256);
        uint4 u10 = *(const uint4*)(img8 + (size_t)(yc1 * 64 + xc0) * 256);
        uint4 u11 = *(const uint4*)(img8 + (size_t)(yc1 * 64 + xc1) * 256);
        const unsigned short* s00 = (const unsigned short*)&u00;
        const unsigned short* s01 = (const unsigned short*)&u01;
        const unsigned short* s10 = (const unsigned short*)&u10;
        const unsigned short* s11 = (const unsigned short*)&u11;
        f32x4 oA, oB;
        #pragma unroll
        for (int e = 0; e < 4; ++e)
            oA[e] = w00 * bf2f(s00[e]) + w01 * bf2f(s01[e])
                  + w10 * bf2f(s10[e]) + w11 * bf2f(s11[e]);
        #pragma unroll
        for (int e = 0; e < 4; ++e)
            oB[e] = w00 * bf2f(s00[e + 4]) + w01 * bf2f(s01[e + 4])
                  + w10 * bf2f(s10[e + 4]) + w11 * bf2f(s11[e + 4]);
        *(f32x4*)&sm[ns * 2 + j][c8 * 8]     = oA;
        *(f32x4*)&sm[ns * 2 + j][c8 * 8 + 4] = oB;
    }
    __syncthreads();
    size_t obase = ((((size_t)(b * 256 + g * 64)) * 9 + km) << 11) + n0;
    int nn = tid & 63;
    #pragma unroll
    for (int rep = 0; rep < 4; ++rep) {
        int cc4 = (tid >> 6) + rep * 4;
        float4 v4 = *(const float4*)&sm[nn][cc4 * 4];
        o_xs[obase + (size_t)(cc4 * 4 + 0) * 18432 + nn] = v4.x;
        o_xs[obase + (size_t)(cc4 * 4 + 1) * 18432 + nn] = v4.y;
        o_xs[obase + (size_t)(cc4 * 4 + 2) * 18432 + nn] = v4.z;
        o_xs[obase + (size_t)(cc4 * 4 + 3) * 18432 + nn] = v4.w;
    }
}

// ---------------------------------------------------------------------------
// qk3[((b*2048+n)*8+h)*256 + c] = sum_j Wk[h*32+j, c] * q[b, h*32+j, n]
// MFMA K=32 with inline q-row gather (qft + idx), flat (b,n,h,c) layout.
// grid (16 n-tiles, 2 c-tiles, 64 bh)
// ---------------------------------------------------------------------------
__global__ __launch_bounds__(256) void qk_mfma_kernel(
    const unsigned short* __restrict__ wktb, const unsigned short* __restrict__ qft,
    const int* __restrict__ idx, unsigned short* __restrict__ qk3)
{
    int bh = blockIdx.z, b = bh >> 3, h = bh & 7;
    int c0 = blockIdx.y * 128;
    int n0 = blockIdx.x * 128;
    __shared__ unsigned short As[128][40];
    __shared__ unsigned short Bs[128][40];
    __shared__ int pn[128];
    int tid = threadIdx.x, lane = tid & 63, wid = tid >> 6;
    int wr = (wid >> 1) * 64, wc = (wid & 1) * 64;
    int lrow = lane & 15, qd = lane >> 4;
    int srow = tid & 127, skc = (tid >> 7) * 16;
    if (tid < 128) pn[tid] = idx[2 * (n0 + tid)] * 64 + idx[2 * (n0 + tid) + 1];
    __syncthreads();
    {
        const unsigned short* Ap = wktb + (size_t)(c0 + srow) * 256 + h * 32 + skc;
        *(uint4*)&As[srow][skc]     = *(const uint4*)Ap;
        *(uint4*)&As[srow][skc + 8] = *(const uint4*)(Ap + 8);
        const unsigned short* Bp = qft + ((size_t)(b * 4096 + pn[srow])) * 256 + h * 32 + skc;
        *(uint4*)&Bs[srow][skc]     = *(const uint4*)Bp;
        *(uint4*)&Bs[srow][skc + 8] = *(const uint4*)(Bp + 8);
    }
    __syncthreads();
    f32x4 acc[4][4];
    #pragma unroll
    for (int i = 0; i < 4; ++i)
        #pragma unroll
        for (int j = 0; j < 4; ++j) {
            acc[i][j][0] = 0.f; acc[i][j][1] = 0.f;
            acc[i][j][2] = 0.f; acc[i][j][3] = 0.f;
        }
    bf16x8 a[4], bv[4];
    #pragma unroll
    for (int i = 0; i < 4; ++i) a[i] = *(const bf16x8*)&As[wr + i * 16 + lrow][qd * 8];
    #pragma unroll
    for (int j = 0; j < 4; ++j) bv[j] = *(const bf16x8*)&Bs[wc + j * 16 + lrow][qd * 8];
    #pragma unroll
    for (int i = 0; i < 4; ++i)
        #pragma unroll
        for (int j = 0; j < 4; ++j)
            acc[i][j] = __builtin_amdgcn_mfma_f32_16x16x32_bf16(a[i], bv[j], acc[i][j], 0, 0, 0);
    #pragma unroll
    for (int i = 0; i < 4; ++i) {
        #pragma unroll
        for (int j = 0; j < 4; ++j) {
            int n = n0 + wc + j * 16 + lrow;
            int c = c0 + wr + i * 16 + qd * 4;
            ushort4 pk;
            pk.x = f2bf(acc[i][j][0]); pk.y = f2bf(acc[i][j][1]);
            pk.z = f2bf(acc[i][j][2]); pk.w = f2bf(acc[i][j][3]);
            *(ushort4*)(qk3 + ((size_t)(b * 2048 + n) * 8 + h) * 256 + c) = pk;
        }
    }
}

// ---------------------------------------------------------------------------
// Fused score+softmax+xsw v8 (measured-best structure), flat qk3 layout.
// grid (256, 8), block 256 = 32 cg x 8 nn.  49.9 KB LDS -> 3 blk/CU.
// ---------------------------------------------------------------------------
__global__ __launch_bounds__(256, 3) void scorexsw8_kernel(
    unsigned short* __restrict__ qk3, const float* __restrict__ xs,
    float* __restrict__ attf)
{
    int b = blockIdx.y;
    int bx = blockIdx.x;
    int nt8 = ((bx & 7) << 5) | (bx >> 3);   // adjacent tiles -> same XCD
    int n0 = nt8 * 8;
    __shared__ unsigned short xs_s[256 * 74];   // [c][km][nn8], stride 74 u16
    __shared__ float sred[4 * 8 * 72];          // [wave][nn][h*9+km]
    __shared__ float a_s[64 * 9];               // [(h*8+nn)][km]
    int tid = threadIdx.x;

    // stage xs tile (f32 global -> bf16 LDS), 18 x float4 per thread
    {
        const float* xsb = xs + (size_t)b * 256 * 18432 + n0;
        #pragma unroll
        for (int k = 0; k < 18; ++k) {
            int li = tid + k * 256;
            int c = li / 18, r = li - c * 18;
            int km = r >> 1, np2 = r & 1;
            float4 v = *(const float4*)(xsb + ((size_t)c * 9 + km) * 2048 + np2 * 4);
            ushort4 o;
            o.x = f2bf(v.x); o.y = f2bf(v.y); o.z = f2bf(v.z); o.w = f2bf(v.w);
            *(ushort4*)&xs_s[c * 74 + km * 8 + np2 * 4] = o;
        }
    }
    __syncthreads();

    int cg = tid >> 3;      // c-group (8 c each), 0..31
    int nn = tid & 7;       // n within 8-tile
    int n = n0 + nn;
    unsigned short* qkp = qk3 + ((size_t)(b * 2048 + n) * 8) * 256 + cg * 8;
    int wv = tid >> 6;
    int sbase = (wv * 8 + nn) * 72;

    // ---- phase A: scores, 2 chunks of 4 heads ----
    #pragma unroll
    for (int hc = 0; hc < 2; ++hc) {
        uint4 qpk[4];
        #pragma unroll
        for (int hh = 0; hh < 4; ++hh)
            qpk[hh] = *(const uint4*)(qkp + (size_t)(hc * 4 + hh) * 256);
        float s[4][9];
        #pragma unroll
        for (int hh = 0; hh < 4; ++hh)
            #pragma unroll
            for (int km = 0; km < 9; ++km) s[hh][km] = 0.0f;
        #pragma unroll
        for (int cl = 0; cl < 8; ++cl) {
            float xv[9];
            const unsigned short* xrow = &xs_s[(cg * 8 + cl) * 74 + nn];
            #pragma unroll
            for (int km = 0; km < 9; ++km) xv[km] = bf2f(xrow[km * 8]);
            #pragma unroll
            for (int hh = 0; hh < 4; ++hh) {
                float qv = bf2f(((const unsigned short*)&qpk[hh])[cl]);
                #pragma unroll
                for (int km = 0; km < 9; ++km) s[hh][km] += qv * xv[km];
            }
        }
        // butterfly over the 8 c-groups within the wave (lane bits 3..5)
        #pragma unroll
        for (int hh = 0; hh < 4; ++hh)
            #pragma unroll
            for (int km = 0; km < 9; ++km) {
                float v = s[hh][km];
                v += __shfl_xor(v, 8);
                v += __shfl_xor(v, 16);
                v += __shfl_xor(v, 32);
                s[hh][km] = v;
            }
        if ((cg & 7) == 0) {
            #pragma unroll
            for (int hh = 0; hh < 4; ++hh)
                #pragma unroll
                for (int km = 0; km < 9; ++km)
                    sred[sbase + (hc * 4 + hh) * 9 + km] = s[hh][km];
        }
    }
    __syncthreads();

    // ---- softmax: 64 threads, one per (h, nn) ----
    if (tid < 64) {
        int h = tid >> 3, nn2 = tid & 7;
        float t[9];
        float m = -1e30f;
        #pragma unroll
        for (int km = 0; km < 9; ++km) {
            t[km] = (sred[(0 * 8 + nn2) * 72 + h * 9 + km]
                   + sred[(1 * 8 + nn2) * 72 + h * 9 + km]
                   + sred[(2 * 8 + nn2) * 72 + h * 9 + km]
                   + sred[(3 * 8 + nn2) * 72 + h * 9 + km]) * SCALE_;
            m = fmaxf(m, t[km]);
        }
        float den = 0.0f;
        #pragma unroll
        for (int km = 0; km < 9; ++km) { t[km] = expf(t[km] - m); den += t[km]; }
        float inv = 1.0f / den;
        size_t ab = (((size_t)(b * 8 + h)) * 2048 + n0 + nn2) * 9;
        #pragma unroll
        for (int km = 0; km < 9; ++km) {
            float av = t[km] * inv;
            attf[ab + km] = av;
            a_s[(h * 8 + nn2) * 9 + km] = av;
        }
    }
    __syncthreads();

    // ---- phase B: xsw in-place, 2 chunks of 4 heads ----
    #pragma unroll
    for (int hc = 0; hc < 2; ++hc) {
        float a[4][9];
        #pragma unroll
        for (int hh = 0; hh < 4; ++hh)
            #pragma unroll
            for (int km = 0; km < 9; ++km)
                a[hh][km] = a_s[((hc * 4 + hh) * 8 + nn) * 9 + km];
        unsigned short ov[4][8];
        #pragma unroll
        for (int cl = 0; cl < 8; ++cl) {
            float xv[9];
            const unsigned short* xrow = &xs_s[(cg * 8 + cl) * 74 + nn];
            #pragma unroll
            for (int km = 0; km < 9; ++km) xv[km] = bf2f(xrow[km * 8]);
            #pragma unroll
            for (int hh = 0; hh < 4; ++hh) {
                float acc = 0.0f;
                #pragma unroll
                for (int km = 0; km < 9; ++km) acc += a[hh][km] * xv[km];
                ov[hh][cl] = f2bf(acc);
            }
        }
        #pragma unroll
        for (int hh = 0; hh < 4; ++hh)
            *(uint4*)(qkp + (size_t)(hc * 4 + hh) * 256) = *(const uint4*)&ov[hh][0];
    }
}

// attn.mean(0) -> (NS, KM), deterministic
__global__ __launch_bounds__(256) void attn_reduce_kernel(
    const float* __restrict__ attf, float* __restrict__ o_attn)
{
    int e = blockIdx.x * 256 + threadIdx.x;
    int n = e / 9, km = e % 9;
    float sum = 0.0f;
    for (int bh = 0; bh < 64; ++bh)
        sum += attf[(((size_t)bh << 11) + n) * 9 + km];
    o_attn[e] = sum * (1.0f / 64.0f);
}

// ---------------------------------------------------------------------------
// outv via MFMA -> outb bf16 (r, 256)
// grid (128 row-tiles, 8 h), block 256.
// ---------------------------------------------------------------------------
__global__ __launch_bounds__(256) void outv_mfma_kernel(
    const unsigned short* __restrict__ xswb, const unsigned short* __restrict__ wvb,
    const float* __restrict__ bv, unsigned short* __restrict__ outb)
{
    int h = blockIdx.y;
    int r0 = blockIdx.x * 128;
    __shared__ unsigned short As[128][40];
    __shared__ unsigned short Bs[32][40];
    int tid = threadIdx.x, lane = tid & 63, wid = tid >> 6;
    int lrow = lane & 15, q = lane >> 4;
    int srow = tid & 127, skc = (tid >> 7) * 16;
    f32x4 acc[2][2];
    #pragma unroll
    for (int i = 0; i < 2; ++i)
        #pragma unroll
        for (int j = 0; j < 2; ++j) {
            acc[i][j][0] = 0.f; acc[i][j][1] = 0.f;
            acc[i][j][2] = 0.f; acc[i][j][3] = 0.f;
        }

    for (int k0 = 0; k0 < 256; k0 += 32) {
        const unsigned short* Ap = xswb + ((size_t)(r0 + srow) * 8 + h) * 256 + k0 + skc;
        *(uint4*)&As[srow][skc]     = *(const uint4*)Ap;
        *(uint4*)&As[srow][skc + 8] = *(const uint4*)(Ap + 8);
        if (tid < 64) {
            int o = tid & 31, seg = (tid >> 5) * 16;
            const unsigned short* Wp = wvb + (size_t)(h * 32 + o) * 256 + k0 + seg;
            *(uint4*)&Bs[o][seg]     = *(const uint4*)Wp;
            *(uint4*)&Bs[o][seg + 8] = *(const uint4*)(Wp + 8);
        }
        __syncthreads();
        bf16x8 a2[2], b2[2];
        #pragma unroll
        for (int i = 0; i < 2; ++i) a2[i] = *(const bf16x8*)&As[wid * 32 + i * 16 + lrow][q * 8];
        #pragma unroll
        for (int j = 0; j < 2; ++j) b2[j] = *(const bf16x8*)&Bs[j * 16 + lrow][q * 8];
        #pragma unroll
        for (int i = 0; i < 2; ++i)
            #pragma unroll
            for (int j = 0; j < 2; ++j)
                acc[i][j] = __builtin_amdgcn_mfma_f32_16x16x32_bf16(a2[i], b2[j], acc[i][j], 0, 0, 0);
        __syncthreads();
    }

    #pragma unroll
    for (int i = 0; i < 2; ++i) {
        int rr = r0 + wid * 32 + i * 16 + q * 4;
        #pragma unroll
        for (int j = 0; j < 2; ++j) {
            int oo = h * 32 + j * 16 + lrow;
            float bvv = bv[oo];
            #pragma unroll
            for (int g2 = 0; g2 < 4; ++g2)
                outb[(size_t)(rr + g2) * 256 + oo] = f2bf(acc[i][j][g2] + bvv);
        }
    }
}

// pred_loc = l2 @ Wl3^T + bl3  (Cout=2), l2 in bf16
__global__ __launch_bounds__(256) void loc_kernel(
    const unsigned short* __restrict__ l2, const float* __restrict__ Wl3,
    const float* __restrict__ bl3, float* __restrict__ o_loc)
{
    int f = blockIdx.x * 256 + threadIdx.x;
    int r = f >> 1, o = f & 1;
    const unsigned short* row = l2 + (size_t)r * 256;
    const float* wr = Wl3 + (size_t)o * 256;
    float sum = bl3[o];
    for (int c = 0; c < 256; c += 8) {
        uint4 u = *(const uint4*)&row[c];
        const unsigned short* us = (const unsigned short*)&u;
        float4 w0 = *(const float4*)&wr[c];
        float4 w1 = *(const float4*)&wr[c + 4];
        sum += bf2f(us[0]) * w0.x + bf2f(us[1]) * w0.y + bf2f(us[2]) * w0.z + bf2f(us[3]) * w0.w;
        sum += bf2f(us[4]) * w1.x + bf2f(us[5]) * w1.y + bf2f(us[6]) * w1.z + bf2f(us[7]) * w1.w;
    }
    o_loc[f] = sum;
}

__global__ __launch_bounds__(256) void loss_loc_partial(
    const float* __restrict__ pred, const float* __restrict__ coords,
    float* __restrict__ partial)
{
    int tid = threadIdx.x;
    float sum = 0.0f;
    for (int e = blockIdx.x * 256 + tid; e < 32768; e += 65536)
        sum += fabsf(pred[e] - coords[e]);
    __shared__ float red[256];
    red[tid] = sum;
    __syncthreads();
    for (int w = 128; w > 0; w >>= 1) {
        if (tid < w) red[tid] += red[tid + w];
        __syncthreads();
    }
    if (tid == 0) partial[blockIdx.x] = red[0];
}

__global__ __launch_bounds__(256) void loss_final(
    const float* __restrict__ part, float* __restrict__ out)
{
    __shared__ float red[256];
    int t = threadIdx.x;
    red[t] = part[t];
    __syncthreads();
    for (int w = 128; w > 0; w >>= 1) {
        if (t < w) red[t] += red[t + w];
        __syncthreads();
    }
    if (t == 0) out[0] = red[0] * (1.0f / 4194304.0f);
    __syncthreads();
    red[t] = part[256 + t];
    __syncthreads();
    for (int w = 128; w > 0; w >>= 1) {
        if (t < w) red[t] += red[t + w];
        __syncthreads();
    }
    if (t == 0) out[1] = red[0] * (1.0f / 32768.0f);
}

extern "C" void kernel_launch(void* const* d_in, const int* in_sizes, int n_in,
                              void* d_out, int out_size, void* d_ws, size_t ws_size,
                              hipStream_t stream) {
    const float* x     = (const float*)d_in[0];
    const int*   idx   = (const int*)d_in[1];
    const int*   labels= (const int*)d_in[2];
    const float* coords= (const float*)d_in[3];
    const float* W_ip  = (const float*)d_in[4];
    const float* b_ip  = (const float*)d_in[5];
    const float* Wq    = (const float*)d_in[6];
    const float* bq    = (const float*)d_in[7];
    const float* Wk    = (const float*)d_in[8];
    const float* bk    = (const float*)d_in[9];
    const float* Wv    = (const float*)d_in[10];
    const float* bv    = (const float*)d_in[11];
    const float* W_dw  = (const float*)d_in[12];
    const float* b_dw  = (const float*)d_in[13];
    const float* W_pw  = (const float*)d_in[14];
    const float* Wc1   = (const float*)d_in[15];
    const float* bc1   = (const float*)d_in[16];
    const float* Wc2   = (const float*)d_in[17];
    const float* bc2   = (const float*)d_in[18];
    const float* Wc3   = (const float*)d_in[19];
    const float* bc3   = (const float*)d_in[20];
    const float* Wl1   = (const float*)d_in[21];
    const float* bl1   = (const float*)d_in[22];
    const float* Wl2   = (const float*)d_in[23];
    const float* bl2   = (const float*)d_in[24];
    const float* Wl3   = (const float*)d_in[25];
    const float* bl3   = (const float*)d_in[26];

    float* out = (float*)d_out;
    float* ws  = (float*)d_ws;

    // workspace (f32 units), total ~24.6M = 98.5 MB.
    unsigned short* xt   = (unsigned short*)ws;                       // [0, 8.4M)
    unsigned short* x1t  = (unsigned short*)(ws + 8388608);           // [8.4M, 12.6M)
    unsigned short* qk3  = (unsigned short*)ws;                       // [0, 16.8M) over dead xt/x1t
    unsigned short* qft  = (unsigned short*)(ws + 16777216);          // [16.8M, 21.0M)
    unsigned short* h1   = (unsigned short*)ws;                       // [0, 4.2M) over dead qk3
    unsigned short* h2c  = (unsigned short*)(ws + 4194304);
    unsigned short* h2l  = (unsigned short*)(ws + 6291456);
    float*          posb = ws + 20971520;                             // [21.0M, 22.15M) (later attf)
    float*          attf = ws + 20971520;
    unsigned short* wktb = (unsigned short*)(ws + 22151168);          // 65536 bf16
    unsigned short* wb   = (unsigned short*)(ws + 22183936);          // 8x65536 bf16
    float*          b512 = ws + 22446080;
    float*          part = ws + 22446592;                             // 512
    unsigned short* outb = (unsigned short*)(ws + 22447104);          // 16384x256 bf16

    unsigned short* wipb = wb;
    unsigned short* wqb  = wb + 65536;
    unsigned short* wc1b = wb + 131072;   // wl1 adjacent -> merged 512-row weight
    unsigned short* wl1b = wb + 196608;
    unsigned short* wc2b = wb + 262144;
    unsigned short* wl2b = wb + 327680;
    unsigned short* wc3b = wb + 393216;
    unsigned short* wvb  = wb + 458752;
    (void)wl1b;

    float* o_xs   = out + 2;
    float* o_cls  = out + 37748738;
    float* o_loc  = out + 41943042;
    float* o_attn = out + 41975810;

    // 0. weight casts + Wk^T + merged bias
    WC wc;
    wc.s[0] = W_ip; wc.d[0] = wipb;
    wc.s[1] = Wq;   wc.d[1] = wqb;
    wc.s[2] = Wc1;  wc.d[2] = wc1b;
    wc.s[3] = Wl1;  wc.d[3] = wl1b;
    wc.s[4] = Wc2;  wc.d[4] = wc2b;
    wc.s[5] = Wl2;  wc.d[5] = wl2b;
    wc.s[6] = Wc3;  wc.d[6] = wc3b;
    wc.s[7] = Wv;   wc.d[7] = wvb;
    wcast_kernel<<<dim3(64, 8), 256, 0, stream>>>(wc);
    wtrans_kernel<<<dim3(4, 4), 256, 0, stream>>>(Wk, wktb);
    biascat_kernel<<<1, 512, 0, stream>>>(bc1, bl1, b512);
    // 0b. x -> xt (b,p,c) bf16
    xtk_kernel<<<dim3(64, 4, 8), 256, 0, stream>>>(x, xt);
    // 1. x1t = gelu(xt @ W_ip^T + b_ip)
    mfma_gemm<1, false, true><<<dim3(256, 2), 256, 0, stream>>>(xt, 256, wipb, b_ip, x1t, 256);
    // 2. qft = x1t @ Wq^T + bq
    mfma_gemm<0, false, true><<<dim3(256, 2), 256, 0, stream>>>(x1t, 256, wqb, bq, qft, 256);
    // 3. positions (vectorized-gather dwconv + pointwise + tanh, 6 blk/CU)
    posk3_kernel<<<dim3(32, 32), 256, 0, stream>>>(qft, idx, W_dw, b_dw, W_pw, posb);
    // 4. bilinear sample (ushort8 gathers, 6 blk/CU) -> x_sampled (output)
    sample5_kernel<<<dim3(32, 36, 8), 256, 0, stream>>>(x1t, posb, o_xs);
    // 5. qk (MFMA, inline q-gather) -> qk3 (b,n,h,c)
    qk_mfma_kernel<<<dim3(16, 2, 64), 256, 0, stream>>>(wktb, qft, idx, qk3);
    // 6. fused scores + softmax + xsw (v8 proven structure, in-place)
    scorexsw8_kernel<<<dim3(256, 8), 256, 0, stream>>>(qk3, o_xs, attf);
    // 7. attn mean
    attn_reduce_kernel<<<72, 256, 0, stream>>>(attf, o_attn);
    // 8. out = Wv @ xsw + bv -> outb BF16 (B*NS, 256)  [MFMA]
    outv_mfma_kernel<<<dim3(128, 8), 256, 0, stream>>>(qk3, wvb, bv, outb);
    // 9. merged MLP layer 1 (cls||loc) -> h1 (16384 x 512)  [bf16 A]
    mfma_gemm<2, false, true><<<dim3(128, 4), 256, 0, stream>>>(outb, 256, wc1b, b512, h1, 512);
    // 10-11. layer 2
    mfma_gemm<2, false, true><<<dim3(128, 2), 256, 0, stream>>>(h1, 512, wc2b, bc2, h2c, 256);
    mfma_gemm<2, false, true><<<dim3(128, 2), 256, 0, stream>>>(h1 + 256, 512, wl2b, bl2, h2l, 256);
    // 12. cls layer 3 -> o_cls with FUSED loss partial -> part[0..255]
    mfma_gemm_cls<<<dim3(128, 2), 256, 0, stream>>>(h2c, wc3b, bc3, o_cls, labels, part);
    // 13. loc layer 3
    loc_kernel<<<128, 256, 0, stream>>>(h2l, Wl3, bl3, o_loc);
    // 14-15. losses (cls partial already fused into GEMM)
    loss_loc_partial<<<256, 256, 0, stream>>>(o_loc, coords, part + 256);
    loss_final<<<1, 256, 0, stream>>>(part, out);
}

// Round 19
// 373.522 us; speedup vs baseline: 1.1940x; 1.0011x over previous
//
#include <hip/hip_runtime.h>
#include <hip/hip_bf16.h>

#define SCALE_ 0.17677669529663687f  // 32^-0.5

typedef __attribute__((ext_vector_type(4))) float f32x4;
typedef __attribute__((ext_vector_type(8))) short bf16x8;

__device__ __forceinline__ float gelu_f(float v) {
    return 0.5f * v * (1.0f + erff(v * 0.70710678118654752f));
}

__device__ __forceinline__ unsigned short f2bf(float f) {
    __hip_bfloat16 hb = __float2bfloat16(f);
    return *reinterpret_cast<unsigned short*>(&hb);
}
__device__ __forceinline__ float bf2f(unsigned short u) {
    unsigned int ui = ((unsigned int)u) << 16;
    float f;
    __builtin_memcpy(&f, &ui, 4);
    return f;
}

// ---------------------------------------------------------------------------
// Weight cast f32 -> bf16 (8 matrices of 256x256, incl. Wv)
// ---------------------------------------------------------------------------
struct WC {
    const float* s[8];
    unsigned short* d[8];
};

__global__ __launch_bounds__(256) void wcast_kernel(WC wc) {
    int m = blockIdx.y;
    int e = blockIdx.x * 1024 + threadIdx.x * 4;
    const float4 v = *(const float4*)(wc.s[m] + e);
    ushort4 o;
    o.x = f2bf(v.x); o.y = f2bf(v.y); o.z = f2bf(v.z); o.w = f2bf(v.w);
    *(ushort4*)(wc.d[m] + e) = o;
}

// Wk (256x256) -> Wk^T bf16
__global__ __launch_bounds__(256) void wtrans_kernel(
    const float* __restrict__ Wk, unsigned short* __restrict__ wktb)
{
    int o0 = blockIdx.x * 64, c0 = blockIdx.y * 64;
    __shared__ float sm[64][65];
    int tid = threadIdx.x;
    #pragma unroll
    for (int rep = 0; rep < 16; ++rep) {
        int oo = (tid >> 6) + rep * 4, cc = tid & 63;
        sm[oo][cc] = Wk[(size_t)(o0 + oo) * 256 + c0 + cc];
    }
    __syncthreads();
    #pragma unroll
    for (int rep = 0; rep < 16; ++rep) {
        int cc = (tid >> 6) + rep * 4, oo = tid & 63;
        wktb[(size_t)(c0 + cc) * 256 + o0 + oo] = f2bf(sm[oo][cc]);
    }
}

__global__ __launch_bounds__(512) void biascat_kernel(
    const float* __restrict__ bc1, const float* __restrict__ bl1,
    float* __restrict__ bias512)
{
    int t = threadIdx.x;
    bias512[t] = (t < 256) ? bc1[t] : bl1[t - 256];
}

// ---------------------------------------------------------------------------
// x (b, c, p) f32  ->  xt (b, p, c) bf16
// ---------------------------------------------------------------------------
__global__ __launch_bounds__(256) void xtk_kernel(
    const float* __restrict__ x, unsigned short* __restrict__ xt)
{
    int b = blockIdx.z;
    int c0 = blockIdx.y * 64;
    int p0 = blockIdx.x * 64;
    __shared__ float sm[64][65];
    int tid = threadIdx.x;
    #pragma unroll
    for (int rep = 0; rep < 16; ++rep) {
        int cc = (tid >> 6) + rep * 4, pp = tid & 63;
        sm[cc][pp] = x[(((size_t)(b * 256 + c0 + cc)) << 12) + p0 + pp];
    }
    __syncthreads();
    #pragma unroll
    for (int rep = 0; rep < 16; ++rep) {
        int pp = (tid >> 6) + rep * 4, cc = tid & 63;
        xt[((size_t)(b * 4096 + p0 + pp)) * 256 + c0 + cc] = f2bf(sm[cc][pp]);
    }
}

// ---------------------------------------------------------------------------
// MFMA GEMM: Y[r, o] = act(sum_k A[r,k] * W[o,k] + bias[o]), K = 256 fixed.
// BK=64: 4 k-iterations (half the barriers of BK=32).  LDS 36.9 KB; occupancy
// stays VGPR-bound (~3 blocks/CU) so no residency loss.
// ---------------------------------------------------------------------------
template<int ACT, bool OUT_BF16>
__global__ __launch_bounds__(256) void mfma_gemm(
    const unsigned short* __restrict__ Ab, int lda,
    const unsigned short* __restrict__ Wb,
    const float* __restrict__ bias, void* __restrict__ Yv, int ldy)
{
    int r0 = blockIdx.x * 128;
    int o0 = blockIdx.y * 128;
    __shared__ unsigned short As[128][72];
    __shared__ unsigned short Bs[128][72];
    int tid = threadIdx.x;
    int lane = tid & 63;
    int wid = tid >> 6;
    int wr = (wid >> 1) * 64, wc = (wid & 1) * 64;
    int lrow = lane & 15, q = lane >> 4;
    f32x4 acc[4][4];
    #pragma unroll
    for (int i = 0; i < 4; ++i)
        #pragma unroll
        for (int j = 0; j < 4; ++j) {
            acc[i][j][0] = 0.f; acc[i][j][1] = 0.f;
            acc[i][j][2] = 0.f; acc[i][j][3] = 0.f;
        }

    int srow = tid & 127;
    int skc = (tid >> 7) * 32;

    for (int k0 = 0; k0 < 256; k0 += 64) {
        const unsigned short* Ap = Ab + (size_t)(r0 + srow) * lda + k0 + skc;
        *(uint4*)&As[srow][skc]      = *(const uint4*)Ap;
        *(uint4*)&As[srow][skc + 8]  = *(const uint4*)(Ap + 8);
        *(uint4*)&As[srow][skc + 16] = *(const uint4*)(Ap + 16);
        *(uint4*)&As[srow][skc + 24] = *(const uint4*)(Ap + 24);
        const unsigned short* Wp = Wb + (size_t)(o0 + srow) * 256 + k0 + skc;
        *(uint4*)&Bs[srow][skc]      = *(const uint4*)Wp;
        *(uint4*)&Bs[srow][skc + 8]  = *(const uint4*)(Wp + 8);
        *(uint4*)&Bs[srow][skc + 16] = *(const uint4*)(Wp + 16);
        *(uint4*)&Bs[srow][skc + 24] = *(const uint4*)(Wp + 24);
        __syncthreads();
        #pragma unroll
        for (int kk = 0; kk < 64; kk += 32) {
            bf16x8 a[4], bv[4];
            #pragma unroll
            for (int i = 0; i < 4; ++i) a[i] = *(const bf16x8*)&As[wr + i * 16 + lrow][kk + q * 8];
            #pragma unroll
            for (int j = 0; j < 4; ++j) bv[j] = *(const bf16x8*)&Bs[wc + j * 16 + lrow][kk + q * 8];
            #pragma unroll
            for (int i = 0; i < 4; ++i)
                #pragma unroll
                for (int j = 0; j < 4; ++j)
                    acc[i][j] = __builtin_amdgcn_mfma_f32_16x16x32_bf16(a[i], bv[j], acc[i][j], 0, 0, 0);
        }
        __syncthreads();
    }

    #pragma unroll
    for (int i = 0; i < 4; ++i) {
        int rr = r0 + wr + i * 16 + q * 4;
        #pragma unroll
        for (int j = 0; j < 4; ++j) {
            int oo = o0 + wc + j * 16 + lrow;
            float bb = bias[oo];
            #pragma unroll
            for (int g2 = 0; g2 < 4; ++g2) {
                float v = acc[i][j][g2] + bb;
                if constexpr (ACT == 1) v = gelu_f(v);
                else if constexpr (ACT == 2) v = fmaxf(v, 0.0f);
                if constexpr (OUT_BF16)
                    ((unsigned short*)Yv)[(size_t)(rr + g2) * ldy + oo] = f2bf(v);
                else
                    ((float*)Yv)[(size_t)(rr + g2) * ldy + oo] = v;
            }
        }
    }
}

// ---------------------------------------------------------------------------
// cls layer-3 GEMM with FUSED BCE-loss partial (BK=64).
// grid (128, 2), block 256.
// ---------------------------------------------------------------------------
__global__ __launch_bounds__(256) void mfma_gemm_cls(
    const unsigned short* __restrict__ Ab,
    const unsigned short* __restrict__ Wb,
    const float* __restrict__ bias, float* __restrict__ Y,
    const int* __restrict__ labels, float* __restrict__ part)
{
    int r0 = blockIdx.x * 128;
    int o0 = blockIdx.y * 128;
    __shared__ unsigned short As[128][72];
    __shared__ unsigned short Bs[128][72];
    __shared__ float red[256];
    int tid = threadIdx.x;
    int lane = tid & 63;
    int wid = tid >> 6;
    int wr = (wid >> 1) * 64, wc = (wid & 1) * 64;
    int lrow = lane & 15, q = lane >> 4;
    f32x4 acc[4][4];
    #pragma unroll
    for (int i = 0; i < 4; ++i)
        #pragma unroll
        for (int j = 0; j < 4; ++j) {
            acc[i][j][0] = 0.f; acc[i][j][1] = 0.f;
            acc[i][j][2] = 0.f; acc[i][j][3] = 0.f;
        }

    int srow = tid & 127;
    int skc = (tid >> 7) * 32;

    for (int k0 = 0; k0 < 256; k0 += 64) {
        const unsigned short* Ap = Ab + (size_t)(r0 + srow) * 256 + k0 + skc;
        *(uint4*)&As[srow][skc]      = *(const uint4*)Ap;
        *(uint4*)&As[srow][skc + 8]  = *(const uint4*)(Ap + 8);
        *(uint4*)&As[srow][skc + 16] = *(const uint4*)(Ap + 16);
        *(uint4*)&As[srow][skc + 24] = *(const uint4*)(Ap + 24);
        const unsigned short* Wp = Wb + (size_t)(o0 + srow) * 256 + k0 + skc;
        *(uint4*)&Bs[srow][skc]      = *(const uint4*)Wp;
        *(uint4*)&Bs[srow][skc + 8]  = *(const uint4*)(Wp + 8);
        *(uint4*)&Bs[srow][skc + 16] = *(const uint4*)(Wp + 16);
        *(uint4*)&Bs[srow][skc + 24] = *(const uint4*)(Wp + 24);
        __syncthreads();
        #pragma unroll
        for (int kk = 0; kk < 64; kk += 32) {
            bf16x8 a[4], bv[4];
            #pragma unroll
            for (int i = 0; i < 4; ++i) a[i] = *(const bf16x8*)&As[wr + i * 16 + lrow][kk + q * 8];
            #pragma unroll
            for (int j = 0; j < 4; ++j) bv[j] = *(const bf16x8*)&Bs[wc + j * 16 + lrow][kk + q * 8];
            #pragma unroll
            for (int i = 0; i < 4; ++i)
                #pragma unroll
                for (int j = 0; j < 4; ++j)
                    acc[i][j] = __builtin_amdgcn_mfma_f32_16x16x32_bf16(a[i], bv[j], acc[i][j], 0, 0, 0);
        }
        __syncthreads();
    }

    int lab[4][4];
    #pragma unroll
    for (int i = 0; i < 4; ++i) {
        int rr = r0 + wr + i * 16 + q * 4;
        #pragma unroll
        for (int g2 = 0; g2 < 4; ++g2) lab[i][g2] = labels[rr + g2];
    }

    float lsum = 0.0f;
    #pragma unroll
    for (int i = 0; i < 4; ++i) {
        int rr = r0 + wr + i * 16 + q * 4;
        #pragma unroll
        for (int j = 0; j < 4; ++j) {
            int oo = o0 + wc + j * 16 + lrow;
            float bb = bias[oo];
            #pragma unroll
            for (int g2 = 0; g2 < 4; ++g2) {
                float p = acc[i][j][g2] + bb;
                Y[(size_t)(rr + g2) * 256 + oo] = p;
                float t = (lab[i][g2] == oo) ? 1.0f : 0.0f;
                lsum += fmaxf(p, 0.0f) - p * t + log1pf(expf(-fabsf(p)));
            }
        }
    }
    red[tid] = lsum;
    __syncthreads();
    for (int w = 128; w > 0; w >>= 1) {
        if (tid < w) red[tid] += red[tid + w];
        __syncthreads();
    }
    if (tid == 0) part[blockIdx.y * 128 + blockIdx.x] = red[0];
}

// ---------------------------------------------------------------------------
// posk3: fused dwconv@points + pointwise + tanh; channel-vectorized gathers.
// grid (32 n-tiles, 32 bg), block 256.
// ---------------------------------------------------------------------------
__global__ __launch_bounds__(256, 6) void posk3_kernel(
    const unsigned short* __restrict__ qft, const int* __restrict__ idx,
    const float* __restrict__ W_dw, const float* __restrict__ b_dw,
    const float* __restrict__ W_pw, float* __restrict__ posb)
{
    int bg = blockIdx.y;
    int b = bg >> 2, g = bg & 3;
    int n0 = blockIdx.x * 64;
    __shared__ unsigned short h_s[64][68];   // [n][c]
    __shared__ float wpw_s[20 * 64];         // padded to 20 outputs
    __shared__ float off_s[20][64];
    __shared__ int pny[64], pnx[64];
    int tid = threadIdx.x;

    if (tid < 64) {
        pny[tid] = idx[2 * (n0 + tid)];
        pnx[tid] = idx[2 * (n0 + tid) + 1];
    }
    #pragma unroll
    for (int k = 0; k < 5; ++k) {
        int e = tid + k * 256;
        wpw_s[e] = (e < 1152) ? W_pw[e] : 0.0f;
    }
    __syncthreads();

    int cq = tid & 15, ns = tid >> 4;
    int cb = cq * 4;
    float wdw[4][9];
    #pragma unroll
    for (int cc = 0; cc < 4; ++cc)
        #pragma unroll
        for (int k = 0; k < 9; ++k) wdw[cc][k] = W_dw[(cb + cc) * 9 + k];
    float bdw[4];
    #pragma unroll
    for (int cc = 0; cc < 4; ++cc) bdw[cc] = b_dw[cb + cc];
    const unsigned short* qp4 = qft + (((size_t)b) << 12) * 256 + g * 64 + cb;

    #pragma unroll
    for (int jj = 0; jj < 4; ++jj) {
        int nl = ns * 4 + jj;
        int yn = pny[nl], xn = pnx[nl];
        float acc0 = bdw[0], acc1 = bdw[1], acc2 = bdw[2], acc3 = bdw[3];
        #pragma unroll
        for (int ky = 0; ky < 3; ++ky) {
            int yy = yn + ky - 1;
            if (yy < 0 || yy > 63) continue;
            #pragma unroll
            for (int kx = 0; kx < 3; ++kx) {
                int xx = xn + kx - 1;
                if (xx < 0 || xx > 63) continue;
                ushort4 u = *(const ushort4*)(qp4 + (size_t)(yy * 64 + xx) * 256);
                int k = ky * 3 + kx;
                acc0 += wdw[0][k] * bf2f(u.x);
                acc1 += wdw[1][k] * bf2f(u.y);
                acc2 += wdw[2][k] * bf2f(u.z);
                acc3 += wdw[3][k] * bf2f(u.w);
            }
        }
        ushort4 hv;
        hv.x = f2bf(gelu_f(acc0)); hv.y = f2bf(gelu_f(acc1));
        hv.z = f2bf(gelu_f(acc2)); hv.w = f2bf(gelu_f(acc3));
        *(ushort4*)&h_s[nl][cb] = hv;
    }
    __syncthreads();

    // phase 2: off[o][n] = sum_c wpw[o][c] * h[n][c]
    {
        int n = tid & 63, og = tid >> 6;
        int obase = og * 5;
        float acc[5] = {};
        for (int cc = 0; cc < 64; ++cc) {
            float hval = bf2f(h_s[n][cc]);
            #pragma unroll
            for (int j = 0; j < 5; ++j)
                acc[j] += wpw_s[(obase + j) * 64 + cc] * hval;
        }
        #pragma unroll
        for (int j = 0; j < 5; ++j) off_s[obase + j][n] = acc[j];
    }
    __syncthreads();

    // phase 3: tanh + clamp + write positions
    for (int e = tid; e < 576; e += 256) {
        int km = e / 64, n2 = e & 63;
        int yn = pny[n2], xn = pnx[n2];
        int ky = km / 3, kx = km % 3;
        int yc = yn + ky - 1; yc = yc < 0 ? 0 : (yc > 63 ? 63 : yc);
        int xc = xn + kx - 1; xc = xc < 0 ? 0 : (xc > 63 ? 63 : xc);
        float py = tanhf(off_s[2 * km][n2])     * 0.03125f + ((yc + 0.5f) * 0.03125f - 1.0f);
        float px = tanhf(off_s[2 * km + 1][n2]) * 0.03125f + ((xc + 0.5f) * 0.03125f - 1.0f);
        size_t pb = (((size_t)bg * 9 + km) * 2048 + n0 + n2) * 2;
        posb[pb] = py;
        posb[pb + 1] = px;
    }
}

// ---------------------------------------------------------------------------
// Bilinear sample v5: ushort8 gathers (8 channels/lane).
// grid (32 n-tiles, 36 = g*9+km, 8 b), block 256.
// ---------------------------------------------------------------------------
__global__ __launch_bounds__(256, 6) void sample5_kernel(
    const unsigned short* __restrict__ x1t, const float* __restrict__ posb,
    float* __restrict__ o_xs)
{
    int b = blockIdx.z;
    int g = blockIdx.y / 9, km = blockIdx.y % 9;
    int n0 = blockIdx.x * 64;
    int tid = threadIdx.x;
    int c8 = tid & 7;         // 8 channels each: c = c8*8 .. +7
    int ns = tid >> 3;        // 32 n-slots x 2 consecutive n each
    int bg = b * 4 + g;
    __shared__ float sm[64][68];
    const unsigned short* img8 = x1t + (((size_t)b) << 12) * 256 + g * 64 + c8 * 8;
    size_t pb = (((size_t)bg * 9 + km) * 2048 + n0 + ns * 2) * 2;
    float4 P = *(const float4*)&posb[pb];   // (y0,x0,y1,x1)
    float py[2] = {P.x, P.z};
    float px[2] = {P.y, P.w};
    #pragma unroll
    for (int j = 0; j < 2; ++j) {
        float iy = (py[j] + 1.0f) * 31.5f;
        float ix = (px[j] + 1.0f) * 31.5f;
        float y0f = floorf(iy), x0f = floorf(ix);
        float wy = iy - y0f, wx = ix - x0f;
        int yy = (int)y0f, xx = (int)x0f;
        float w00 = (1.0f - wx) * (1.0f - wy), w01 = wx * (1.0f - wy);
        float w10 = (1.0f - wx) * wy,          w11 = wx * wy;
        bool vy0 = (yy >= 0) & (yy <= 63), vy1 = (yy >= -1) & (yy <= 62);
        bool vx0 = (xx >= 0) & (xx <= 63), vx1 = (xx >= -1) & (xx <= 62);
        if (!vy0) { w00 = 0.f; w01 = 0.f; }
        if (!vy1) { w10 = 0.f; w11 = 0.f; }
        if (!vx0) { w00 = 0.f; w10 = 0.f; }
        if (!vx1) { w01 = 0.f; w11 = 0.f; }
        int yc0 = yy < 0 ? 0 : (yy > 63 ? 63 : yy);
        int yc1 = yy + 1 < 0 ? 0 : (yy + 1 > 63 ? 63 : yy + 1);
        int xc0 = xx < 0 ? 0 : (xx > 63 ? 63 : xx);
        int xc1 = xx + 1 < 0 ? 0 : (xx + 1 > 63 ? 63 : xx + 1);
        uint4 u00 = *(const uint4*)(img8 + (size_t)(yc0 * 64 + xc0) * 256);
        uint4 u01 = *(const uint4*)(img8 + (size_t)(yc0 * 64 + xc1) * 256);
        uint4 u10 = *(const uint4*)(img8 + (size_t)(yc1 * 64 + xc0) * 256);
        uint4 u11 = *(const uint4*)(img8 + (size_t)(yc1 * 64 + xc1) * 256);
        const unsigned short* s00 = (const unsigned short*)&u00;
        const unsigned short* s01 = (const unsigned short*)&u01;
        const unsigned short* s10 = (const unsigned short*)&u10;
        const unsigned short* s11 = (const unsigned short*)&u11;
        f32x4 oA, oB;
        #pragma unroll
        for (int e = 0; e < 4; ++e)
            oA[e] = w00 * bf2f(s00[e]) + w01 * bf2f(s01[e])
                  + w10 * bf2f(s10[e]) + w11 * bf2f(s11[e]);
        #pragma unroll
        for (int e = 0; e < 4; ++e)
            oB[e] = w00 * bf2f(s00[e + 4]) + w01 * bf2f(s01[e + 4])
                  + w10 * bf2f(s10[e + 4]) + w11 * bf2f(s11[e + 4]);
        *(f32x4*)&sm[ns * 2 + j][c8 * 8]     = oA;
        *(f32x4*)&sm[ns * 2 + j][c8 * 8 + 4] = oB;
    }
    __syncthreads();
    size_t obase = ((((size_t)(b * 256 + g * 64)) * 9 + km) << 11) + n0;
    int nn = tid & 63;
    #pragma unroll
    for (int rep = 0; rep < 4; ++rep) {
        int cc4 = (tid >> 6) + rep * 4;
        float4 v4 = *(const float4*)&sm[nn][cc4 * 4];
        o_xs[obase + (size_t)(cc4 * 4 + 0) * 18432 + nn] = v4.x;
        o_xs[obase + (size_t)(cc4 * 4 + 1) * 18432 + nn] = v4.y;
        o_xs[obase + (size_t)(cc4 * 4 + 2) * 18432 + nn] = v4.z;
        o_xs[obase + (size_t)(cc4 * 4 + 3) * 18432 + nn] = v4.w;
    }
}

// ---------------------------------------------------------------------------
// qk3[((b*2048+n)*8+h)*256 + c] = sum_j Wk[h*32+j, c] * q[b, h*32+j, n]
// MFMA K=32 with inline q-row gather (qft + idx), flat (b,n,h,c) layout.
// grid (16 n-tiles, 2 c-tiles, 64 bh)
// ---------------------------------------------------------------------------
__global__ __launch_bounds__(256) void qk_mfma_kernel(
    const unsigned short* __restrict__ wktb, const unsigned short* __restrict__ qft,
    const int* __restrict__ idx, unsigned short* __restrict__ qk3)
{
    int bh = blockIdx.z, b = bh >> 3, h = bh & 7;
    int c0 = blockIdx.y * 128;
    int n0 = blockIdx.x * 128;
    __shared__ unsigned short As[128][40];
    __shared__ unsigned short Bs[128][40];
    __shared__ int pn[128];
    int tid = threadIdx.x, lane = tid & 63, wid = tid >> 6;
    int wr = (wid >> 1) * 64, wc = (wid & 1) * 64;
    int lrow = lane & 15, qd = lane >> 4;
    int srow = tid & 127, skc = (tid >> 7) * 16;
    if (tid < 128) pn[tid] = idx[2 * (n0 + tid)] * 64 + idx[2 * (n0 + tid) + 1];
    __syncthreads();
    {
        const unsigned short* Ap = wktb + (size_t)(c0 + srow) * 256 + h * 32 + skc;
        *(uint4*)&As[srow][skc]     = *(const uint4*)Ap;
        *(uint4*)&As[srow][skc + 8] = *(const uint4*)(Ap + 8);
        const unsigned short* Bp = qft + ((size_t)(b * 4096 + pn[srow])) * 256 + h * 32 + skc;
        *(uint4*)&Bs[srow][skc]     = *(const uint4*)Bp;
        *(uint4*)&Bs[srow][skc + 8] = *(const uint4*)(Bp + 8);
    }
    __syncthreads();
    f32x4 acc[4][4];
    #pragma unroll
    for (int i = 0; i < 4; ++i)
        #pragma unroll
        for (int j = 0; j < 4; ++j) {
            acc[i][j][0] = 0.f; acc[i][j][1] = 0.f;
            acc[i][j][2] = 0.f; acc[i][j][3] = 0.f;
        }
    bf16x8 a[4], bv[4];
    #pragma unroll
    for (int i = 0; i < 4; ++i) a[i] = *(const bf16x8*)&As[wr + i * 16 + lrow][qd * 8];
    #pragma unroll
    for (int j = 0; j < 4; ++j) bv[j] = *(const bf16x8*)&Bs[wc + j * 16 + lrow][qd * 8];
    #pragma unroll
    for (int i = 0; i < 4; ++i)
        #pragma unroll
        for (int j = 0; j < 4; ++j)
            acc[i][j] = __builtin_amdgcn_mfma_f32_16x16x32_bf16(a[i], bv[j], acc[i][j], 0, 0, 0);
    #pragma unroll
    for (int i = 0; i < 4; ++i) {
        #pragma unroll
        for (int j = 0; j < 4; ++j) {
            int n = n0 + wc + j * 16 + lrow;
            int c = c0 + wr + i * 16 + qd * 4;
            ushort4 pk;
            pk.x = f2bf(acc[i][j][0]); pk.y = f2bf(acc[i][j][1]);
            pk.z = f2bf(acc[i][j][2]); pk.w = f2bf(acc[i][j][3]);
            *(ushort4*)(qk3 + ((size_t)(b * 2048 + n) * 8 + h) * 256 + c) = pk;
        }
    }
}

// ---------------------------------------------------------------------------
// Fused score+softmax+xsw v8 (measured-best structure), flat qk3 layout.
// grid (256, 8), block 256 = 32 cg x 8 nn.  49.9 KB LDS -> 3 blk/CU.
// ---------------------------------------------------------------------------
__global__ __launch_bounds__(256, 3) void scorexsw8_kernel(
    unsigned short* __restrict__ qk3, const float* __restrict__ xs,
    float* __restrict__ attf)
{
    int b = blockIdx.y;
    int bx = blockIdx.x;
    int nt8 = ((bx & 7) << 5) | (bx >> 3);   // adjacent tiles -> same XCD
    int n0 = nt8 * 8;
    __shared__ unsigned short xs_s[256 * 74];   // [c][km][nn8], stride 74 u16
    __shared__ float sred[4 * 8 * 72];          // [wave][nn][h*9+km]
    __shared__ float a_s[64 * 9];               // [(h*8+nn)][km]
    int tid = threadIdx.x;

    // stage xs tile (f32 global -> bf16 LDS), 18 x float4 per thread
    {
        const float* xsb = xs + (size_t)b * 256 * 18432 + n0;
        #pragma unroll
        for (int k = 0; k < 18; ++k) {
            int li = tid + k * 256;
            int c = li / 18, r = li - c * 18;
            int km = r >> 1, np2 = r & 1;
            float4 v = *(const float4*)(xsb + ((size_t)c * 9 + km) * 2048 + np2 * 4);
            ushort4 o;
            o.x = f2bf(v.x); o.y = f2bf(v.y); o.z = f2bf(v.z); o.w = f2bf(v.w);
            *(ushort4*)&xs_s[c * 74 + km * 8 + np2 * 4] = o;
        }
    }
    __syncthreads();

    int cg = tid >> 3;      // c-group (8 c each), 0..31
    int nn = tid & 7;       // n within 8-tile
    int n = n0 + nn;
    unsigned short* qkp = qk3 + ((size_t)(b * 2048 + n) * 8) * 256 + cg * 8;
    int wv = tid >> 6;
    int sbase = (wv * 8 + nn) * 72;

    // ---- phase A: scores, 2 chunks of 4 heads ----
    #pragma unroll
    for (int hc = 0; hc < 2; ++hc) {
        uint4 qpk[4];
        #pragma unroll
        for (int hh = 0; hh < 4; ++hh)
            qpk[hh] = *(const uint4*)(qkp + (size_t)(hc * 4 + hh) * 256);
        float s[4][9];
        #pragma unroll
        for (int hh = 0; hh < 4; ++hh)
            #pragma unroll
            for (int km = 0; km < 9; ++km) s[hh][km] = 0.0f;
        #pragma unroll
        for (int cl = 0; cl < 8; ++cl) {
            float xv[9];
            const unsigned short* xrow = &xs_s[(cg * 8 + cl) * 74 + nn];
            #pragma unroll
            for (int km = 0; km < 9; ++km) xv[km] = bf2f(xrow[km * 8]);
            #pragma unroll
            for (int hh = 0; hh < 4; ++hh) {
                float qv = bf2f(((const unsigned short*)&qpk[hh])[cl]);
                #pragma unroll
                for (int km = 0; km < 9; ++km) s[hh][km] += qv * xv[km];
            }
        }
        // butterfly over the 8 c-groups within the wave (lane bits 3..5)
        #pragma unroll
        for (int hh = 0; hh < 4; ++hh)
            #pragma unroll
            for (int km = 0; km < 9; ++km) {
                float v = s[hh][km];
                v += __shfl_xor(v, 8);
                v += __shfl_xor(v, 16);
                v += __shfl_xor(v, 32);
                s[hh][km] = v;
            }
        if ((cg & 7) == 0) {
            #pragma unroll
            for (int hh = 0; hh < 4; ++hh)
                #pragma unroll
                for (int km = 0; km < 9; ++km)
                    sred[sbase + (hc * 4 + hh) * 9 + km] = s[hh][km];
        }
    }
    __syncthreads();

    // ---- softmax: 64 threads, one per (h, nn) ----
    if (tid < 64) {
        int h = tid >> 3, nn2 = tid & 7;
        float t[9];
        float m = -1e30f;
        #pragma unroll
        for (int km = 0; km < 9; ++km) {
            t[km] = (sred[(0 * 8 + nn2) * 72 + h * 9 + km]
                   + sred[(1 * 8 + nn2) * 72 + h * 9 + km]
                   + sred[(2 * 8 + nn2) * 72 + h * 9 + km]
                   + sred[(3 * 8 + nn2) * 72 + h * 9 + km]) * SCALE_;
            m = fmaxf(m, t[km]);
        }
        float den = 0.0f;
        #pragma unroll
        for (int km = 0; km < 9; ++km) { t[km] = expf(t[km] - m); den += t[km]; }
        float inv = 1.0f / den;
        size_t ab = (((size_t)(b * 8 + h)) * 2048 + n0 + nn2) * 9;
        #pragma unroll
        for (int km = 0; km < 9; ++km) {
            float av = t[km] * inv;
            attf[ab + km] = av;
            a_s[(h * 8 + nn2) * 9 + km] = av;
        }
    }
    __syncthreads();

    // ---- phase B: xsw in-place, 2 chunks of 4 heads ----
    #pragma unroll
    for (int hc = 0; hc < 2; ++hc) {
        float a[4][9];
        #pragma unroll
        for (int hh = 0; hh < 4; ++hh)
            #pragma unroll
            for (int km = 0; km < 9; ++km)
                a[hh][km] = a_s[((hc * 4 + hh) * 8 + nn) * 9 + km];
        unsigned short ov[4][8];
        #pragma unroll
        for (int cl = 0; cl < 8; ++cl) {
            float xv[9];
            const unsigned short* xrow = &xs_s[(cg * 8 + cl) * 74 + nn];
            #pragma unroll
            for (int km = 0; km < 9; ++km) xv[km] = bf2f(xrow[km * 8]);
            #pragma unroll
            for (int hh = 0; hh < 4; ++hh) {
                float acc = 0.0f;
                #pragma unroll
                for (int km = 0; km < 9; ++km) acc += a[hh][km] * xv[km];
                ov[hh][cl] = f2bf(acc);
            }
        }
        #pragma unroll
        for (int hh = 0; hh < 4; ++hh)
            *(uint4*)(qkp + (size_t)(hc * 4 + hh) * 256) = *(const uint4*)&ov[hh][0];
    }
}

// attn.mean(0) -> (NS, KM), deterministic
__global__ __launch_bounds__(256) void attn_reduce_kernel(
    const float* __restrict__ attf, float* __restrict__ o_attn)
{
    int e = blockIdx.x * 256 + threadIdx.x;
    int n = e / 9, km = e % 9;
    float sum = 0.0f;
    for (int bh = 0; bh < 64; ++bh)
        sum += attf[(((size_t)bh << 11) + n) * 9 + km];
    o_attn[e] = sum * (1.0f / 64.0f);
}

// ---------------------------------------------------------------------------
// outv via MFMA -> outb bf16 (r, 256)
// grid (128 row-tiles, 8 h), block 256.
// ---------------------------------------------------------------------------
__global__ __launch_bounds__(256) void outv_mfma_kernel(
    const unsigned short* __restrict__ xswb, const unsigned short* __restrict__ wvb,
    const float* __restrict__ bv, unsigned short* __restrict__ outb)
{
    int h = blockIdx.y;
    int r0 = blockIdx.x * 128;
    __shared__ unsigned short As[128][40];
    __shared__ unsigned short Bs[32][40];
    int tid = threadIdx.x, lane = tid & 63, wid = tid >> 6;
    int lrow = lane & 15, q = lane >> 4;
    int srow = tid & 127, skc = (tid >> 7) * 16;
    f32x4 acc[2][2];
    #pragma unroll
    for (int i = 0; i < 2; ++i)
        #pragma unroll
        for (int j = 0; j < 2; ++j) {
            acc[i][j][0] = 0.f; acc[i][j][1] = 0.f;
            acc[i][j][2] = 0.f; acc[i][j][3] = 0.f;
        }

    for (int k0 = 0; k0 < 256; k0 += 32) {
        const unsigned short* Ap = xswb + ((size_t)(r0 + srow) * 8 + h) * 256 + k0 + skc;
        *(uint4*)&As[srow][skc]     = *(const uint4*)Ap;
        *(uint4*)&As[srow][skc + 8] = *(const uint4*)(Ap + 8);
        if (tid < 64) {
            int o = tid & 31, seg = (tid >> 5) * 16;
            const unsigned short* Wp = wvb + (size_t)(h * 32 + o) * 256 + k0 + seg;
            *(uint4*)&Bs[o][seg]     = *(const uint4*)Wp;
            *(uint4*)&Bs[o][seg + 8] = *(const uint4*)(Wp + 8);
        }
        __syncthreads();
        bf16x8 a2[2], b2[2];
        #pragma unroll
        for (int i = 0; i < 2; ++i) a2[i] = *(const bf16x8*)&As[wid * 32 + i * 16 + lrow][q * 8];
        #pragma unroll
        for (int j = 0; j < 2; ++j) b2[j] = *(const bf16x8*)&Bs[j * 16 + lrow][q * 8];
        #pragma unroll
        for (int i = 0; i < 2; ++i)
            #pragma unroll
            for (int j = 0; j < 2; ++j)
                acc[i][j] = __builtin_amdgcn_mfma_f32_16x16x32_bf16(a2[i], b2[j], acc[i][j], 0, 0, 0);
        __syncthreads();
    }

    #pragma unroll
    for (int i = 0; i < 2; ++i) {
        int rr = r0 + wid * 32 + i * 16 + q * 4;
        #pragma unroll
        for (int j = 0; j < 2; ++j) {
            int oo = h * 32 + j * 16 + lrow;
            float bvv = bv[oo];
            #pragma unroll
            for (int g2 = 0; g2 < 4; ++g2)
                outb[(size_t)(rr + g2) * 256 + oo] = f2bf(acc[i][j][g2] + bvv);
        }
    }
}

// pred_loc = l2 @ Wl3^T + bl3  (Cout=2), l2 in bf16
__global__ __launch_bounds__(256) void loc_kernel(
    const unsigned short* __restrict__ l2, const float* __restrict__ Wl3,
    const float* __restrict__ bl3, float* __restrict__ o_loc)
{
    int f = blockIdx.x * 256 + threadIdx.x;
    int r = f >> 1, o = f & 1;
    const unsigned short* row = l2 + (size_t)r * 256;
    const float* wr = Wl3 + (size_t)o * 256;
    float sum = bl3[o];
    for (int c = 0; c < 256; c += 8) {
        uint4 u = *(const uint4*)&row[c];
        const unsigned short* us = (const unsigned short*)&u;
        float4 w0 = *(const float4*)&wr[c];
        float4 w1 = *(const float4*)&wr[c + 4];
        sum += bf2f(us[0]) * w0.x + bf2f(us[1]) * w0.y + bf2f(us[2]) * w0.z + bf2f(us[3]) * w0.w;
        sum += bf2f(us[4]) * w1.x + bf2f(us[5]) * w1.y + bf2f(us[6]) * w1.z + bf2f(us[7]) * w1.w;
    }
    o_loc[f] = sum;
}

__global__ __launch_bounds__(256) void loss_loc_partial(
    const float* __restrict__ pred, const float* __restrict__ coords,
    float* __restrict__ partial)
{
    int tid = threadIdx.x;
    float sum = 0.0f;
    for (int e = blockIdx.x * 256 + tid; e < 32768; e += 65536)
        sum += fabsf(pred[e] - coords[e]);
    __shared__ float red[256];
    red[tid] = sum;
    __syncthreads();
    for (int w = 128; w > 0; w >>= 1) {
        if (tid < w) red[tid] += red[tid + w];
        __syncthreads();
    }
    if (tid == 0) partial[blockIdx.x] = red[0];
}

__global__ __launch_bounds__(256) void loss_final(
    const float* __restrict__ part, float* __restrict__ out)
{
    __shared__ float red[256];
    int t = threadIdx.x;
    red[t] = part[t];
    __syncthreads();
    for (int w = 128; w > 0; w >>= 1) {
        if (t < w) red[t] += red[t + w];
        __syncthreads();
    }
    if (t == 0) out[0] = red[0] * (1.0f / 4194304.0f);
    __syncthreads();
    red[t] = part[256 + t];
    __syncthreads();
    for (int w = 128; w > 0; w >>= 1) {
        if (t < w) red[t] += red[t + w];
        __syncthreads();
    }
    if (t == 0) out[1] = red[0] * (1.0f / 32768.0f);
}

extern "C" void kernel_launch(void* const* d_in, const int* in_sizes, int n_in,
                              void* d_out, int out_size, void* d_ws, size_t ws_size,
                              hipStream_t stream) {
    const float* x     = (const float*)d_in[0];
    const int*   idx   = (const int*)d_in[1];
    const int*   labels= (const int*)d_in[2];
    const float* coords= (const float*)d_in[3];
    const float* W_ip  = (const float*)d_in[4];
    const float* b_ip  = (const float*)d_in[5];
    const float* Wq    = (const float*)d_in[6];
    const float* bq    = (const float*)d_in[7];
    const float* Wk    = (const float*)d_in[8];
    const float* bk    = (const float*)d_in[9];
    const float* Wv    = (const float*)d_in[10];
    const float* bv    = (const float*)d_in[11];
    const float* W_dw  = (const float*)d_in[12];
    const float* b_dw  = (const float*)d_in[13];
    const float* W_pw  = (const float*)d_in[14];
    const float* Wc1   = (const float*)d_in[15];
    const float* bc1   = (const float*)d_in[16];
    const float* Wc2   = (const float*)d_in[17];
    const float* bc2   = (const float*)d_in[18];
    const float* Wc3   = (const float*)d_in[19];
    const float* bc3   = (const float*)d_in[20];
    const float* Wl1   = (const float*)d_in[21];
    const float* bl1   = (const float*)d_in[22];
    const float* Wl2   = (const float*)d_in[23];
    const float* bl2   = (const float*)d_in[24];
    const float* Wl3   = (const float*)d_in[25];
    const float* bl3   = (const float*)d_in[26];

    float* out = (float*)d_out;
    float* ws  = (float*)d_ws;

    // workspace (f32 units), total ~24.6M = 98.5 MB.
    unsigned short* xt   = (unsigned short*)ws;                       // [0, 8.4M)
    unsigned short* x1t  = (unsigned short*)(ws + 8388608);           // [8.4M, 12.6M)
    unsigned short* qk3  = (unsigned short*)ws;                       // [0, 16.8M) over dead xt/x1t
    unsigned short* qft  = (unsigned short*)(ws + 16777216);          // [16.8M, 21.0M)
    unsigned short* h1   = (unsigned short*)ws;                       // [0, 4.2M) over dead qk3
    unsigned short* h2c  = (unsigned short*)(ws + 4194304);
    unsigned short* h2l  = (unsigned short*)(ws + 6291456);
    float*          posb = ws + 20971520;                             // [21.0M, 22.15M) (later attf)
    float*          attf = ws + 20971520;
    unsigned short* wktb = (unsigned short*)(ws + 22151168);          // 65536 bf16
    unsigned short* wb   = (unsigned short*)(ws + 22183936);          // 8x65536 bf16
    float*          b512 = ws + 22446080;
    float*          part = ws + 22446592;                             // 512
    unsigned short* outb = (unsigned short*)(ws + 22447104);          // 16384x256 bf16

    unsigned short* wipb = wb;
    unsigned short* wqb  = wb + 65536;
    unsigned short* wc1b = wb + 131072;   // wl1 adjacent -> merged 512-row weight
    unsigned short* wl1b = wb + 196608;
    unsigned short* wc2b = wb + 262144;
    unsigned short* wl2b = wb + 327680;
    unsigned short* wc3b = wb + 393216;
    unsigned short* wvb  = wb + 458752;
    (void)wl1b;

    float* o_xs   = out + 2;
    float* o_cls  = out + 37748738;
    float* o_loc  = out + 41943042;
    float* o_attn = out + 41975810;

    // 0. weight casts + Wk^T + merged bias
    WC wc;
    wc.s[0] = W_ip; wc.d[0] = wipb;
    wc.s[1] = Wq;   wc.d[1] = wqb;
    wc.s[2] = Wc1;  wc.d[2] = wc1b;
    wc.s[3] = Wl1;  wc.d[3] = wl1b;
    wc.s[4] = Wc2;  wc.d[4] = wc2b;
    wc.s[5] = Wl2;  wc.d[5] = wl2b;
    wc.s[6] = Wc3;  wc.d[6] = wc3b;
    wc.s[7] = Wv;   wc.d[7] = wvb;
    wcast_kernel<<<dim3(64, 8), 256, 0, stream>>>(wc);
    wtrans_kernel<<<dim3(4, 4), 256, 0, stream>>>(Wk, wktb);
    biascat_kernel<<<1, 512, 0, stream>>>(bc1, bl1, b512);
    // 0b. x -> xt (b,p,c) bf16
    xtk_kernel<<<dim3(64, 4, 8), 256, 0, stream>>>(x, xt);
    // 1. x1t = gelu(xt @ W_ip^T + b_ip)
    mfma_gemm<1, true><<<dim3(256, 2), 256, 0, stream>>>(xt, 256, wipb, b_ip, x1t, 256);
    // 2. qft = x1t @ Wq^T + bq
    mfma_gemm<0, true><<<dim3(256, 2), 256, 0, stream>>>(x1t, 256, wqb, bq, qft, 256);
    // 3. positions (vectorized-gather dwconv + pointwise + tanh, 6 blk/CU)
    posk3_kernel<<<dim3(32, 32), 256, 0, stream>>>(qft, idx, W_dw, b_dw, W_pw, posb);
    // 4. bilinear sample (ushort8 gathers, 6 blk/CU) -> x_sampled (output)
    sample5_kernel<<<dim3(32, 36, 8), 256, 0, stream>>>(x1t, posb, o_xs);
    // 5. qk (MFMA, inline q-gather) -> qk3 (b,n,h,c)
    qk_mfma_kernel<<<dim3(16, 2, 64), 256, 0, stream>>>(wktb, qft, idx, qk3);
    // 6. fused scores + softmax + xsw (v8 proven structure, in-place)
    scorexsw8_kernel<<<dim3(256, 8), 256, 0, stream>>>(qk3, o_xs, attf);
    // 7. attn mean
    attn_reduce_kernel<<<72, 256, 0, stream>>>(attf, o_attn);
    // 8. out = Wv @ xsw + bv -> outb BF16 (B*NS, 256)  [MFMA]
    outv_mfma_kernel<<<dim3(128, 8), 256, 0, stream>>>(qk3, wvb, bv, outb);
    // 9. merged MLP layer 1 (cls||loc) -> h1 (16384 x 512)  [bf16 A]
    mfma_gemm<2, true><<<dim3(128, 4), 256, 0, stream>>>(outb, 256, wc1b, b512, h1, 512);
    // 10-11. layer 2
    mfma_gemm<2, true><<<dim3(128, 2), 256, 0, stream>>>(h1, 512, wc2b, bc2, h2c, 256);
    mfma_gemm<2, true><<<dim3(128, 2), 256, 0, stream>>>(h1 + 256, 512, wl2b, bl2, h2l, 256);
    // 12. cls layer 3 -> o_cls with FUSED loss partial -> part[0..255]
    mfma_gemm_cls<<<dim3(128, 2), 256, 0, stream>>>(h2c, wc3b, bc3, o_cls, labels, part);
    // 13. loc layer 3
    loc_kernel<<<128, 256, 0, stream>>>(h2l, Wl3, bl3, o_loc);
    // 14-15. losses (cls partial already fused into GEMM)
    loss_loc_partial<<<256, 256, 0, stream>>>(o_loc, coords, part + 256);
    loss_final<<<1, 256, 0, stream>>>(part, out);
}